// Round 4
// baseline (1290.091 us; speedup 1.0000x reference)
//
#include <hip/hip_runtime.h>
#include <math.h>

#define B 4
#define CG 256
#define CM 128
#define CA 128
#define H 128
#define W_ 128
#define HS 64
#define WS 64
#define L 4096
#define D1 1152
#define D2 2048
#define NPIX 65536
#define DELTA 2e-3f

// per-concurrent-batch slot: [ST 16777216 f][WfZ 4718592 f][WhiA 4718592 f][Pbf 8388608 f]
#define SLOT_F 34603008UL
#define SLOT_U 69206016UL

typedef unsigned short u16;
typedef __attribute__((ext_vector_type(8))) short short8v;
typedef __attribute__((ext_vector_type(4))) float f32x4;

__device__ __forceinline__ float bf2f(u16 x) {
    union { unsigned int u; float f; } v; v.u = ((unsigned int)x) << 16; return v.f;
}
__device__ __forceinline__ u16 f2bf(float x) {
    union { float f; unsigned int u; } v; v.f = x;
    unsigned int r = (v.u + 0x7FFFu + ((v.u >> 16) & 1u)) >> 16;
    return (u16)r;
}
__device__ __forceinline__ void gll16(const void* g, void* l) {
    __builtin_amdgcn_global_load_lds((const __attribute__((address_space(1))) void*)g,
                                     (__attribute__((address_space(3))) void*)l, 16, 0, 0);
}
__device__ __forceinline__ int refl(int i, int n) {
    return i < 0 ? -i : (i >= n ? 2 * n - 2 - i : i);
}

// K0: f_ds = 1x1 conv at even pixels, LDS-staged f strip
__global__ __launch_bounds__(256) void k_conv_ds(const float* __restrict__ f,
                                                 const float* __restrict__ gw,
                                                 const float* __restrict__ gb,
                                                 float* __restrict__ fds) {
    __shared__ float sf[CG * 64];
    int t = threadIdx.x;
    int hs = blockIdx.x, b = blockIdx.y;
    const float* fb = f + (size_t)b * CG * H * W_ + (2 * hs) * W_;
    for (int idx = t; idx < CG * 64; idx += 256) {
        int ci = idx >> 6, ws = idx & 63;
        sf[idx] = fb[(size_t)ci * H * W_ + 2 * ws];
    }
    __syncthreads();
    int ws = t & 63;
    int wave = __builtin_amdgcn_readfirstlane(t >> 6);
    const float* gwp = gw + (size_t)(wave * 32) * CG;
    float acc[32];
#pragma unroll
    for (int r = 0; r < 32; ++r) acc[r] = gb[wave * 32 + r];
    for (int ci = 0; ci < CG; ++ci) {
        float fv = sf[ci * 64 + ws];
#pragma unroll
        for (int r = 0; r < 32; ++r) acc[r] += gwp[r * CG + ci] * fv;
    }
#pragma unroll
    for (int r = 0; r < 32; ++r) {
        int co = wave * 32 + r;
        fds[(((size_t)b * CM + co) * HS + hs) * WS + ws] = acc[r];
    }
}

__global__ __launch_bounds__(64) void k_ssq(const float* __restrict__ fds,
                                            float* __restrict__ ssq) {
    int ws = threadIdx.x, hs = blockIdx.x, b = blockIdx.y;
    float s = 0.f;
    for (int c = 0; c < CM; ++c) {
        float v = fds[(((size_t)b * CM + c) * HS + hs) * WS + ws];
        s += v * v;
    }
    ssq[((size_t)b * HS + hs) * WS + ws] = s;
}

__global__ __launch_bounds__(256) void k_scale(const float* __restrict__ unk,
                                               float* __restrict__ suk,
                                               float* __restrict__ out2) {
    int b = blockIdx.x, t = threadIdx.x;
    __shared__ float red[256];
    float s = 0.f;
    for (int i = t; i < L; i += 256) {
        int hs = i >> 6, ws = i & 63;
        s += unk[(size_t)b * H * W_ + (2 * hs) * W_ + 2 * ws];
    }
    red[t] = s;
    __syncthreads();
    for (int o = 128; o > 0; o >>= 1) {
        if (t < o) red[t] += red[t + o];
        __syncthreads();
    }
    if (t == 0) {
        float u = red[0] / (float)L;
        float k = 1.0f - u;
        float su = sqrtf(u / k); su = fminf(fmaxf(su, 0.1f), 10.0f);
        float sk = sqrtf(k / u); sk = fminf(fmaxf(sk, 0.1f), 10.0f);
        suk[b * 2] = su; suk[b * 2 + 1] = sk;
        out2[b * 2] = su; out2[b * 2 + 1] = sk;
    }
}

__global__ __launch_bounds__(64) void k_gate(const float* __restrict__ unk,
                                             const float* __restrict__ ssq,
                                             const float* __restrict__ suk,
                                             float* __restrict__ g,
                                             float* __restrict__ dg) {
    int ws = threadIdx.x, hs = blockIdx.x, b = blockIdx.y;
    float sm = 0.f, sq = 0.f;
    for (int di = -1; di <= 1; ++di) {
        int rh = refl(hs + di, HS);
        for (int dj = -1; dj <= 1; ++dj) {
            int rw = refl(ws + dj, WS);
            sm += unk[(size_t)b * H * W_ + (2 * rh) * W_ + 2 * rw];
            sq += ssq[((size_t)b * HS + rh) * WS + rw];
        }
    }
    float mm   = (sm > 0.0f) ? 1.0f : 0.0f;
    float norm = sqrtf(sq);
    float gate = (mm > 0.0f) ? suk[2 * b] : suk[2 * b + 1];
    int q = hs * WS + ws;
    g[(size_t)b * L + q]  = gate / fmaxf(norm, 1e-4f);
    dg[(size_t)b * L + q] = -10000.0f * mm;
}

// K4: fp32 W + bf16 hi/lo split (batched over z)
__global__ __launch_bounds__(256) void k_buildW(const float* __restrict__ fds,
                                                float* __restrict__ Wf0,
                                                u16* __restrict__ Whi0, int b0) {
    int bz = blockIdx.z;
    int b  = b0 + bz;
    float* Wf  = Wf0  + (size_t)bz * SLOT_F;
    u16*   Whi = Whi0 + (size_t)bz * SLOT_U;
    u16*   Wlo = Whi + (size_t)L * D1;
    int ws = threadIdx.x;
    int c  = blockIdx.y * 4 + threadIdx.y;
    int hs = blockIdx.x;
    int q = hs * WS + ws;
    size_t base = (size_t)q * D1 + c * 9;
    const float* src = fds + ((size_t)b * CM + c) * HS * WS;
#pragma unroll
    for (int i = 0; i < 3; ++i) {
        int rh = refl(hs + i - 1, HS);
#pragma unroll
        for (int j = 0; j < 3; ++j) {
            int rw = refl(ws + j - 1, WS);
            float v = src[rh * WS + rw];
            u16 h = f2bf(v);
            Wf[base + i * 3 + j]  = v;
            Whi[base + i * 3 + j] = h;
            Wlo[base + i * 3 + j] = f2bf(v - bf2f(h));
        }
    }
}

// K5: symmetric split-bf16 MFMA score GEMM (upper-triangle blocks + mirror, batched)
__global__ __launch_bounds__(256) void k_gemm1(const u16* __restrict__ Whi0,
                                               const float* __restrict__ g0,
                                               const float* __restrict__ dg0,
                                               float* __restrict__ ST0, int b0) {
    __shared__ u16 sAh[128 * 32], sAl[128 * 32], sBh[128 * 32], sBl[128 * 32];
    int bz = blockIdx.z;
    const u16* Whi = Whi0 + (size_t)bz * SLOT_U;
    const u16* Wlo = Whi + (size_t)L * D1;
    const float* g  = g0  + (size_t)(b0 + bz) * L;
    const float* dg = dg0 + (size_t)(b0 + bz) * L;
    float* ST = ST0 + (size_t)bz * SLOT_F;

    int tid = threadIdx.x;
    int wv = tid >> 6, lane = tid & 63;
    int t = blockIdx.x, I = 0;
    while (t >= 32 - I) { t -= 32 - I; ++I; }
    int J = I + t;
    int pTile = I * 128, qTile = J * 128;
    int wp = (wv >> 1) * 64, wq = (wv & 1) * 64;
    int r0 = wv * 32;
    int lrow = lane >> 2, lk = (lane & 3) * 8;
    int fr = lane & 15, fq = lane >> 4;

    f32x4 acc[4][4];
#pragma unroll
    for (int mi = 0; mi < 4; ++mi)
#pragma unroll
        for (int ni = 0; ni < 4; ++ni)
#pragma unroll
            for (int r = 0; r < 4; ++r) acc[mi][ni][r] = 0.f;

    for (int k0 = 0; k0 < D1; k0 += 32) {
        __syncthreads();
        const u16* gA = Whi + (size_t)(pTile + r0 + lrow) * D1 + k0 + lk;
        gll16(gA, &sAh[r0 * 32]);
        gll16(gA + (size_t)16 * D1, &sAh[(r0 + 16) * 32]);
        const u16* gAl = Wlo + (size_t)(pTile + r0 + lrow) * D1 + k0 + lk;
        gll16(gAl, &sAl[r0 * 32]);
        gll16(gAl + (size_t)16 * D1, &sAl[(r0 + 16) * 32]);
        const u16* gB = Whi + (size_t)(qTile + r0 + lrow) * D1 + k0 + lk;
        gll16(gB, &sBh[r0 * 32]);
        gll16(gB + (size_t)16 * D1, &sBh[(r0 + 16) * 32]);
        const u16* gBl = Wlo + (size_t)(qTile + r0 + lrow) * D1 + k0 + lk;
        gll16(gBl, &sBl[r0 * 32]);
        gll16(gBl + (size_t)16 * D1, &sBl[(r0 + 16) * 32]);
        __syncthreads();

        short8v ah[4], al[4], bh[4], bl[4];
#pragma unroll
        for (int i = 0; i < 4; ++i) {
            ah[i] = *(const short8v*)&sAh[(wp + i * 16 + fr) * 32 + fq * 8];
            al[i] = *(const short8v*)&sAl[(wp + i * 16 + fr) * 32 + fq * 8];
            bh[i] = *(const short8v*)&sBh[(wq + i * 16 + fr) * 32 + fq * 8];
            bl[i] = *(const short8v*)&sBl[(wq + i * 16 + fr) * 32 + fq * 8];
        }
#pragma unroll
        for (int mi = 0; mi < 4; ++mi)
#pragma unroll
            for (int ni = 0; ni < 4; ++ni) {
                acc[mi][ni] = __builtin_amdgcn_mfma_f32_16x16x32_bf16(ah[mi], bh[ni], acc[mi][ni], 0, 0, 0);
                acc[mi][ni] = __builtin_amdgcn_mfma_f32_16x16x32_bf16(ah[mi], bl[ni], acc[mi][ni], 0, 0, 0);
                acc[mi][ni] = __builtin_amdgcn_mfma_f32_16x16x32_bf16(al[mi], bh[ni], acc[mi][ni], 0, 0, 0);
            }
    }

#pragma unroll
    for (int ni = 0; ni < 4; ++ni) {
        int qq = qTile + wq + ni * 16 + fr;
        float gq = g[qq];
        float dq = dg[qq];
#pragma unroll
        for (int mi = 0; mi < 4; ++mi) {
            int pB = pTile + wp + mi * 16 + fq * 4;
#pragma unroll
            for (int r = 0; r < 4; ++r) {
                int p = pB + r;
                float v = acc[mi][ni][r] * gq;
                if (p == qq) v += dq;
                ST[(size_t)p * L + qq] = v;
            }
        }
    }
    if (I != J) {
#pragma unroll
        for (int mi = 0; mi < 4; ++mi) {
            int p0 = pTile + wp + mi * 16 + fq * 4;
            float gp0 = g[p0], gp1 = g[p0 + 1], gp2 = g[p0 + 2], gp3 = g[p0 + 3];
#pragma unroll
            for (int ni = 0; ni < 4; ++ni) {
                int qq = qTile + wq + ni * 16 + fr;
                *(float4*)(ST + (size_t)qq * L + p0) =
                    make_float4(acc[mi][ni][0] * gp0, acc[mi][ni][1] * gp1,
                                acc[mi][ni][2] * gp2, acc[mi][ni][3] * gp3);
            }
        }
    }
}

// K6: argmax(top-2 + exact refinement) + softmax -> bf16 P (batched over y)
__global__ __launch_bounds__(256) void k_softmax(const float* __restrict__ ST0,
                                                 u16* __restrict__ Pbf0,
                                                 const float* __restrict__ Wf0,
                                                 const float* __restrict__ g0,
                                                 const float* __restrict__ dg0,
                                                 float* __restrict__ out1, int b0) {
    __shared__ float buf[L];
    __shared__ float sv1[256], sv2[256];
    __shared__ int   si1[256], si2[256];
    __shared__ float red1[256], red2[256];
    int bz = blockIdx.y;
    int b  = b0 + bz;
    const float* ST  = ST0 + (size_t)bz * SLOT_F;
    u16* Pbf         = Pbf0 + (size_t)bz * SLOT_U;
    const float* Wf  = Wf0 + (size_t)bz * SLOT_F;
    const float* g   = g0  + (size_t)b * L;
    const float* dg  = dg0 + (size_t)b * L;

    int p = blockIdx.x, t = threadIdx.x;
    const float* rowp = ST + (size_t)p * L;
    float v1 = -3.4e38f, v2 = -3.4e38f; int i1 = L, i2 = L;
    for (int i = t; i < L; i += 256) {
        float v = rowp[i];
        buf[i] = v;
        if (v > v1) { v2 = v1; i2 = i1; v1 = v; i1 = i; }
        else if (v > v2) { v2 = v; i2 = i; }
    }
    sv1[t] = v1; si1[t] = i1; sv2[t] = v2; si2[t] = i2;
    __syncthreads();
    for (int o = 128; o > 0; o >>= 1) {
        if (t < o) {
            float av1 = sv1[t], av2 = sv2[t]; int ai1 = si1[t], ai2 = si2[t];
            float bv1 = sv1[t + o], bv2 = sv2[t + o]; int bi1 = si1[t + o], bi2 = si2[t + o];
            float nv1, nv2; int ni1, ni2;
            bool bfirst = (bv1 > av1) || (bv1 == av1 && bi1 < ai1);
            if (bfirst) {
                nv1 = bv1; ni1 = bi1;
                if ((av1 > bv2) || (av1 == bv2 && ai1 < bi2)) { nv2 = av1; ni2 = ai1; }
                else { nv2 = bv2; ni2 = bi2; }
            } else {
                nv1 = av1; ni1 = ai1;
                if ((bv1 > av2) || (bv1 == av2 && bi1 < ai2)) { nv2 = bv1; ni2 = bi1; }
                else { nv2 = av2; ni2 = ai2; }
            }
            sv1[t] = nv1; si1[t] = ni1; sv2[t] = nv2; si2[t] = ni2;
        }
        __syncthreads();
    }
    float gmax = sv1[0]; int gi1 = si1[0];
    float gv2  = sv2[0]; int gi2 = si2[0];

    float s = 0.f;
    for (int i = t; i < L; i += 256) {
        float e = __expf(buf[i] - gmax);
        buf[i] = e;
        s += e;
    }
    red1[t] = s;
    __syncthreads();
    for (int o = 128; o > 0; o >>= 1) {
        if (t < o) red1[t] += red1[t + o];
        __syncthreads();
    }
    float inv = 1.0f / red1[0];
    for (int i = t; i < L; i += 256)
        Pbf[(size_t)p * L + i] = f2bf(buf[i] * inv);

    int winner = gi1;
    if (gmax - gv2 < DELTA) {
        __syncthreads();
        const float* wp_ = Wf + (size_t)p * D1;
        const float* w1  = Wf + (size_t)gi1 * D1;
        const float* w2  = Wf + (size_t)gi2 * D1;
        float s1 = 0.f, s2 = 0.f;
        for (int k = t; k < D1; k += 256) { float a = wp_[k]; s1 += a * w1[k]; s2 += a * w2[k]; }
        red1[t] = s1; red2[t] = s2;
        __syncthreads();
        for (int o = 128; o > 0; o >>= 1) {
            if (t < o) { red1[t] += red1[t + o]; red2[t] += red2[t + o]; }
            __syncthreads();
        }
        if (t == 0) {
            float e1 = red1[0] * g[gi1] + (p == gi1 ? dg[gi1] : 0.f);
            float e2 = red2[0] * g[gi2] + (p == gi2 ? dg[gi2] : 0.f);
            if (e2 > e1 || (e2 == e1 && gi2 < gi1)) winner = gi2;
            out1[(size_t)(b * 2 + 0) * L + p] = (float)(winner / WS - 32);
            out1[(size_t)(b * 2 + 1) * L + p] = (float)(winner % WS - 32);
        }
    } else if (t == 0) {
        out1[(size_t)(b * 2 + 0) * L + p] = (float)(winner / WS - 32);
        out1[(size_t)(b * 2 + 1) * L + p] = (float)(winner % WS - 32);
    }
}

// K7: At[n,q] = bf16(alpha patch), transposed (batched over z)
__global__ __launch_bounds__(256) void k_buildA(const float* __restrict__ alpha,
                                                u16* __restrict__ At0, int b0) {
    int bz = blockIdx.z;
    int b  = b0 + bz;
    u16* At = At0 + (size_t)bz * SLOT_U;
    int q = blockIdx.x * 256 + threadIdx.x;
    int n = blockIdx.y;
    int hs = q >> 6, ws = q & 63;
    int c = n >> 4, ki = (n >> 2) & 3, kj = n & 3;
    int rh = refl(2 * hs + ki - 1, H);
    int rw = refl(2 * ws + kj - 1, W_);
    At[(size_t)n * L + q] = f2bf(alpha[((size_t)b * CA + c) * H * W_ + rh * W_ + rw]);
}

// K8: bf16 MFMA paste GEMM (batched over z)
__global__ __launch_bounds__(256) void k_gemm2(const u16* __restrict__ P0,
                                               const u16* __restrict__ At0,
                                               u16* __restrict__ Z0) {
    __shared__ u16 sA[128 * 32], sB[128 * 32];
    int bz = blockIdx.z;
    const u16* P  = P0  + (size_t)bz * SLOT_U;
    const u16* At = At0 + (size_t)bz * SLOT_U;
    u16* Z        = Z0  + (size_t)bz * SLOT_U;

    int tid = threadIdx.x;
    int wv = tid >> 6, lane = tid & 63;
    int pTile = blockIdx.y * 128, nTile = blockIdx.x * 128;
    int wp = (wv >> 1) * 64, wn = (wv & 1) * 64;
    int r0 = wv * 32;
    int lrow = lane >> 2, lk = (lane & 3) * 8;
    int fr = lane & 15, fq = lane >> 4;

    f32x4 acc[4][4];
#pragma unroll
    for (int mi = 0; mi < 4; ++mi)
#pragma unroll
        for (int ni = 0; ni < 4; ++ni)
#pragma unroll
            for (int r = 0; r < 4; ++r) acc[mi][ni][r] = 0.f;

    for (int k0 = 0; k0 < L; k0 += 32) {
        __syncthreads();
        const u16* gA = P + (size_t)(pTile + r0 + lrow) * L + k0 + lk;
        gll16(gA, &sA[r0 * 32]);
        gll16(gA + (size_t)16 * L, &sA[(r0 + 16) * 32]);
        const u16* gB = At + (size_t)(nTile + r0 + lrow) * L + k0 + lk;
        gll16(gB, &sB[r0 * 32]);
        gll16(gB + (size_t)16 * L, &sB[(r0 + 16) * 32]);
        __syncthreads();

        short8v a[4], bb[4];
#pragma unroll
        for (int i = 0; i < 4; ++i) {
            a[i]  = *(const short8v*)&sA[(wp + i * 16 + fr) * 32 + fq * 8];
            bb[i] = *(const short8v*)&sB[(wn + i * 16 + fr) * 32 + fq * 8];
        }
#pragma unroll
        for (int mi = 0; mi < 4; ++mi)
#pragma unroll
            for (int ni = 0; ni < 4; ++ni)
                acc[mi][ni] = __builtin_amdgcn_mfma_f32_16x16x32_bf16(a[mi], bb[ni], acc[mi][ni], 0, 0, 0);
    }

#pragma unroll
    for (int mi = 0; mi < 4; ++mi)
#pragma unroll
        for (int ni = 0; ni < 4; ++ni) {
            int n = nTile + wn + ni * 16 + fr;
#pragma unroll
            for (int r = 0; r < 4; ++r) {
                int p = pTile + wp + mi * 16 + fq * 4 + r;
                Z[(size_t)p * D2 + n] = f2bf(acc[mi][ni][r]);
            }
        }
}

// K9: transposed-conv gather -> yt[pix, c] bf16 (batched over z)
__global__ __launch_bounds__(256) void k_gather(const u16* __restrict__ Z0,
                                                u16* __restrict__ yt, int b0) {
    int bz = blockIdx.z;
    int b  = b0 + bz;
    const u16* Z = Z0 + (size_t)bz * SLOT_U;
    int c  = threadIdx.x & 127;
    int pl = threadIdx.x >> 7;
    int w  = blockIdx.x * 2 + pl;
    int h  = blockIdx.y;
    float s = 0.f;
#pragma unroll
    for (int ki = 0; ki < 4; ++ki) {
        int num = h + 1 - ki;
        if (num < 0 || (num & 1)) continue;
        int hs = num >> 1;
        if (hs >= HS) continue;
#pragma unroll
        for (int kj = 0; kj < 4; ++kj) {
            int numw = w + 1 - kj;
            if (numw < 0 || (numw & 1)) continue;
            int wsd = numw >> 1;
            if (wsd >= WS) continue;
            s += bf2f(Z[(size_t)(hs * WS + wsd) * D2 + c * 16 + ki * 4 + kj]);
        }
    }
    int pix = h * W_ + w;
    int cs = c ^ ((pix & 7) << 3);
    yt[((size_t)b * 16384 + pix) * 128 + cs] = f2bf(0.25f * s);
}

__global__ __launch_bounds__(256) void k_cvtww(const float* __restrict__ ww,
                                               u16* __restrict__ wwbf) {
    int i = blockIdx.x * 256 + threadIdx.x;
    int o = i >> 7, c = i & 127;
    wwbf[o * 128 + (c ^ ((o & 7) << 3))] = f2bf(ww[i]);
}

// K10: yw[o, gp] = sum_c w_w[o,c] * y[gp, c]   MFMA, K=128
__global__ __launch_bounds__(256) void k_ywgemm(const u16* __restrict__ wwbf,
                                                const u16* __restrict__ yt,
                                                float* __restrict__ yw) {
    __shared__ u16 sA[128 * 128], sB[128 * 128];
    int tid = threadIdx.x;
    int wv = tid >> 6, lane = tid & 63;
    int nTile = blockIdx.x * 128;
    int wp = (wv >> 1) * 64, wn = (wv & 1) * 64;
    int fr = lane & 15, fq = lane >> 4;

    const u16* gB = yt + (size_t)nTile * 128;
#pragma unroll
    for (int i = 0; i < 8; ++i) {
        int o = (i * 4 + wv) * 512;
        gll16(wwbf + o + lane * 8, &sA[o]);
        gll16(gB + o + lane * 8, &sB[o]);
    }
    __syncthreads();

    f32x4 acc[4][4];
#pragma unroll
    for (int mi = 0; mi < 4; ++mi)
#pragma unroll
        for (int ni = 0; ni < 4; ++ni)
#pragma unroll
            for (int r = 0; r < 4; ++r) acc[mi][ni][r] = 0.f;

#pragma unroll
    for (int ks = 0; ks < 4; ++ks) {
        int k0 = ks * 32 + fq * 8;
        short8v a[4], bb[4];
#pragma unroll
        for (int i = 0; i < 4; ++i) {
            int ra = wp + i * 16 + fr;
            a[i] = *(const short8v*)&sA[ra * 128 + (k0 ^ ((ra & 7) << 3))];
            int rb = wn + i * 16 + fr;
            bb[i] = *(const short8v*)&sB[rb * 128 + (k0 ^ ((rb & 7) << 3))];
        }
#pragma unroll
        for (int mi = 0; mi < 4; ++mi)
#pragma unroll
            for (int ni = 0; ni < 4; ++ni)
                acc[mi][ni] = __builtin_amdgcn_mfma_f32_16x16x32_bf16(a[mi], bb[ni], acc[mi][ni], 0, 0, 0);
    }

#pragma unroll
    for (int mi = 0; mi < 4; ++mi)
#pragma unroll
        for (int ni = 0; ni < 4; ++ni) {
            int gp = nTile + wn + ni * 16 + fr;
#pragma unroll
            for (int r = 0; r < 4; ++r) {
                int o = wp + mi * 16 + fq * 4 + r;
                yw[(size_t)o * NPIX + gp] = acc[mi][ni][r];
            }
        }
}

__global__ __launch_bounds__(256) void k_stats(const float* __restrict__ yw,
                                               float* __restrict__ meanvar) {
    int o = blockIdx.x, t = threadIdx.x;
    __shared__ float rs[256], rq[256];
    float s = 0.f, q = 0.f;
    const float* p = yw + (size_t)o * NPIX;
    for (int i = t; i < NPIX; i += 256) {
        float v = p[i];
        s += v;
        q += v * v;
    }
    rs[t] = s; rq[t] = q;
    __syncthreads();
    for (int off = 128; off > 0; off >>= 1) {
        if (t < off) { rs[t] += rs[t + off]; rq[t] += rq[t + off]; }
        __syncthreads();
    }
    if (t == 0) {
        float n = (float)NPIX;
        float mean = rs[0] / n;
        float var  = rq[0] / n - mean * mean;
        meanvar[o] = mean;
        meanvar[CA + o] = var;
    }
}

__global__ __launch_bounds__(256) void k_final(const float* __restrict__ yw,
                                               const float* __restrict__ meanvar,
                                               const float* __restrict__ gamma,
                                               const float* __restrict__ beta,
                                               const float* __restrict__ alpha,
                                               float* __restrict__ out0) {
    size_t i = ((size_t)blockIdx.x * 256 + threadIdx.x) * 4;
    int c = (int)((i >> 14) & 127);
    int b = (int)(i >> 21);
    int pix = (int)(i & 16383);
    float4 v = *(const float4*)(yw + (size_t)c * NPIX + b * 16384 + pix);
    float4 a = *(const float4*)(alpha + i);
    float mean = meanvar[c];
    float var  = meanvar[CA + c];
    float sc   = rsqrtf(var + 1e-5f) * gamma[c];
    float bt   = beta[c];
    float4 r;
    r.x = (v.x - mean) * sc + bt + a.x;
    r.y = (v.y - mean) * sc + bt + a.y;
    r.z = (v.z - mean) * sc + bt + a.z;
    r.w = (v.w - mean) * sc + bt + a.w;
    *(float4*)(out0 + i) = r;
}

extern "C" void kernel_launch(void* const* d_in, const int* in_sizes, int n_in,
                              void* d_out, int out_size, void* d_ws, size_t ws_size,
                              hipStream_t stream) {
    (void)in_sizes; (void)n_in; (void)out_size;
    const float* f     = (const float*)d_in[0];
    const float* alpha = (const float*)d_in[1];
    const float* unk   = (const float*)d_in[2];
    const float* gw    = (const float*)d_in[3];
    const float* gb    = (const float*)d_in[4];
    const float* ww    = (const float*)d_in[5];
    const float* gamma = (const float*)d_in[6];
    const float* beta  = (const float*)d_in[7];

    float* out0 = (float*)d_out;
    float* out1 = out0 + (size_t)B * CA * H * W_;
    float* out2 = out1 + (size_t)B * 2 * HS * WS;

    // ---- persistent region ----
    float* wsf = (float*)d_ws;
    size_t off = 0;
    float* fds     = wsf + off; off += (size_t)B * CM * HS * WS;  // 2,097,152
    float* ssq     = wsf + off; off += (size_t)B * HS * WS;
    float* gbuf    = wsf + off; off += (size_t)B * L;
    float* dgbuf   = wsf + off; off += (size_t)B * L;
    float* suk     = wsf + off; off += 64;
    float* ytF     = wsf + off; off += (size_t)NPIX * 128 / 2;    // 4,194,304
    float* wwbfF   = wsf + off; off += 8192;
    float* meanvar = wsf + off; off += 256;
    // ---- batch-slot region: nb slots of SLOT_F floats each ----
    float* base = wsf + off;   // off = 6,349,120

    const size_t PRE_F = off;
    int nb = 1;
    if (ws_size >= (PRE_F + 4 * SLOT_F) * 4) nb = 4;
    else if (ws_size >= (PRE_F + 2 * SLOT_F) * 4) nb = 2;

    float* ST0  = base;
    float* Wf0  = base + 16777216;
    u16*   Whi0 = (u16*)(base + 16777216 + 4718592);
    u16*   Pbf0 = (u16*)(base + 16777216 + 4718592 + 4718592);
    u16*   At0  = Whi0;          // aliases Whi/Wlo (dead after gemm1)
    u16*   Zb0  = (u16*)Wf0;     // aliases Wf (dead after softmax)
    float* yw   = ST0;           // used after batch loop
    u16*   yt   = (u16*)ytF;
    u16*   wwbf = (u16*)wwbfF;

    k_cvtww<<<64, 256, 0, stream>>>(ww, wwbf);
    k_conv_ds<<<dim3(64, 4), 256, 0, stream>>>(f, gw, gb, fds);
    k_ssq<<<dim3(64, 4), 64, 0, stream>>>(fds, ssq);
    k_scale<<<4, 256, 0, stream>>>(unk, suk, out2);
    k_gate<<<dim3(64, 4), 64, 0, stream>>>(unk, ssq, suk, gbuf, dgbuf);

    for (int b0 = 0; b0 < B; b0 += nb) {
        k_buildW<<<dim3(64, 32, nb), dim3(64, 4), 0, stream>>>(fds, Wf0, Whi0, b0);
        k_gemm1<<<dim3(528, 1, nb), 256, 0, stream>>>(Whi0, gbuf, dgbuf, ST0, b0);
        k_softmax<<<dim3(4096, nb), 256, 0, stream>>>(ST0, Pbf0, Wf0, gbuf, dgbuf, out1, b0);
        k_buildA<<<dim3(16, 2048, nb), 256, 0, stream>>>(alpha, At0, b0);
        k_gemm2<<<dim3(16, 32, nb), 256, 0, stream>>>(Pbf0, At0, Zb0);
        k_gather<<<dim3(64, 128, nb), 256, 0, stream>>>(Zb0, yt, b0);
    }

    k_ywgemm<<<512, 256, 0, stream>>>(wwbf, yt, yw);
    k_stats<<<128, 256, 0, stream>>>(yw, meanvar);
    k_final<<<8192, 256, 0, stream>>>(yw, meanvar, gamma, beta, alpha, out0);
}

// Round 5
// 1150.304 us; speedup vs baseline: 1.1215x; 1.1215x over previous
//
#include <hip/hip_runtime.h>
#include <math.h>

#define B 4
#define CG 256
#define CM 128
#define CA 128
#define H 128
#define W_ 128
#define HS 64
#define WS 64
#define L 4096
#define D1 1152
#define D2 2048
#define NPIX 65536

// slot layout (floats): [STP bf16 L*L = 8388608][Wf fp32 = 4718592][Whi+Wlo bf16 = 4718592]
#define STP_F 8388608UL
#define WF_F  4718592UL
#define SLOT_F (STP_F + WF_F + WF_F)

typedef unsigned short u16;
typedef __attribute__((ext_vector_type(8))) short short8v;
typedef __attribute__((ext_vector_type(4))) unsigned short u16x4;
typedef __attribute__((ext_vector_type(4))) float f32x4;

__device__ __forceinline__ float bf2f(u16 x) {
    union { unsigned int u; float f; } v; v.u = ((unsigned int)x) << 16; return v.f;
}
__device__ __forceinline__ u16 f2bf(float x) {
    union { float f; unsigned int u; } v; v.f = x;
    unsigned int r = (v.u + 0x7FFFu + ((v.u >> 16) & 1u)) >> 16;
    return (u16)r;
}
__device__ __forceinline__ void gll16(const void* g, void* l) {
    __builtin_amdgcn_global_load_lds((const __attribute__((address_space(1))) void*)g,
                                     (__attribute__((address_space(3))) void*)l, 16, 0, 0);
}
__device__ __forceinline__ int refl(int i, int n) {
    return i < 0 ? -i : (i >= n ? 2 * n - 2 - i : i);
}
// swizzled LDS element offset for [128][32 u16] tiles: 16B-chunk XOR
__device__ __forceinline__ int swz(int row, int fq) {
    return row * 32 + ((fq ^ ((row >> 1) & 3)) * 8);
}

// K0: f_ds = 1x1 conv at even pixels
__global__ __launch_bounds__(256) void k_conv_ds(const float* __restrict__ f,
                                                 const float* __restrict__ gw,
                                                 const float* __restrict__ gb,
                                                 float* __restrict__ fds) {
    __shared__ float sf[CG * 64];
    int t = threadIdx.x;
    int hs = blockIdx.x, b = blockIdx.y;
    const float* fb = f + (size_t)b * CG * H * W_ + (2 * hs) * W_;
    for (int idx = t; idx < CG * 64; idx += 256) {
        int ci = idx >> 6, ws = idx & 63;
        sf[idx] = fb[(size_t)ci * H * W_ + 2 * ws];
    }
    __syncthreads();
    int ws = t & 63;
    int wave = __builtin_amdgcn_readfirstlane(t >> 6);
    const float* gwp = gw + (size_t)(wave * 32) * CG;
    float acc[32];
#pragma unroll
    for (int r = 0; r < 32; ++r) acc[r] = gb[wave * 32 + r];
    for (int ci = 0; ci < CG; ++ci) {
        float fv = sf[ci * 64 + ws];
#pragma unroll
        for (int r = 0; r < 32; ++r) acc[r] += gwp[r * CG + ci] * fv;
    }
#pragma unroll
    for (int r = 0; r < 32; ++r) {
        int co = wave * 32 + r;
        fds[(((size_t)b * CM + co) * HS + hs) * WS + ws] = acc[r];
    }
}

__global__ __launch_bounds__(64) void k_ssq(const float* __restrict__ fds,
                                            float* __restrict__ ssq) {
    int ws = threadIdx.x, hs = blockIdx.x, b = blockIdx.y;
    float s = 0.f;
    for (int c = 0; c < CM; ++c) {
        float v = fds[(((size_t)b * CM + c) * HS + hs) * WS + ws];
        s += v * v;
    }
    ssq[((size_t)b * HS + hs) * WS + ws] = s;
}

__global__ __launch_bounds__(256) void k_scale(const float* __restrict__ unk,
                                               float* __restrict__ suk,
                                               float* __restrict__ out2) {
    int b = blockIdx.x, t = threadIdx.x;
    __shared__ float red[256];
    float s = 0.f;
    for (int i = t; i < L; i += 256) {
        int hs = i >> 6, ws = i & 63;
        s += unk[(size_t)b * H * W_ + (2 * hs) * W_ + 2 * ws];
    }
    red[t] = s;
    __syncthreads();
    for (int o = 128; o > 0; o >>= 1) {
        if (t < o) red[t] += red[t + o];
        __syncthreads();
    }
    if (t == 0) {
        float u = red[0] / (float)L;
        float k = 1.0f - u;
        float su = sqrtf(u / k); su = fminf(fmaxf(su, 0.1f), 10.0f);
        float sk = sqrtf(k / u); sk = fminf(fmaxf(sk, 0.1f), 10.0f);
        suk[b * 2] = su; suk[b * 2 + 1] = sk;
        out2[b * 2] = su; out2[b * 2 + 1] = sk;
    }
}

__global__ __launch_bounds__(64) void k_gate(const float* __restrict__ unk,
                                             const float* __restrict__ ssq,
                                             const float* __restrict__ suk,
                                             float* __restrict__ g,
                                             float* __restrict__ dg) {
    int ws = threadIdx.x, hs = blockIdx.x, b = blockIdx.y;
    float sm = 0.f, sq = 0.f;
    for (int di = -1; di <= 1; ++di) {
        int rh = refl(hs + di, HS);
        for (int dj = -1; dj <= 1; ++dj) {
            int rw = refl(ws + dj, WS);
            sm += unk[(size_t)b * H * W_ + (2 * rh) * W_ + 2 * rw];
            sq += ssq[((size_t)b * HS + rh) * WS + rw];
        }
    }
    float mm   = (sm > 0.0f) ? 1.0f : 0.0f;
    float norm = sqrtf(sq);
    float gate = (mm > 0.0f) ? suk[2 * b] : suk[2 * b + 1];
    int q = hs * WS + ws;
    g[(size_t)b * L + q]  = gate / fmaxf(norm, 1e-4f);
    dg[(size_t)b * L + q] = -10000.0f * mm;
}

// K4: fp32 W + bf16 hi/lo split (batched over z)
__global__ __launch_bounds__(256) void k_buildW(const float* __restrict__ fds,
                                                float* __restrict__ base, int b0) {
    int bz = blockIdx.z;
    int b  = b0 + bz;
    float* S   = base + (size_t)bz * SLOT_F;
    float* Wf  = S + STP_F;
    u16*   Whi = (u16*)(S + STP_F + WF_F);
    u16*   Wlo = Whi + (size_t)L * D1;
    int ws = threadIdx.x;
    int c  = blockIdx.y * 4 + threadIdx.y;
    int hs = blockIdx.x;
    int q = hs * WS + ws;
    size_t bo = (size_t)q * D1 + c * 9;
    const float* src = fds + ((size_t)b * CM + c) * HS * WS;
#pragma unroll
    for (int i = 0; i < 3; ++i) {
        int rh = refl(hs + i - 1, HS);
#pragma unroll
        for (int j = 0; j < 3; ++j) {
            int rw = refl(ws + j - 1, WS);
            float v = src[rh * WS + rw];
            u16 h = f2bf(v);
            Wf[bo + i * 3 + j]  = v;
            Whi[bo + i * 3 + j] = h;
            Wlo[bo + i * 3 + j] = f2bf(v - bf2f(h));
        }
    }
}

// K5: symmetric split-bf16 MFMA score GEMM -> bf16 ST (upper-tri blocks + mirror)
__global__ __launch_bounds__(256) void k_gemm1(float* __restrict__ base,
                                               const float* __restrict__ g0,
                                               const float* __restrict__ dg0,
                                               int b0) {
    __shared__ u16 sAh[128 * 32], sAl[128 * 32], sBh[128 * 32], sBl[128 * 32];
    int bz = blockIdx.z;
    float* S = base + (size_t)bz * SLOT_F;
    u16* STP = (u16*)S;
    const u16* Whi = (const u16*)(S + STP_F + WF_F);
    const u16* Wlo = Whi + (size_t)L * D1;
    const float* g  = g0  + (size_t)(b0 + bz) * L;
    const float* dg = dg0 + (size_t)(b0 + bz) * L;

    int tid = threadIdx.x;
    int wv = tid >> 6, lane = tid & 63;
    int t = blockIdx.x, I = 0;
    while (t >= 32 - I) { t -= 32 - I; ++I; }
    int J = I + t;
    int pTile = I * 128, qTile = J * 128;
    int wp = (wv >> 1) * 64, wq = (wv & 1) * 64;
    int r0 = wv * 32;
    int lrow = lane >> 2;
    int csw = ((lane & 3) ^ ((lrow >> 1) & 3)) * 8;   // pre-swizzled source chunk (elems)
    int fr = lane & 15, fq = lane >> 4;

    f32x4 acc[4][4];
#pragma unroll
    for (int mi = 0; mi < 4; ++mi)
#pragma unroll
        for (int ni = 0; ni < 4; ++ni)
#pragma unroll
            for (int r = 0; r < 4; ++r) acc[mi][ni][r] = 0.f;

    for (int k0 = 0; k0 < D1; k0 += 32) {
        __syncthreads();
        const u16* gA = Whi + (size_t)(pTile + r0 + lrow) * D1 + k0 + csw;
        gll16(gA, &sAh[r0 * 32]);
        gll16(gA + (size_t)16 * D1, &sAh[(r0 + 16) * 32]);
        const u16* gAl = Wlo + (size_t)(pTile + r0 + lrow) * D1 + k0 + csw;
        gll16(gAl, &sAl[r0 * 32]);
        gll16(gAl + (size_t)16 * D1, &sAl[(r0 + 16) * 32]);
        const u16* gB = Whi + (size_t)(qTile + r0 + lrow) * D1 + k0 + csw;
        gll16(gB, &sBh[r0 * 32]);
        gll16(gB + (size_t)16 * D1, &sBh[(r0 + 16) * 32]);
        const u16* gBl = Wlo + (size_t)(qTile + r0 + lrow) * D1 + k0 + csw;
        gll16(gBl, &sBl[r0 * 32]);
        gll16(gBl + (size_t)16 * D1, &sBl[(r0 + 16) * 32]);
        __syncthreads();

        short8v ah[4], al[4], bh[4], bl[4];
#pragma unroll
        for (int i = 0; i < 4; ++i) {
            ah[i] = *(const short8v*)&sAh[swz(wp + i * 16 + fr, fq)];
            al[i] = *(const short8v*)&sAl[swz(wp + i * 16 + fr, fq)];
            bh[i] = *(const short8v*)&sBh[swz(wq + i * 16 + fr, fq)];
            bl[i] = *(const short8v*)&sBl[swz(wq + i * 16 + fr, fq)];
        }
#pragma unroll
        for (int mi = 0; mi < 4; ++mi)
#pragma unroll
            for (int ni = 0; ni < 4; ++ni) {
                acc[mi][ni] = __builtin_amdgcn_mfma_f32_16x16x32_bf16(ah[mi], bh[ni], acc[mi][ni], 0, 0, 0);
                acc[mi][ni] = __builtin_amdgcn_mfma_f32_16x16x32_bf16(ah[mi], bl[ni], acc[mi][ni], 0, 0, 0);
                acc[mi][ni] = __builtin_amdgcn_mfma_f32_16x16x32_bf16(al[mi], bh[ni], acc[mi][ni], 0, 0, 0);
            }
    }

    // direct tile: rows p (I), cols q (J)
#pragma unroll
    for (int ni = 0; ni < 4; ++ni) {
        int qq = qTile + wq + ni * 16 + fr;
        float gq = g[qq];
        float dq = dg[qq];
#pragma unroll
        for (int mi = 0; mi < 4; ++mi) {
            int pB = pTile + wp + mi * 16 + fq * 4;
#pragma unroll
            for (int r = 0; r < 4; ++r) {
                int p = pB + r;
                float v = acc[mi][ni][r] * gq;
                if (p == qq) v += dq;
                STP[(size_t)p * L + qq] = f2bf(v);
            }
        }
    }
    // mirror tile: rows q (J), cols p (I)
    if (I != J) {
#pragma unroll
        for (int mi = 0; mi < 4; ++mi) {
            int p0 = pTile + wp + mi * 16 + fq * 4;
            float gp0 = g[p0], gp1 = g[p0 + 1], gp2 = g[p0 + 2], gp3 = g[p0 + 3];
#pragma unroll
            for (int ni = 0; ni < 4; ++ni) {
                int qq = qTile + wq + ni * 16 + fr;
                u16x4 mv;
                mv[0] = f2bf(acc[mi][ni][0] * gp0);
                mv[1] = f2bf(acc[mi][ni][1] * gp1);
                mv[2] = f2bf(acc[mi][ni][2] * gp2);
                mv[3] = f2bf(acc[mi][ni][3] * gp3);
                *(u16x4*)(STP + (size_t)qq * L + p0) = mv;
            }
        }
    }
}

// K6: softmax in-place (bf16) + exact argmax via candidate refinement
__global__ __launch_bounds__(256) void k_softmax(float* __restrict__ base,
                                                 const float* __restrict__ g0,
                                                 const float* __restrict__ dg0,
                                                 float* __restrict__ out1, int b0) {
    __shared__ float buf[L];
    __shared__ float red[256];
    __shared__ int candList[128];
    __shared__ int candCount;
    int bz = blockIdx.y;
    int b  = b0 + bz;
    float* S = base + (size_t)bz * SLOT_F;
    u16* STP = (u16*)S;
    const float* Wf = S + STP_F;
    const float* g  = g0  + (size_t)b * L;
    const float* dg = dg0 + (size_t)b * L;

    int p = blockIdx.x, t = threadIdx.x;
    u16* rowp = STP + (size_t)p * L;

    if (t == 0) candCount = 0;
    float mx = -3.4e38f;
    for (int i = t; i < L / 8; i += 256) {
        short8v v8 = ((const short8v*)rowp)[i];
#pragma unroll
        for (int j = 0; j < 8; ++j) {
            float v = bf2f((u16)v8[j]);
            buf[i * 8 + j] = v;
            mx = fmaxf(mx, v);
        }
    }
    red[t] = mx;
    __syncthreads();
    for (int o = 128; o > 0; o >>= 1) {
        if (t < o) red[t] = fmaxf(red[t], red[t + o]);
        __syncthreads();
    }
    float M = red[0];
    float u = fabsf(M) * 0.03125f + 1e-5f;   // bf16-rounding slack bound (2^-5 + floor)
    float cth = M - u;
    __syncthreads();

    float s = 0.f;
    for (int i = t; i < L; i += 256) {
        float v = buf[i];
        if (v >= cth) {
            int ix = atomicAdd(&candCount, 1);
            if (ix < 128) candList[ix] = i;
        }
        float e = __expf(v - M);
        buf[i] = e;
        s += e;
    }
    red[t] = s;
    __syncthreads();
    for (int o = 128; o > 0; o >>= 1) {
        if (t < o) red[t] += red[t + o];
        __syncthreads();
    }
    float inv = 1.0f / red[0];
    __syncthreads();

    // write-back P (in place, bf16)
    for (int i = t; i < L / 8; i += 256) {
        short8v o8;
#pragma unroll
        for (int j = 0; j < 8; ++j) o8[j] = (short)f2bf(buf[i * 8 + j] * inv);
        ((short8v*)rowp)[i] = o8;
    }
    __syncthreads();

    int nc = candCount; if (nc > 128) nc = 128;
    int bestI;
    if (nc == 1) {
        bestI = candList[0];
    } else {
        float bestE = -3.4e38f; bestI = L;
        const float* wp_ = Wf + (size_t)p * D1;
        for (int k = 0; k < nc; ++k) {
            int cand = candList[k];
            const float* wc = Wf + (size_t)cand * D1;
            float part = 0.f;
            for (int j = t; j < D1; j += 256) part += wp_[j] * wc[j];
            red[t] = part;
            __syncthreads();
            for (int o = 128; o > 0; o >>= 1) {
                if (t < o) red[t] += red[t + o];
                __syncthreads();
            }
            float e1 = red[0] * g[cand] + (p == cand ? dg[cand] : 0.f);
            if (e1 > bestE || (e1 == bestE && cand < bestI)) { bestE = e1; bestI = cand; }
            __syncthreads();
        }
    }
    if (t == 0) {
        out1[(size_t)(b * 2 + 0) * L + p] = (float)(bestI / WS - 32);
        out1[(size_t)(b * 2 + 1) * L + p] = (float)(bestI % WS - 32);
    }
}

// K7: At[n,q] = bf16(alpha patch), transposed (batched over z)
__global__ __launch_bounds__(256) void k_buildA(const float* __restrict__ alpha,
                                                float* __restrict__ base, int b0) {
    int bz = blockIdx.z;
    int b  = b0 + bz;
    u16* At = (u16*)(base + (size_t)bz * SLOT_F + STP_F + WF_F);
    int q = blockIdx.x * 256 + threadIdx.x;
    int n = blockIdx.y;
    int hs = q >> 6, ws = q & 63;
    int c = n >> 4, ki = (n >> 2) & 3, kj = n & 3;
    int rh = refl(2 * hs + ki - 1, H);
    int rw = refl(2 * ws + kj - 1, W_);
    At[(size_t)n * L + q] = f2bf(alpha[((size_t)b * CA + c) * H * W_ + rh * W_ + rw]);
}

// K8: bf16 MFMA paste GEMM (batched over z): Z[p,n] = sum_q P[p,q]*At[n,q]
__global__ __launch_bounds__(256) void k_gemm2(float* __restrict__ base) {
    __shared__ u16 sA[128 * 32], sB[128 * 32];
    int bz = blockIdx.z;
    float* S = base + (size_t)bz * SLOT_F;
    const u16* P  = (const u16*)S;
    const u16* At = (const u16*)(S + STP_F + WF_F);
    u16* Z        = (u16*)(S + STP_F);

    int tid = threadIdx.x;
    int wv = tid >> 6, lane = tid & 63;
    int pTile = blockIdx.y * 128, nTile = blockIdx.x * 128;
    int wp = (wv >> 1) * 64, wn = (wv & 1) * 64;
    int r0 = wv * 32;
    int lrow = lane >> 2;
    int csw = ((lane & 3) ^ ((lrow >> 1) & 3)) * 8;
    int fr = lane & 15, fq = lane >> 4;

    f32x4 acc[4][4];
#pragma unroll
    for (int mi = 0; mi < 4; ++mi)
#pragma unroll
        for (int ni = 0; ni < 4; ++ni)
#pragma unroll
            for (int r = 0; r < 4; ++r) acc[mi][ni][r] = 0.f;

    for (int k0 = 0; k0 < L; k0 += 32) {
        __syncthreads();
        const u16* gA = P + (size_t)(pTile + r0 + lrow) * L + k0 + csw;
        gll16(gA, &sA[r0 * 32]);
        gll16(gA + (size_t)16 * L, &sA[(r0 + 16) * 32]);
        const u16* gB = At + (size_t)(nTile + r0 + lrow) * L + k0 + csw;
        gll16(gB, &sB[r0 * 32]);
        gll16(gB + (size_t)16 * L, &sB[(r0 + 16) * 32]);
        __syncthreads();

        short8v a[4], bb[4];
#pragma unroll
        for (int i = 0; i < 4; ++i) {
            a[i]  = *(const short8v*)&sA[swz(wp + i * 16 + fr, fq)];
            bb[i] = *(const short8v*)&sB[swz(wn + i * 16 + fr, fq)];
        }
#pragma unroll
        for (int mi = 0; mi < 4; ++mi)
#pragma unroll
            for (int ni = 0; ni < 4; ++ni)
                acc[mi][ni] = __builtin_amdgcn_mfma_f32_16x16x32_bf16(a[mi], bb[ni], acc[mi][ni], 0, 0, 0);
    }

#pragma unroll
    for (int mi = 0; mi < 4; ++mi)
#pragma unroll
        for (int ni = 0; ni < 4; ++ni) {
            int n = nTile + wn + ni * 16 + fr;
#pragma unroll
            for (int r = 0; r < 4; ++r) {
                int p = pTile + wp + mi * 16 + fq * 4 + r;
                Z[(size_t)p * D2 + n] = f2bf(acc[mi][ni][r]);
            }
        }
}

// K9: transposed-conv gather -> yt[pix, c] bf16 (batched over z)
__global__ __launch_bounds__(256) void k_gather(float* __restrict__ base,
                                                u16* __restrict__ yt, int b0) {
    int bz = blockIdx.z;
    int b  = b0 + bz;
    const u16* Z = (const u16*)(base + (size_t)bz * SLOT_F + STP_F);
    int c  = threadIdx.x & 127;
    int pl = threadIdx.x >> 7;
    int w  = blockIdx.x * 2 + pl;
    int h  = blockIdx.y;
    float s = 0.f;
#pragma unroll
    for (int ki = 0; ki < 4; ++ki) {
        int num = h + 1 - ki;
        if (num < 0 || (num & 1)) continue;
        int hs = num >> 1;
        if (hs >= HS) continue;
#pragma unroll
        for (int kj = 0; kj < 4; ++kj) {
            int numw = w + 1 - kj;
            if (numw < 0 || (numw & 1)) continue;
            int wsd = numw >> 1;
            if (wsd >= WS) continue;
            s += bf2f(Z[(size_t)(hs * WS + wsd) * D2 + c * 16 + ki * 4 + kj]);
        }
    }
    int pix = h * W_ + w;
    int cs = c ^ ((pix & 7) << 3);
    yt[((size_t)b * 16384 + pix) * 128 + cs] = f2bf(0.25f * s);
}

__global__ __launch_bounds__(256) void k_cvtww(const float* __restrict__ ww,
                                               u16* __restrict__ wwbf) {
    int i = blockIdx.x * 256 + threadIdx.x;
    int o = i >> 7, c = i & 127;
    wwbf[o * 128 + (c ^ ((o & 7) << 3))] = f2bf(ww[i]);
}

// K10: yw[o, gp] = sum_c w_w[o,c] * y[gp, c]   MFMA, K=128
__global__ __launch_bounds__(256) void k_ywgemm(const u16* __restrict__ wwbf,
                                                const u16* __restrict__ yt,
                                                float* __restrict__ yw) {
    __shared__ u16 sA[128 * 128], sB[128 * 128];
    int tid = threadIdx.x;
    int wv = tid >> 6, lane = tid & 63;
    int nTile = blockIdx.x * 128;
    int wp = (wv >> 1) * 64, wn = (wv & 1) * 64;
    int fr = lane & 15, fq = lane >> 4;

    const u16* gB = yt + (size_t)nTile * 128;
#pragma unroll
    for (int i = 0; i < 8; ++i) {
        int o = (i * 4 + wv) * 512;
        gll16(wwbf + o + lane * 8, &sA[o]);
        gll16(gB + o + lane * 8, &sB[o]);
    }
    __syncthreads();

    f32x4 acc[4][4];
#pragma unroll
    for (int mi = 0; mi < 4; ++mi)
#pragma unroll
        for (int ni = 0; ni < 4; ++ni)
#pragma unroll
            for (int r = 0; r < 4; ++r) acc[mi][ni][r] = 0.f;

#pragma unroll
    for (int ks = 0; ks < 4; ++ks) {
        int k0 = ks * 32 + fq * 8;
        short8v a[4], bb[4];
#pragma unroll
        for (int i = 0; i < 4; ++i) {
            int ra = wp + i * 16 + fr;
            a[i] = *(const short8v*)&sA[ra * 128 + (k0 ^ ((ra & 7) << 3))];
            int rb = wn + i * 16 + fr;
            bb[i] = *(const short8v*)&sB[rb * 128 + (k0 ^ ((rb & 7) << 3))];
        }
#pragma unroll
        for (int mi = 0; mi < 4; ++mi)
#pragma unroll
            for (int ni = 0; ni < 4; ++ni)
                acc[mi][ni] = __builtin_amdgcn_mfma_f32_16x16x32_bf16(a[mi], bb[ni], acc[mi][ni], 0, 0, 0);
    }

#pragma unroll
    for (int mi = 0; mi < 4; ++mi)
#pragma unroll
        for (int ni = 0; ni < 4; ++ni) {
            int gp = nTile + wn + ni * 16 + fr;
#pragma unroll
            for (int r = 0; r < 4; ++r) {
                int o = wp + mi * 16 + fq * 4 + r;
                yw[(size_t)o * NPIX + gp] = acc[mi][ni][r];
            }
        }
}

__global__ __launch_bounds__(256) void k_stats(const float* __restrict__ yw,
                                               float* __restrict__ meanvar) {
    int o = blockIdx.x, t = threadIdx.x;
    __shared__ float rs[256], rq[256];
    float s = 0.f, q = 0.f;
    const float* p = yw + (size_t)o * NPIX;
    for (int i = t; i < NPIX; i += 256) {
        float v = p[i];
        s += v;
        q += v * v;
    }
    rs[t] = s; rq[t] = q;
    __syncthreads();
    for (int off = 128; off > 0; off >>= 1) {
        if (t < off) { rs[t] += rs[t + off]; rq[t] += rq[t + off]; }
        __syncthreads();
    }
    if (t == 0) {
        float n = (float)NPIX;
        float mean = rs[0] / n;
        float var  = rq[0] / n - mean * mean;
        meanvar[o] = mean;
        meanvar[CA + o] = var;
    }
}

__global__ __launch_bounds__(256) void k_final(const float* __restrict__ yw,
                                               const float* __restrict__ meanvar,
                                               const float* __restrict__ gamma,
                                               const float* __restrict__ beta,
                                               const float* __restrict__ alpha,
                                               float* __restrict__ out0) {
    size_t i = ((size_t)blockIdx.x * 256 + threadIdx.x) * 4;
    int c = (int)((i >> 14) & 127);
    int b = (int)(i >> 21);
    int pix = (int)(i & 16383);
    float4 v = *(const float4*)(yw + (size_t)c * NPIX + b * 16384 + pix);
    float4 a = *(const float4*)(alpha + i);
    float mean = meanvar[c];
    float var  = meanvar[CA + c];
    float sc   = rsqrtf(var + 1e-5f) * gamma[c];
    float bt   = beta[c];
    float4 r;
    r.x = (v.x - mean) * sc + bt + a.x;
    r.y = (v.y - mean) * sc + bt + a.y;
    r.z = (v.z - mean) * sc + bt + a.z;
    r.w = (v.w - mean) * sc + bt + a.w;
    *(float4*)(out0 + i) = r;
}

extern "C" void kernel_launch(void* const* d_in, const int* in_sizes, int n_in,
                              void* d_out, int out_size, void* d_ws, size_t ws_size,
                              hipStream_t stream) {
    (void)in_sizes; (void)n_in; (void)out_size;
    const float* f     = (const float*)d_in[0];
    const float* alpha = (const float*)d_in[1];
    const float* unk   = (const float*)d_in[2];
    const float* gw    = (const float*)d_in[3];
    const float* gb    = (const float*)d_in[4];
    const float* ww    = (const float*)d_in[5];
    const float* gamma = (const float*)d_in[6];
    const float* beta  = (const float*)d_in[7];

    float* out0 = (float*)d_out;
    float* out1 = out0 + (size_t)B * CA * H * W_;
    float* out2 = out1 + (size_t)B * 2 * HS * WS;

    // ---- persistent region ----
    float* wsf = (float*)d_ws;
    size_t off = 0;
    float* fds     = wsf + off; off += (size_t)B * CM * HS * WS;  // 2,097,152
    float* ssq     = wsf + off; off += (size_t)B * HS * WS;
    float* gbuf    = wsf + off; off += (size_t)B * L;
    float* dgbuf   = wsf + off; off += (size_t)B * L;
    float* suk     = wsf + off; off += 64;
    float* ytF     = wsf + off; off += (size_t)NPIX * 128 / 2;    // 4,194,304
    float* wwbfF   = wsf + off; off += 8192;
    float* meanvar = wsf + off; off += 256;
    float* base    = wsf + off;                                   // slots

    const size_t PRE_F = off;
    int nb = (ws_size >= (PRE_F + 4 * SLOT_F) * sizeof(float)) ? 4 : 2;  // nb=2 fits in 168MB (ws >= ~210MB proven)

    float* yw   = base;          // fp32 [128][NPIX], used after batch loop (aliases slot0 STP)
    u16*   yt   = (u16*)ytF;
    u16*   wwbf = (u16*)wwbfF;

    k_cvtww<<<64, 256, 0, stream>>>(ww, wwbf);
    k_conv_ds<<<dim3(64, 4), 256, 0, stream>>>(f, gw, gb, fds);
    k_ssq<<<dim3(64, 4), 64, 0, stream>>>(fds, ssq);
    k_scale<<<4, 256, 0, stream>>>(unk, suk, out2);
    k_gate<<<dim3(64, 4), 64, 0, stream>>>(unk, ssq, suk, gbuf, dgbuf);

    for (int b0 = 0; b0 < B; b0 += nb) {
        k_buildW<<<dim3(64, 32, nb), dim3(64, 4), 0, stream>>>(fds, base, b0);
        k_gemm1<<<dim3(528, 1, nb), 256, 0, stream>>>(base, gbuf, dgbuf, b0);
        k_softmax<<<dim3(4096, nb), 256, 0, stream>>>(base, gbuf, dgbuf, out1, b0);
        k_buildA<<<dim3(16, 2048, nb), 256, 0, stream>>>(alpha, base, b0);
        k_gemm2<<<dim3(16, 32, nb), 256, 0, stream>>>(base);
        k_gather<<<dim3(64, 128, nb), 256, 0, stream>>>(base, yt, b0);
    }

    k_ywgemm<<<512, 256, 0, stream>>>(wwbf, yt, yw);
    k_stats<<<128, 256, 0, stream>>>(yw, meanvar);
    k_final<<<8192, 256, 0, stream>>>(yw, meanvar, gamma, beta, alpha, out0);
}

// Round 6
// 1014.274 us; speedup vs baseline: 1.2719x; 1.1341x over previous
//
#include <hip/hip_runtime.h>
#include <math.h>

#define B 4
#define CG 256
#define CM 128
#define CA 128
#define H 128
#define W_ 128
#define HS 64
#define WS 64
#define L 4096
#define D1 1152
#define D2 2048
#define NPIX 65536

// slot layout (floats): [STP bf16 L*L][Wf fp32 -> At bf16][Whi bf16 -> Z bf16]
#define STP_F 8388608UL
#define WF_F  4718592UL
#define ZB_F  4194304UL
#define SLOT_F (STP_F + WF_F + ZB_F)   // 17,301,504 floats = 69.2 MB

typedef unsigned short u16;
typedef __attribute__((ext_vector_type(8))) short short8v;
typedef __attribute__((ext_vector_type(4))) unsigned short u16x4;
typedef __attribute__((ext_vector_type(4))) float f32x4;

__device__ __forceinline__ float bf2f(u16 x) {
    union { unsigned int u; float f; } v; v.u = ((unsigned int)x) << 16; return v.f;
}
__device__ __forceinline__ u16 f2bf(float x) {
    union { float f; unsigned int u; } v; v.f = x;
    unsigned int r = (v.u + 0x7FFFu + ((v.u >> 16) & 1u)) >> 16;
    return (u16)r;
}
__device__ __forceinline__ void gll16(const void* g, void* l) {
    __builtin_amdgcn_global_load_lds((const __attribute__((address_space(1))) void*)g,
                                     (__attribute__((address_space(3))) void*)l, 16, 0, 0);
}
__device__ __forceinline__ int refl(int i, int n) {
    return i < 0 ? -i : (i >= n ? 2 * n - 2 - i : i);
}
// swizzled LDS element offset for [128][32 u16] tiles: 16B-chunk XOR
__device__ __forceinline__ int swz(int row, int fq) {
    return row * 32 + ((fq ^ ((row >> 1) & 3)) * 8);
}

// K0: f_ds = 1x1 conv at even pixels
__global__ __launch_bounds__(256) void k_conv_ds(const float* __restrict__ f,
                                                 const float* __restrict__ gw,
                                                 const float* __restrict__ gb,
                                                 float* __restrict__ fds) {
    __shared__ float sf[CG * 64];
    int t = threadIdx.x;
    int hs = blockIdx.x, b = blockIdx.y;
    const float* fb = f + (size_t)b * CG * H * W_ + (2 * hs) * W_;
    for (int idx = t; idx < CG * 64; idx += 256) {
        int ci = idx >> 6, ws = idx & 63;
        sf[idx] = fb[(size_t)ci * H * W_ + 2 * ws];
    }
    __syncthreads();
    int ws = t & 63;
    int wave = __builtin_amdgcn_readfirstlane(t >> 6);
    const float* gwp = gw + (size_t)(wave * 32) * CG;
    float acc[32];
#pragma unroll
    for (int r = 0; r < 32; ++r) acc[r] = gb[wave * 32 + r];
    for (int ci = 0; ci < CG; ++ci) {
        float fv = sf[ci * 64 + ws];
#pragma unroll
        for (int r = 0; r < 32; ++r) acc[r] += gwp[r * CG + ci] * fv;
    }
#pragma unroll
    for (int r = 0; r < 32; ++r) {
        int co = wave * 32 + r;
        fds[(((size_t)b * CM + co) * HS + hs) * WS + ws] = acc[r];
    }
}

__global__ __launch_bounds__(64) void k_ssq(const float* __restrict__ fds,
                                            float* __restrict__ ssq) {
    int ws = threadIdx.x, hs = blockIdx.x, b = blockIdx.y;
    float s = 0.f;
    for (int c = 0; c < CM; ++c) {
        float v = fds[(((size_t)b * CM + c) * HS + hs) * WS + ws];
        s += v * v;
    }
    ssq[((size_t)b * HS + hs) * WS + ws] = s;
}

__global__ __launch_bounds__(256) void k_scale(const float* __restrict__ unk,
                                               float* __restrict__ suk,
                                               float* __restrict__ out2) {
    int b = blockIdx.x, t = threadIdx.x;
    __shared__ float red[256];
    float s = 0.f;
    for (int i = t; i < L; i += 256) {
        int hs = i >> 6, ws = i & 63;
        s += unk[(size_t)b * H * W_ + (2 * hs) * W_ + 2 * ws];
    }
    red[t] = s;
    __syncthreads();
    for (int o = 128; o > 0; o >>= 1) {
        if (t < o) red[t] += red[t + o];
        __syncthreads();
    }
    if (t == 0) {
        float u = red[0] / (float)L;
        float k = 1.0f - u;
        float su = sqrtf(u / k); su = fminf(fmaxf(su, 0.1f), 10.0f);
        float sk = sqrtf(k / u); sk = fminf(fmaxf(sk, 0.1f), 10.0f);
        suk[b * 2] = su; suk[b * 2 + 1] = sk;
        out2[b * 2] = su; out2[b * 2 + 1] = sk;
    }
}

__global__ __launch_bounds__(64) void k_gate(const float* __restrict__ unk,
                                             const float* __restrict__ ssq,
                                             const float* __restrict__ suk,
                                             float* __restrict__ g,
                                             float* __restrict__ dg) {
    int ws = threadIdx.x, hs = blockIdx.x, b = blockIdx.y;
    float sm = 0.f, sq = 0.f;
    for (int di = -1; di <= 1; ++di) {
        int rh = refl(hs + di, HS);
        for (int dj = -1; dj <= 1; ++dj) {
            int rw = refl(ws + dj, WS);
            sm += unk[(size_t)b * H * W_ + (2 * rh) * W_ + 2 * rw];
            sq += ssq[((size_t)b * HS + rh) * WS + rw];
        }
    }
    float mm   = (sm > 0.0f) ? 1.0f : 0.0f;
    float norm = sqrtf(sq);
    float gate = (mm > 0.0f) ? suk[2 * b] : suk[2 * b + 1];
    int q = hs * WS + ws;
    g[(size_t)b * L + q]  = gate / fmaxf(norm, 1e-4f);
    dg[(size_t)b * L + q] = -10000.0f * mm;
}

// K4: fp32 W + bf16 W (batched over z)
__global__ __launch_bounds__(256) void k_buildW(const float* __restrict__ fds,
                                                float* __restrict__ base, int b0) {
    int bz = blockIdx.z;
    int b  = b0 + bz;
    float* S   = base + (size_t)bz * SLOT_F;
    float* Wf  = S + STP_F;
    u16*   Whi = (u16*)(S + STP_F + WF_F);
    int ws = threadIdx.x;
    int c  = blockIdx.y * 4 + threadIdx.y;
    int hs = blockIdx.x;
    int q = hs * WS + ws;
    size_t bo = (size_t)q * D1 + c * 9;
    const float* src = fds + ((size_t)b * CM + c) * HS * WS;
#pragma unroll
    for (int i = 0; i < 3; ++i) {
        int rh = refl(hs + i - 1, HS);
#pragma unroll
        for (int j = 0; j < 3; ++j) {
            int rw = refl(ws + j - 1, WS);
            float v = src[rh * WS + rw];
            Wf[bo + i * 3 + j]  = v;
            Whi[bo + i * 3 + j] = f2bf(v);
        }
    }
}

// K5: symmetric bf16 MFMA score GEMM -> bf16 ST (upper-tri blocks + mirror)
__global__ __launch_bounds__(256) void k_gemm1(float* __restrict__ base,
                                               const float* __restrict__ g0,
                                               const float* __restrict__ dg0,
                                               int b0) {
    __shared__ u16 sAh[128 * 32], sBh[128 * 32];
    int bz = blockIdx.z;
    float* S = base + (size_t)bz * SLOT_F;
    u16* STP = (u16*)S;
    const u16* Whi = (const u16*)(S + STP_F + WF_F);
    const float* g  = g0  + (size_t)(b0 + bz) * L;
    const float* dg = dg0 + (size_t)(b0 + bz) * L;

    int tid = threadIdx.x;
    int wv = tid >> 6, lane = tid & 63;
    int t = blockIdx.x, I = 0;
    while (t >= 32 - I) { t -= 32 - I; ++I; }
    int J = I + t;
    int pTile = I * 128, qTile = J * 128;
    int wp = (wv >> 1) * 64, wq = (wv & 1) * 64;
    int r0 = wv * 32;
    int lrow = lane >> 2;
    int csw = ((lane & 3) ^ ((lrow >> 1) & 3)) * 8;   // pre-swizzled source chunk (elems)
    int fr = lane & 15, fq = lane >> 4;

    f32x4 acc[4][4];
#pragma unroll
    for (int mi = 0; mi < 4; ++mi)
#pragma unroll
        for (int ni = 0; ni < 4; ++ni)
#pragma unroll
            for (int r = 0; r < 4; ++r) acc[mi][ni][r] = 0.f;

    for (int k0 = 0; k0 < D1; k0 += 32) {
        __syncthreads();
        const u16* gA = Whi + (size_t)(pTile + r0 + lrow) * D1 + k0 + csw;
        gll16(gA, &sAh[r0 * 32]);
        gll16(gA + (size_t)16 * D1, &sAh[(r0 + 16) * 32]);
        const u16* gB = Whi + (size_t)(qTile + r0 + lrow) * D1 + k0 + csw;
        gll16(gB, &sBh[r0 * 32]);
        gll16(gB + (size_t)16 * D1, &sBh[(r0 + 16) * 32]);
        __syncthreads();

        short8v ah[4], bh[4];
#pragma unroll
        for (int i = 0; i < 4; ++i) {
            ah[i] = *(const short8v*)&sAh[swz(wp + i * 16 + fr, fq)];
            bh[i] = *(const short8v*)&sBh[swz(wq + i * 16 + fr, fq)];
        }
#pragma unroll
        for (int mi = 0; mi < 4; ++mi)
#pragma unroll
            for (int ni = 0; ni < 4; ++ni)
                acc[mi][ni] = __builtin_amdgcn_mfma_f32_16x16x32_bf16(ah[mi], bh[ni], acc[mi][ni], 0, 0, 0);
    }

    // direct tile: rows p (I), cols q (J)
#pragma unroll
    for (int ni = 0; ni < 4; ++ni) {
        int qq = qTile + wq + ni * 16 + fr;
        float gq = g[qq];
        float dq = dg[qq];
#pragma unroll
        for (int mi = 0; mi < 4; ++mi) {
            int pB = pTile + wp + mi * 16 + fq * 4;
#pragma unroll
            for (int r = 0; r < 4; ++r) {
                int p = pB + r;
                float v = acc[mi][ni][r] * gq;
                if (p == qq) v += dq;
                STP[(size_t)p * L + qq] = f2bf(v);
            }
        }
    }
    // mirror tile: rows q (J), cols p (I)
    if (I != J) {
#pragma unroll
        for (int mi = 0; mi < 4; ++mi) {
            int p0 = pTile + wp + mi * 16 + fq * 4;
            float gp0 = g[p0], gp1 = g[p0 + 1], gp2 = g[p0 + 2], gp3 = g[p0 + 3];
#pragma unroll
            for (int ni = 0; ni < 4; ++ni) {
                int qq = qTile + wq + ni * 16 + fr;
                u16x4 mv;
                mv[0] = f2bf(acc[mi][ni][0] * gp0);
                mv[1] = f2bf(acc[mi][ni][1] * gp1);
                mv[2] = f2bf(acc[mi][ni][2] * gp2);
                mv[3] = f2bf(acc[mi][ni][3] * gp3);
                *(u16x4*)(STP + (size_t)qq * L + p0) = mv;
            }
        }
    }
}

// K6: softmax in-place (bf16) + exact argmax via candidate refinement
__global__ __launch_bounds__(256) void k_softmax(float* __restrict__ base,
                                                 const float* __restrict__ g0,
                                                 const float* __restrict__ dg0,
                                                 float* __restrict__ out1, int b0) {
    __shared__ float buf[L];
    __shared__ float red[256];
    __shared__ int candList[128];
    __shared__ int candCount;
    int bz = blockIdx.y;
    int b  = b0 + bz;
    float* S = base + (size_t)bz * SLOT_F;
    u16* STP = (u16*)S;
    const float* Wf = S + STP_F;
    const float* g  = g0  + (size_t)b * L;
    const float* dg = dg0 + (size_t)b * L;

    int p = blockIdx.x, t = threadIdx.x;
    u16* rowp = STP + (size_t)p * L;

    if (t == 0) candCount = 0;
    float mx = -3.4e38f;
    for (int i = t; i < L / 8; i += 256) {
        short8v v8 = ((const short8v*)rowp)[i];
#pragma unroll
        for (int j = 0; j < 8; ++j) {
            float v = bf2f((u16)v8[j]);
            buf[i * 8 + j] = v;
            mx = fmaxf(mx, v);
        }
    }
    red[t] = mx;
    __syncthreads();
    for (int o = 128; o > 0; o >>= 1) {
        if (t < o) red[t] = fmaxf(red[t], red[t + o]);
        __syncthreads();
    }
    float M = red[0];
    float u = fabsf(M) * 0.0625f + 1e-5f;   // window covers bf16 storage + hi-only MFMA error (30x margin)
    float cth = M - u;
    __syncthreads();

    float s = 0.f;
    for (int i = t; i < L; i += 256) {
        float v = buf[i];
        if (v >= cth) {
            int ix = atomicAdd(&candCount, 1);
            if (ix < 128) candList[ix] = i;
        }
        float e = __expf(v - M);
        buf[i] = e;
        s += e;
    }
    red[t] = s;
    __syncthreads();
    for (int o = 128; o > 0; o >>= 1) {
        if (t < o) red[t] += red[t + o];
        __syncthreads();
    }
    float inv = 1.0f / red[0];
    __syncthreads();

    // write-back P (in place, bf16)
    for (int i = t; i < L / 8; i += 256) {
        short8v o8;
#pragma unroll
        for (int j = 0; j < 8; ++j) o8[j] = (short)f2bf(buf[i * 8 + j] * inv);
        ((short8v*)rowp)[i] = o8;
    }
    __syncthreads();

    int nc = candCount; if (nc > 128) nc = 128;
    int bestI;
    if (nc == 1) {
        bestI = candList[0];
    } else {
        float bestE = -3.4e38f; bestI = L;
        const float* wp_ = Wf + (size_t)p * D1;
        for (int k = 0; k < nc; ++k) {
            int cand = candList[k];
            const float* wc = Wf + (size_t)cand * D1;
            float part = 0.f;
            for (int j = t; j < D1; j += 256) part += wp_[j] * wc[j];
            red[t] = part;
            __syncthreads();
            for (int o = 128; o > 0; o >>= 1) {
                if (t < o) red[t] += red[t + o];
                __syncthreads();
            }
            float e1 = red[0] * g[cand] + (p == cand ? dg[cand] : 0.f);
            if (e1 > bestE || (e1 == bestE && cand < bestI)) { bestE = e1; bestI = cand; }
            __syncthreads();
        }
    }
    if (t == 0) {
        out1[(size_t)(b * 2 + 0) * L + p] = (float)(bestI / WS - 32);
        out1[(size_t)(b * 2 + 1) * L + p] = (float)(bestI % WS - 32);
    }
}

// K7: At[n,q] = bf16(alpha patch), transposed (overwrites Wf region; batched over z)
__global__ __launch_bounds__(256) void k_buildA(const float* __restrict__ alpha,
                                                float* __restrict__ base, int b0) {
    int bz = blockIdx.z;
    int b  = b0 + bz;
    u16* At = (u16*)(base + (size_t)bz * SLOT_F + STP_F);
    int q = blockIdx.x * 256 + threadIdx.x;
    int n = blockIdx.y;
    int hs = q >> 6, ws = q & 63;
    int c = n >> 4, ki = (n >> 2) & 3, kj = n & 3;
    int rh = refl(2 * hs + ki - 1, H);
    int rw = refl(2 * ws + kj - 1, W_);
    At[(size_t)n * L + q] = f2bf(alpha[((size_t)b * CA + c) * H * W_ + rh * W_ + rw]);
}

// K8: bf16 MFMA paste GEMM (batched over z): Z[p,n] = sum_q P[p,q]*At[n,q]
__global__ __launch_bounds__(256) void k_gemm2(float* __restrict__ base) {
    __shared__ u16 sA[128 * 32], sB[128 * 32];
    int bz = blockIdx.z;
    float* S = base + (size_t)bz * SLOT_F;
    const u16* P  = (const u16*)S;
    const u16* At = (const u16*)(S + STP_F);
    u16* Z        = (u16*)(S + STP_F + WF_F);

    int tid = threadIdx.x;
    int wv = tid >> 6, lane = tid & 63;
    int pTile = blockIdx.y * 128, nTile = blockIdx.x * 128;
    int wp = (wv >> 1) * 64, wn = (wv & 1) * 64;
    int r0 = wv * 32;
    int lrow = lane >> 2;
    int csw = ((lane & 3) ^ ((lrow >> 1) & 3)) * 8;
    int fr = lane & 15, fq = lane >> 4;

    f32x4 acc[4][4];
#pragma unroll
    for (int mi = 0; mi < 4; ++mi)
#pragma unroll
        for (int ni = 0; ni < 4; ++ni)
#pragma unroll
            for (int r = 0; r < 4; ++r) acc[mi][ni][r] = 0.f;

    for (int k0 = 0; k0 < L; k0 += 32) {
        __syncthreads();
        const u16* gA = P + (size_t)(pTile + r0 + lrow) * L + k0 + csw;
        gll16(gA, &sA[r0 * 32]);
        gll16(gA + (size_t)16 * L, &sA[(r0 + 16) * 32]);
        const u16* gB = At + (size_t)(nTile + r0 + lrow) * L + k0 + csw;
        gll16(gB, &sB[r0 * 32]);
        gll16(gB + (size_t)16 * L, &sB[(r0 + 16) * 32]);
        __syncthreads();

        short8v a[4], bb[4];
#pragma unroll
        for (int i = 0; i < 4; ++i) {
            a[i]  = *(const short8v*)&sA[swz(wp + i * 16 + fr, fq)];
            bb[i] = *(const short8v*)&sB[swz(wn + i * 16 + fr, fq)];
        }
#pragma unroll
        for (int mi = 0; mi < 4; ++mi)
#pragma unroll
            for (int ni = 0; ni < 4; ++ni)
                acc[mi][ni] = __builtin_amdgcn_mfma_f32_16x16x32_bf16(a[mi], bb[ni], acc[mi][ni], 0, 0, 0);
    }

#pragma unroll
    for (int mi = 0; mi < 4; ++mi)
#pragma unroll
        for (int ni = 0; ni < 4; ++ni) {
            int n = nTile + wn + ni * 16 + fr;
#pragma unroll
            for (int r = 0; r < 4; ++r) {
                int p = pTile + wp + mi * 16 + fq * 4 + r;
                Z[(size_t)p * D2 + n] = f2bf(acc[mi][ni][r]);
            }
        }
}

// K9: transposed-conv gather -> yt[pix, c] bf16 (batched over z)
__global__ __launch_bounds__(256) void k_gather(float* __restrict__ base,
                                                u16* __restrict__ yt, int b0) {
    int bz = blockIdx.z;
    int b  = b0 + bz;
    const u16* Z = (const u16*)(base + (size_t)bz * SLOT_F + STP_F + WF_F);
    int c  = threadIdx.x & 127;
    int pl = threadIdx.x >> 7;
    int w  = blockIdx.x * 2 + pl;
    int h  = blockIdx.y;
    float s = 0.f;
#pragma unroll
    for (int ki = 0; ki < 4; ++ki) {
        int num = h + 1 - ki;
        if (num < 0 || (num & 1)) continue;
        int hs = num >> 1;
        if (hs >= HS) continue;
#pragma unroll
        for (int kj = 0; kj < 4; ++kj) {
            int numw = w + 1 - kj;
            if (numw < 0 || (numw & 1)) continue;
            int wsd = numw >> 1;
            if (wsd >= WS) continue;
            s += bf2f(Z[(size_t)(hs * WS + wsd) * D2 + c * 16 + ki * 4 + kj]);
        }
    }
    int pix = h * W_ + w;
    int cs = c ^ ((pix & 7) << 3);
    yt[((size_t)b * 16384 + pix) * 128 + cs] = f2bf(0.25f * s);
}

__global__ __launch_bounds__(256) void k_cvtww(const float* __restrict__ ww,
                                               u16* __restrict__ wwbf) {
    int i = blockIdx.x * 256 + threadIdx.x;
    int o = i >> 7, c = i & 127;
    wwbf[o * 128 + (c ^ ((o & 7) << 3))] = f2bf(ww[i]);
}

// K10: yw[o, gp] = sum_c w_w[o,c] * y[gp, c]   MFMA, K=128
__global__ __launch_bounds__(256) void k_ywgemm(const u16* __restrict__ wwbf,
                                                const u16* __restrict__ yt,
                                                float* __restrict__ yw) {
    __shared__ u16 sA[128 * 128], sB[128 * 128];
    int tid = threadIdx.x;
    int wv = tid >> 6, lane = tid & 63;
    int nTile = blockIdx.x * 128;
    int wp = (wv >> 1) * 64, wn = (wv & 1) * 64;
    int fr = lane & 15, fq = lane >> 4;

    const u16* gB = yt + (size_t)nTile * 128;
#pragma unroll
    for (int i = 0; i < 8; ++i) {
        int o = (i * 4 + wv) * 512;
        gll16(wwbf + o + lane * 8, &sA[o]);
        gll16(gB + o + lane * 8, &sB[o]);
    }
    __syncthreads();

    f32x4 acc[4][4];
#pragma unroll
    for (int mi = 0; mi < 4; ++mi)
#pragma unroll
        for (int ni = 0; ni < 4; ++ni)
#pragma unroll
            for (int r = 0; r < 4; ++r) acc[mi][ni][r] = 0.f;

#pragma unroll
    for (int ks = 0; ks < 4; ++ks) {
        int k0 = ks * 32 + fq * 8;
        short8v a[4], bb[4];
#pragma unroll
        for (int i = 0; i < 4; ++i) {
            int ra = wp + i * 16 + fr;
            a[i] = *(const short8v*)&sA[ra * 128 + (k0 ^ ((ra & 7) << 3))];
            int rb = wn + i * 16 + fr;
            bb[i] = *(const short8v*)&sB[rb * 128 + (k0 ^ ((rb & 7) << 3))];
        }
#pragma unroll
        for (int mi = 0; mi < 4; ++mi)
#pragma unroll
            for (int ni = 0; ni < 4; ++ni)
                acc[mi][ni] = __builtin_amdgcn_mfma_f32_16x16x32_bf16(a[mi], bb[ni], acc[mi][ni], 0, 0, 0);
    }

#pragma unroll
    for (int mi = 0; mi < 4; ++mi)
#pragma unroll
        for (int ni = 0; ni < 4; ++ni) {
            int gp = nTile + wn + ni * 16 + fr;
#pragma unroll
            for (int r = 0; r < 4; ++r) {
                int o = wp + mi * 16 + fq * 4 + r;
                yw[(size_t)o * NPIX + gp] = acc[mi][ni][r];
            }
        }
}

__global__ __launch_bounds__(256) void k_stats(const float* __restrict__ yw,
                                               float* __restrict__ meanvar) {
    int o = blockIdx.x, t = threadIdx.x;
    __shared__ float rs[256], rq[256];
    float s = 0.f, q = 0.f;
    const float* p = yw + (size_t)o * NPIX;
    for (int i = t; i < NPIX; i += 256) {
        float v = p[i];
        s += v;
        q += v * v;
    }
    rs[t] = s; rq[t] = q;
    __syncthreads();
    for (int off = 128; off > 0; off >>= 1) {
        if (t < off) { rs[t] += rs[t + off]; rq[t] += rq[t + off]; }
        __syncthreads();
    }
    if (t == 0) {
        float n = (float)NPIX;
        float mean = rs[0] / n;
        float var  = rq[0] / n - mean * mean;
        meanvar[o] = mean;
        meanvar[CA + o] = var;
    }
}

__global__ __launch_bounds__(256) void k_final(const float* __restrict__ yw,
                                               const float* __restrict__ meanvar,
                                               const float* __restrict__ gamma,
                                               const float* __restrict__ beta,
                                               const float* __restrict__ alpha,
                                               float* __restrict__ out0) {
    size_t i = ((size_t)blockIdx.x * 256 + threadIdx.x) * 4;
    int c = (int)((i >> 14) & 127);
    int b = (int)(i >> 21);
    int pix = (int)(i & 16383);
    float4 v = *(const float4*)(yw + (size_t)c * NPIX + b * 16384 + pix);
    float4 a = *(const float4*)(alpha + i);
    float mean = meanvar[c];
    float var  = meanvar[CA + c];
    float sc   = rsqrtf(var + 1e-5f) * gamma[c];
    float bt   = beta[c];
    float4 r;
    r.x = (v.x - mean) * sc + bt + a.x;
    r.y = (v.y - mean) * sc + bt + a.y;
    r.z = (v.z - mean) * sc + bt + a.z;
    r.w = (v.w - mean) * sc + bt + a.w;
    *(float4*)(out0 + i) = r;
}

extern "C" void kernel_launch(void* const* d_in, const int* in_sizes, int n_in,
                              void* d_out, int out_size, void* d_ws, size_t ws_size,
                              hipStream_t stream) {
    (void)in_sizes; (void)n_in; (void)out_size;
    const float* f     = (const float*)d_in[0];
    const float* alpha = (const float*)d_in[1];
    const float* unk   = (const float*)d_in[2];
    const float* gw    = (const float*)d_in[3];
    const float* gb    = (const float*)d_in[4];
    const float* ww    = (const float*)d_in[5];
    const float* gamma = (const float*)d_in[6];
    const float* beta  = (const float*)d_in[7];

    float* out0 = (float*)d_out;
    float* out1 = out0 + (size_t)B * CA * H * W_;
    float* out2 = out1 + (size_t)B * 2 * HS * WS;

    // ---- persistent region ----
    float* wsf = (float*)d_ws;
    size_t off = 0;
    float* fds     = wsf + off; off += (size_t)B * CM * HS * WS;  // 2,097,152
    float* ssq     = wsf + off; off += (size_t)B * HS * WS;
    float* gbuf    = wsf + off; off += (size_t)B * L;
    float* dgbuf   = wsf + off; off += (size_t)B * L;
    float* suk     = wsf + off; off += 64;
    float* ytF     = wsf + off; off += (size_t)NPIX * 128 / 2;    // 4,194,304
    float* wwbfF   = wsf + off; off += 8192;
    float* meanvar = wsf + off; off += 256;
    float* base    = wsf + off;                                   // slots

    const size_t PRE_F = off;
    int nb = (ws_size >= (PRE_F + 4 * SLOT_F) * sizeof(float)) ? 4 : 2;  // nb=2 fits in 166MB (proven ws >= 210MB)

    float* yw   = base;          // fp32 [128][NPIX], used after batch loop (aliases slot0 STP)
    u16*   yt   = (u16*)ytF;
    u16*   wwbf = (u16*)wwbfF;

    k_cvtww<<<64, 256, 0, stream>>>(ww, wwbf);
    k_conv_ds<<<dim3(64, 4), 256, 0, stream>>>(f, gw, gb, fds);
    k_ssq<<<dim3(64, 4), 64, 0, stream>>>(fds, ssq);
    k_scale<<<4, 256, 0, stream>>>(unk, suk, out2);
    k_gate<<<dim3(64, 4), 64, 0, stream>>>(unk, ssq, suk, gbuf, dgbuf);

    for (int b0 = 0; b0 < B; b0 += nb) {
        k_buildW<<<dim3(64, 32, nb), dim3(64, 4), 0, stream>>>(fds, base, b0);
        k_gemm1<<<dim3(528, 1, nb), 256, 0, stream>>>(base, gbuf, dgbuf, b0);
        k_softmax<<<dim3(4096, nb), 256, 0, stream>>>(base, gbuf, dgbuf, out1, b0);
        k_buildA<<<dim3(16, 2048, nb), 256, 0, stream>>>(alpha, base, b0);
        k_gemm2<<<dim3(16, 32, nb), 256, 0, stream>>>(base);
        k_gather<<<dim3(64, 128, nb), 256, 0, stream>>>(base, yt, b0);
    }

    k_ywgemm<<<512, 256, 0, stream>>>(wwbf, yt, yw);
    k_stats<<<128, 256, 0, stream>>>(yw, meanvar);
    k_final<<<8192, 256, 0, stream>>>(yw, meanvar, gamma, beta, alpha, out0);
}

// Round 7
// 1007.022 us; speedup vs baseline: 1.2811x; 1.0072x over previous
//
#include <hip/hip_runtime.h>
#include <math.h>

#define B 4
#define CG 256
#define CM 128
#define CA 128
#define H 128
#define W_ 128
#define HS 64
#define WS 64
#define L 4096
#define D1 1152
#define D2 2048
#define NPIX 65536

// slot layout (floats): [STP bf16 L*L][Wf fp32 -> At bf16][Whi bf16 -> Z bf16]
#define STP_F 8388608UL
#define WF_F  4718592UL
#define ZB_F  4194304UL
#define SLOT_F (STP_F + WF_F + ZB_F)   // 17,301,504 floats = 69.2 MB

typedef unsigned short u16;
typedef __attribute__((ext_vector_type(8))) short short8v;
typedef __attribute__((ext_vector_type(4))) unsigned short u16x4;
typedef __attribute__((ext_vector_type(4))) float f32x4;

__device__ __forceinline__ float bf2f(u16 x) {
    union { unsigned int u; float f; } v; v.u = ((unsigned int)x) << 16; return v.f;
}
__device__ __forceinline__ u16 f2bf(float x) {
    union { float f; unsigned int u; } v; v.f = x;
    unsigned int r = (v.u + 0x7FFFu + ((v.u >> 16) & 1u)) >> 16;
    return (u16)r;
}
__device__ __forceinline__ void gll16(const void* g, void* l) {
    __builtin_amdgcn_global_load_lds((const __attribute__((address_space(1))) void*)g,
                                     (__attribute__((address_space(3))) void*)l, 16, 0, 0);
}
__device__ __forceinline__ int refl(int i, int n) {
    return i < 0 ? -i : (i >= n ? 2 * n - 2 - i : i);
}
// swizzled LDS element offset for [128][32 u16] tiles: 16B-chunk XOR
__device__ __forceinline__ int swz(int row, int fq) {
    return row * 32 + ((fq ^ ((row >> 1) & 3)) * 8);
}

// K0: f_ds = 1x1 conv at even pixels + fused ssq
__global__ __launch_bounds__(256) void k_conv_ds(const float* __restrict__ f,
                                                 const float* __restrict__ gw,
                                                 const float* __restrict__ gb,
                                                 float* __restrict__ fds,
                                                 float* __restrict__ ssq) {
    __shared__ float sf[CG * 64];
    __shared__ float part[4][64];
    int t = threadIdx.x;
    int hs = blockIdx.x, b = blockIdx.y;
    const float* fb = f + (size_t)b * CG * H * W_ + (2 * hs) * W_;
    for (int idx = t; idx < CG * 64; idx += 256) {
        int ci = idx >> 6, ws = idx & 63;
        sf[idx] = fb[(size_t)ci * H * W_ + 2 * ws];
    }
    __syncthreads();
    int ws = t & 63;
    int wave = __builtin_amdgcn_readfirstlane(t >> 6);
    const float* gwp = gw + (size_t)(wave * 32) * CG;
    float acc[32];
#pragma unroll
    for (int r = 0; r < 32; ++r) acc[r] = gb[wave * 32 + r];
    for (int ci = 0; ci < CG; ++ci) {
        float fv = sf[ci * 64 + ws];
#pragma unroll
        for (int r = 0; r < 32; ++r) acc[r] += gwp[r * CG + ci] * fv;
    }
    float sq = 0.f;
#pragma unroll
    for (int r = 0; r < 32; ++r) {
        int co = wave * 32 + r;
        fds[(((size_t)b * CM + co) * HS + hs) * WS + ws] = acc[r];
        sq += acc[r] * acc[r];
    }
    part[wave][ws] = sq;
    __syncthreads();
    if (t < 64)
        ssq[((size_t)b * HS + hs) * WS + t] =
            part[0][t] + part[1][t] + part[2][t] + part[3][t];
}

__global__ __launch_bounds__(256) void k_scale(const float* __restrict__ unk,
                                               float* __restrict__ suk,
                                               float* __restrict__ out2) {
    int b = blockIdx.x, t = threadIdx.x;
    __shared__ float red[256];
    float s = 0.f;
    for (int i = t; i < L; i += 256) {
        int hs = i >> 6, ws = i & 63;
        s += unk[(size_t)b * H * W_ + (2 * hs) * W_ + 2 * ws];
    }
    red[t] = s;
    __syncthreads();
    for (int o = 128; o > 0; o >>= 1) {
        if (t < o) red[t] += red[t + o];
        __syncthreads();
    }
    if (t == 0) {
        float u = red[0] / (float)L;
        float k = 1.0f - u;
        float su = sqrtf(u / k); su = fminf(fmaxf(su, 0.1f), 10.0f);
        float sk = sqrtf(k / u); sk = fminf(fmaxf(sk, 0.1f), 10.0f);
        suk[b * 2] = su; suk[b * 2 + 1] = sk;
        out2[b * 2] = su; out2[b * 2 + 1] = sk;
    }
}

__global__ __launch_bounds__(64) void k_gate(const float* __restrict__ unk,
                                             const float* __restrict__ ssq,
                                             const float* __restrict__ suk,
                                             float* __restrict__ g,
                                             float* __restrict__ dg) {
    int ws = threadIdx.x, hs = blockIdx.x, b = blockIdx.y;
    float sm = 0.f, sq = 0.f;
    for (int di = -1; di <= 1; ++di) {
        int rh = refl(hs + di, HS);
        for (int dj = -1; dj <= 1; ++dj) {
            int rw = refl(ws + dj, WS);
            sm += unk[(size_t)b * H * W_ + (2 * rh) * W_ + 2 * rw];
            sq += ssq[((size_t)b * HS + rh) * WS + rw];
        }
    }
    float mm   = (sm > 0.0f) ? 1.0f : 0.0f;
    float norm = sqrtf(sq);
    float gate = (mm > 0.0f) ? suk[2 * b] : suk[2 * b + 1];
    int q = hs * WS + ws;
    g[(size_t)b * L + q]  = gate / fmaxf(norm, 1e-4f);
    dg[(size_t)b * L + q] = -10000.0f * mm;
}

// K4: fp32 W + bf16 W (batched over z)
__global__ __launch_bounds__(256) void k_buildW(const float* __restrict__ fds,
                                                float* __restrict__ base, int b0) {
    int bz = blockIdx.z;
    int b  = b0 + bz;
    float* S   = base + (size_t)bz * SLOT_F;
    float* Wf  = S + STP_F;
    u16*   Whi = (u16*)(S + STP_F + WF_F);
    int ws = threadIdx.x;
    int c  = blockIdx.y * 4 + threadIdx.y;
    int hs = blockIdx.x;
    int q = hs * WS + ws;
    size_t bo = (size_t)q * D1 + c * 9;
    const float* src = fds + ((size_t)b * CM + c) * HS * WS;
#pragma unroll
    for (int i = 0; i < 3; ++i) {
        int rh = refl(hs + i - 1, HS);
#pragma unroll
        for (int j = 0; j < 3; ++j) {
            int rw = refl(ws + j - 1, WS);
            float v = src[rh * WS + rw];
            Wf[bo + i * 3 + j]  = v;
            Whi[bo + i * 3 + j] = f2bf(v);
        }
    }
}

// K5: symmetric bf16 MFMA score GEMM -> bf16 ST (upper-tri + mirror, dbuf pipeline)
__global__ __launch_bounds__(256) void k_gemm1(float* __restrict__ base,
                                               const float* __restrict__ g0,
                                               const float* __restrict__ dg0,
                                               int b0) {
    __shared__ u16 sAh[2][128 * 32], sBh[2][128 * 32];
    int bz = blockIdx.z;
    float* S = base + (size_t)bz * SLOT_F;
    u16* STP = (u16*)S;
    const u16* Whi = (const u16*)(S + STP_F + WF_F);
    const float* g  = g0  + (size_t)(b0 + bz) * L;
    const float* dg = dg0 + (size_t)(b0 + bz) * L;

    int tid = threadIdx.x;
    int wv = tid >> 6, lane = tid & 63;
    int t = blockIdx.x, I = 0;
    while (t >= 32 - I) { t -= 32 - I; ++I; }
    int J = I + t;
    int pTile = I * 128, qTile = J * 128;
    int wp = (wv >> 1) * 64, wq = (wv & 1) * 64;
    int r0 = wv * 32;
    int lrow = lane >> 2;
    int csw = ((lane & 3) ^ ((lrow >> 1) & 3)) * 8;   // pre-swizzled source chunk (elems)
    int fr = lane & 15, fq = lane >> 4;

    const u16* gArow = Whi + (size_t)(pTile + r0 + lrow) * D1 + csw;
    const u16* gBrow = Whi + (size_t)(qTile + r0 + lrow) * D1 + csw;

    f32x4 acc[4][4];
#pragma unroll
    for (int mi = 0; mi < 4; ++mi)
#pragma unroll
        for (int ni = 0; ni < 4; ++ni)
#pragma unroll
            for (int r = 0; r < 4; ++r) acc[mi][ni][r] = 0.f;

    // prologue: stage k0=0 into buf 0
    gll16(gArow, &sAh[0][r0 * 32]);
    gll16(gArow + (size_t)16 * D1, &sAh[0][(r0 + 16) * 32]);
    gll16(gBrow, &sBh[0][r0 * 32]);
    gll16(gBrow + (size_t)16 * D1, &sBh[0][(r0 + 16) * 32]);
    __syncthreads();

    int cur = 0;
    for (int k0 = 0; k0 < D1; k0 += 32) {
        int nxt = k0 + 32;
        if (nxt < D1) {
            gll16(gArow + nxt, &sAh[cur ^ 1][r0 * 32]);
            gll16(gArow + nxt + (size_t)16 * D1, &sAh[cur ^ 1][(r0 + 16) * 32]);
            gll16(gBrow + nxt, &sBh[cur ^ 1][r0 * 32]);
            gll16(gBrow + nxt + (size_t)16 * D1, &sBh[cur ^ 1][(r0 + 16) * 32]);
        }
        short8v ah[4], bh[4];
#pragma unroll
        for (int i = 0; i < 4; ++i) {
            ah[i] = *(const short8v*)&sAh[cur][swz(wp + i * 16 + fr, fq)];
            bh[i] = *(const short8v*)&sBh[cur][swz(wq + i * 16 + fr, fq)];
        }
        __builtin_amdgcn_s_setprio(1);
#pragma unroll
        for (int mi = 0; mi < 4; ++mi)
#pragma unroll
            for (int ni = 0; ni < 4; ++ni)
                acc[mi][ni] = __builtin_amdgcn_mfma_f32_16x16x32_bf16(ah[mi], bh[ni], acc[mi][ni], 0, 0, 0);
        __builtin_amdgcn_s_setprio(0);
        __syncthreads();   // drains vmcnt (next buf staged) + lgkm; protects cur buf reuse
        cur ^= 1;
    }

    // direct tile: rows p (I), cols q (J)
#pragma unroll
    for (int ni = 0; ni < 4; ++ni) {
        int qq = qTile + wq + ni * 16 + fr;
        float gq = g[qq];
        float dq = dg[qq];
#pragma unroll
        for (int mi = 0; mi < 4; ++mi) {
            int pB = pTile + wp + mi * 16 + fq * 4;
#pragma unroll
            for (int r = 0; r < 4; ++r) {
                int p = pB + r;
                float v = acc[mi][ni][r] * gq;
                if (p == qq) v += dq;
                STP[(size_t)p * L + qq] = f2bf(v);
            }
        }
    }
    // mirror tile: rows q (J), cols p (I)
    if (I != J) {
#pragma unroll
        for (int mi = 0; mi < 4; ++mi) {
            int p0 = pTile + wp + mi * 16 + fq * 4;
            float gp0 = g[p0], gp1 = g[p0 + 1], gp2 = g[p0 + 2], gp3 = g[p0 + 3];
#pragma unroll
            for (int ni = 0; ni < 4; ++ni) {
                int qq = qTile + wq + ni * 16 + fr;
                u16x4 mv;
                mv[0] = f2bf(acc[mi][ni][0] * gp0);
                mv[1] = f2bf(acc[mi][ni][1] * gp1);
                mv[2] = f2bf(acc[mi][ni][2] * gp2);
                mv[3] = f2bf(acc[mi][ni][3] * gp3);
                *(u16x4*)(STP + (size_t)qq * L + p0) = mv;
            }
        }
    }
}

// K6: softmax in-place (bf16) + exact argmax via candidate refinement
__global__ __launch_bounds__(256) void k_softmax(float* __restrict__ base,
                                                 const float* __restrict__ g0,
                                                 const float* __restrict__ dg0,
                                                 float* __restrict__ out1, int b0) {
    __shared__ float buf[L];
    __shared__ float red[256];
    __shared__ int candList[128];
    __shared__ int candCount;
    int bz = blockIdx.y;
    int b  = b0 + bz;
    float* S = base + (size_t)bz * SLOT_F;
    u16* STP = (u16*)S;
    const float* Wf = S + STP_F;
    const float* g  = g0  + (size_t)b * L;
    const float* dg = dg0 + (size_t)b * L;

    int p = blockIdx.x, t = threadIdx.x;
    u16* rowp = STP + (size_t)p * L;

    if (t == 0) candCount = 0;
    float mx = -3.4e38f;
    for (int i = t; i < L / 8; i += 256) {
        short8v v8 = ((const short8v*)rowp)[i];
#pragma unroll
        for (int j = 0; j < 8; ++j) {
            float v = bf2f((u16)v8[j]);
            buf[i * 8 + j] = v;
            mx = fmaxf(mx, v);
        }
    }
    red[t] = mx;
    __syncthreads();
    for (int o = 128; o > 0; o >>= 1) {
        if (t < o) red[t] = fmaxf(red[t], red[t + o]);
        __syncthreads();
    }
    float M = red[0];
    float u = fabsf(M) * 0.0625f + 1e-5f;   // window covers bf16 storage + hi-only MFMA error
    float cth = M - u;
    __syncthreads();

    float s = 0.f;
    for (int i = t; i < L; i += 256) {
        float v = buf[i];
        if (v >= cth) {
            int ix = atomicAdd(&candCount, 1);
            if (ix < 128) candList[ix] = i;
        }
        float e = __expf(v - M);
        buf[i] = e;
        s += e;
    }
    red[t] = s;
    __syncthreads();
    for (int o = 128; o > 0; o >>= 1) {
        if (t < o) red[t] += red[t + o];
        __syncthreads();
    }
    float inv = 1.0f / red[0];
    __syncthreads();

    for (int i = t; i < L / 8; i += 256) {
        short8v o8;
#pragma unroll
        for (int j = 0; j < 8; ++j) o8[j] = (short)f2bf(buf[i * 8 + j] * inv);
        ((short8v*)rowp)[i] = o8;
    }
    __syncthreads();

    int nc = candCount; if (nc > 128) nc = 128;
    int bestI;
    if (nc == 1) {
        bestI = candList[0];
    } else {
        float bestE = -3.4e38f; bestI = L;
        const float* wp_ = Wf + (size_t)p * D1;
        for (int k = 0; k < nc; ++k) {
            int cand = candList[k];
            const float* wc = Wf + (size_t)cand * D1;
            float part = 0.f;
            for (int j = t; j < D1; j += 256) part += wp_[j] * wc[j];
            red[t] = part;
            __syncthreads();
            for (int o = 128; o > 0; o >>= 1) {
                if (t < o) red[t] += red[t + o];
                __syncthreads();
            }
            float e1 = red[0] * g[cand] + (p == cand ? dg[cand] : 0.f);
            if (e1 > bestE || (e1 == bestE && cand < bestI)) { bestE = e1; bestI = cand; }
            __syncthreads();
        }
    }
    if (t == 0) {
        out1[(size_t)(b * 2 + 0) * L + p] = (float)(bestI / WS - 32);
        out1[(size_t)(b * 2 + 1) * L + p] = (float)(bestI % WS - 32);
    }
}

// K7: At[n,q] = bf16(alpha patch), transposed (overwrites Wf region; batched over z)
__global__ __launch_bounds__(256) void k_buildA(const float* __restrict__ alpha,
                                                float* __restrict__ base, int b0) {
    int bz = blockIdx.z;
    int b  = b0 + bz;
    u16* At = (u16*)(base + (size_t)bz * SLOT_F + STP_F);
    int q = blockIdx.x * 256 + threadIdx.x;
    int n = blockIdx.y;
    int hs = q >> 6, ws = q & 63;
    int c = n >> 4, ki = (n >> 2) & 3, kj = n & 3;
    int rh = refl(2 * hs + ki - 1, H);
    int rw = refl(2 * ws + kj - 1, W_);
    At[(size_t)n * L + q] = f2bf(alpha[((size_t)b * CA + c) * H * W_ + rh * W_ + rw]);
}

// K8: bf16 MFMA paste GEMM (batched over z, dbuf pipeline): Z[p,n] = sum_q P[p,q]*At[n,q]
__global__ __launch_bounds__(256) void k_gemm2(float* __restrict__ base) {
    __shared__ u16 sA[2][128 * 32], sB[2][128 * 32];
    int bz = blockIdx.z;
    float* S = base + (size_t)bz * SLOT_F;
    const u16* P  = (const u16*)S;
    const u16* At = (const u16*)(S + STP_F);
    u16* Z        = (u16*)(S + STP_F + WF_F);

    int tid = threadIdx.x;
    int wv = tid >> 6, lane = tid & 63;
    int pTile = blockIdx.y * 128, nTile = blockIdx.x * 128;
    int wp = (wv >> 1) * 64, wn = (wv & 1) * 64;
    int r0 = wv * 32;
    int lrow = lane >> 2;
    int csw = ((lane & 3) ^ ((lrow >> 1) & 3)) * 8;
    int fr = lane & 15, fq = lane >> 4;

    const u16* gArow = P  + (size_t)(pTile + r0 + lrow) * L + csw;
    const u16* gBrow = At + (size_t)(nTile + r0 + lrow) * L + csw;

    f32x4 acc[4][4];
#pragma unroll
    for (int mi = 0; mi < 4; ++mi)
#pragma unroll
        for (int ni = 0; ni < 4; ++ni)
#pragma unroll
            for (int r = 0; r < 4; ++r) acc[mi][ni][r] = 0.f;

    // prologue: stage k0=0 into buf 0
    gll16(gArow, &sA[0][r0 * 32]);
    gll16(gArow + (size_t)16 * L, &sA[0][(r0 + 16) * 32]);
    gll16(gBrow, &sB[0][r0 * 32]);
    gll16(gBrow + (size_t)16 * L, &sB[0][(r0 + 16) * 32]);
    __syncthreads();

    int cur = 0;
    for (int k0 = 0; k0 < L; k0 += 32) {
        int nxt = k0 + 32;
        if (nxt < L) {
            gll16(gArow + nxt, &sA[cur ^ 1][r0 * 32]);
            gll16(gArow + nxt + (size_t)16 * L, &sA[cur ^ 1][(r0 + 16) * 32]);
            gll16(gBrow + nxt, &sB[cur ^ 1][r0 * 32]);
            gll16(gBrow + nxt + (size_t)16 * L, &sB[cur ^ 1][(r0 + 16) * 32]);
        }
        short8v a[4], bb[4];
#pragma unroll
        for (int i = 0; i < 4; ++i) {
            a[i]  = *(const short8v*)&sA[cur][swz(wp + i * 16 + fr, fq)];
            bb[i] = *(const short8v*)&sB[cur][swz(wn + i * 16 + fr, fq)];
        }
        __builtin_amdgcn_s_setprio(1);
#pragma unroll
        for (int mi = 0; mi < 4; ++mi)
#pragma unroll
            for (int ni = 0; ni < 4; ++ni)
                acc[mi][ni] = __builtin_amdgcn_mfma_f32_16x16x32_bf16(a[mi], bb[ni], acc[mi][ni], 0, 0, 0);
        __builtin_amdgcn_s_setprio(0);
        __syncthreads();
        cur ^= 1;
    }

#pragma unroll
    for (int mi = 0; mi < 4; ++mi)
#pragma unroll
        for (int ni = 0; ni < 4; ++ni) {
            int n = nTile + wn + ni * 16 + fr;
#pragma unroll
            for (int r = 0; r < 4; ++r) {
                int p = pTile + wp + mi * 16 + fq * 4 + r;
                Z[(size_t)p * D2 + n] = f2bf(acc[mi][ni][r]);
            }
        }
}

// K9: transposed-conv gather -> yt[pix, c] bf16 (batched over z)
__global__ __launch_bounds__(256) void k_gather(float* __restrict__ base,
                                                u16* __restrict__ yt, int b0) {
    int bz = blockIdx.z;
    int b  = b0 + bz;
    const u16* Z = (const u16*)(base + (size_t)bz * SLOT_F + STP_F + WF_F);
    int c  = threadIdx.x & 127;
    int pl = threadIdx.x >> 7;
    int w  = blockIdx.x * 2 + pl;
    int h  = blockIdx.y;
    float s = 0.f;
#pragma unroll
    for (int ki = 0; ki < 4; ++ki) {
        int num = h + 1 - ki;
        if (num < 0 || (num & 1)) continue;
        int hs = num >> 1;
        if (hs >= HS) continue;
#pragma unroll
        for (int kj = 0; kj < 4; ++kj) {
            int numw = w + 1 - kj;
            if (numw < 0 || (numw & 1)) continue;
            int wsd = numw >> 1;
            if (wsd >= WS) continue;
            s += bf2f(Z[(size_t)(hs * WS + wsd) * D2 + c * 16 + ki * 4 + kj]);
        }
    }
    int pix = h * W_ + w;
    int cs = c ^ ((pix & 7) << 3);
    yt[((size_t)b * 16384 + pix) * 128 + cs] = f2bf(0.25f * s);
}

__global__ __launch_bounds__(256) void k_cvtww(const float* __restrict__ ww,
                                               u16* __restrict__ wwbf) {
    int i = blockIdx.x * 256 + threadIdx.x;
    int o = i >> 7, c = i & 127;
    wwbf[o * 128 + (c ^ ((o & 7) << 3))] = f2bf(ww[i]);
}

// K10: yw[o, gp] = sum_c w_w[o,c] * y[gp, c]   MFMA, K=128
__global__ __launch_bounds__(256) void k_ywgemm(const u16* __restrict__ wwbf,
                                                const u16* __restrict__ yt,
                                                float* __restrict__ yw) {
    __shared__ u16 sA[128 * 128], sB[128 * 128];
    int tid = threadIdx.x;
    int wv = tid >> 6, lane = tid & 63;
    int nTile = blockIdx.x * 128;
    int wp = (wv >> 1) * 64, wn = (wv & 1) * 64;
    int fr = lane & 15, fq = lane >> 4;

    const u16* gB = yt + (size_t)nTile * 128;
#pragma unroll
    for (int i = 0; i < 8; ++i) {
        int o = (i * 4 + wv) * 512;
        gll16(wwbf + o + lane * 8, &sA[o]);
        gll16(gB + o + lane * 8, &sB[o]);
    }
    __syncthreads();

    f32x4 acc[4][4];
#pragma unroll
    for (int mi = 0; mi < 4; ++mi)
#pragma unroll
        for (int ni = 0; ni < 4; ++ni)
#pragma unroll
            for (int r = 0; r < 4; ++r) acc[mi][ni][r] = 0.f;

#pragma unroll
    for (int ks = 0; ks < 4; ++ks) {
        int k0 = ks * 32 + fq * 8;
        short8v a[4], bb[4];
#pragma unroll
        for (int i = 0; i < 4; ++i) {
            int ra = wp + i * 16 + fr;
            a[i] = *(const short8v*)&sA[ra * 128 + (k0 ^ ((ra & 7) << 3))];
            int rb = wn + i * 16 + fr;
            bb[i] = *(const short8v*)&sB[rb * 128 + (k0 ^ ((rb & 7) << 3))];
        }
#pragma unroll
        for (int mi = 0; mi < 4; ++mi)
#pragma unroll
            for (int ni = 0; ni < 4; ++ni)
                acc[mi][ni] = __builtin_amdgcn_mfma_f32_16x16x32_bf16(a[mi], bb[ni], acc[mi][ni], 0, 0, 0);
    }

#pragma unroll
    for (int mi = 0; mi < 4; ++mi)
#pragma unroll
        for (int ni = 0; ni < 4; ++ni) {
            int gp = nTile + wn + ni * 16 + fr;
#pragma unroll
            for (int r = 0; r < 4; ++r) {
                int o = wp + mi * 16 + fq * 4 + r;
                yw[(size_t)o * NPIX + gp] = acc[mi][ni][r];
            }
        }
}

__global__ __launch_bounds__(256) void k_stats(const float* __restrict__ yw,
                                               float* __restrict__ meanvar) {
    int o = blockIdx.x, t = threadIdx.x;
    __shared__ float rs[256], rq[256];
    float s = 0.f, q = 0.f;
    const float* p = yw + (size_t)o * NPIX;
    for (int i = t; i < NPIX; i += 256) {
        float v = p[i];
        s += v;
        q += v * v;
    }
    rs[t] = s; rq[t] = q;
    __syncthreads();
    for (int off = 128; off > 0; off >>= 1) {
        if (t < off) { rs[t] += rs[t + off]; rq[t] += rq[t + off]; }
        __syncthreads();
    }
    if (t == 0) {
        float n = (float)NPIX;
        float mean = rs[0] / n;
        float var  = rq[0] / n - mean * mean;
        meanvar[o] = mean;
        meanvar[CA + o] = var;
    }
}

__global__ __launch_bounds__(256) void k_final(const float* __restrict__ yw,
                                               const float* __restrict__ meanvar,
                                               const float* __restrict__ gamma,
                                               const float* __restrict__ beta,
                                               const float* __restrict__ alpha,
                                               float* __restrict__ out0) {
    size_t i = ((size_t)blockIdx.x * 256 + threadIdx.x) * 4;
    int c = (int)((i >> 14) & 127);
    int b = (int)(i >> 21);
    int pix = (int)(i & 16383);
    float4 v = *(const float4*)(yw + (size_t)c * NPIX + b * 16384 + pix);
    float4 a = *(const float4*)(alpha + i);
    float mean = meanvar[c];
    float var  = meanvar[CA + c];
    float sc   = rsqrtf(var + 1e-5f) * gamma[c];
    float bt   = beta[c];
    float4 r;
    r.x = (v.x - mean) * sc + bt + a.x;
    r.y = (v.y - mean) * sc + bt + a.y;
    r.z = (v.z - mean) * sc + bt + a.z;
    r.w = (v.w - mean) * sc + bt + a.w;
    *(float4*)(out0 + i) = r;
}

extern "C" void kernel_launch(void* const* d_in, const int* in_sizes, int n_in,
                              void* d_out, int out_size, void* d_ws, size_t ws_size,
                              hipStream_t stream) {
    (void)in_sizes; (void)n_in; (void)out_size;
    const float* f     = (const float*)d_in[0];
    const float* alpha = (const float*)d_in[1];
    const float* unk   = (const float*)d_in[2];
    const float* gw    = (const float*)d_in[3];
    const float* gb    = (const float*)d_in[4];
    const float* ww    = (const float*)d_in[5];
    const float* gamma = (const float*)d_in[6];
    const float* beta  = (const float*)d_in[7];

    float* out0 = (float*)d_out;
    float* out1 = out0 + (size_t)B * CA * H * W_;
    float* out2 = out1 + (size_t)B * 2 * HS * WS;

    // ---- persistent region ----
    float* wsf = (float*)d_ws;
    size_t off = 0;
    float* fds     = wsf + off; off += (size_t)B * CM * HS * WS;  // 2,097,152
    float* ssq     = wsf + off; off += (size_t)B * HS * WS;
    float* gbuf    = wsf + off; off += (size_t)B * L;
    float* dgbuf   = wsf + off; off += (size_t)B * L;
    float* suk     = wsf + off; off += 64;
    float* ytF     = wsf + off; off += (size_t)NPIX * 128 / 2;    // 4,194,304
    float* wwbfF   = wsf + off; off += 8192;
    float* meanvar = wsf + off; off += 256;
    float* base    = wsf + off;                                   // slots

    const size_t PRE_F = off;
    int nb = (ws_size >= (PRE_F + 4 * SLOT_F) * sizeof(float)) ? 4 : 2;

    float* yw   = base;          // fp32 [128][NPIX], used after batch loop (aliases slot0 STP)
    u16*   yt   = (u16*)ytF;
    u16*   wwbf = (u16*)wwbfF;

    k_cvtww<<<64, 256, 0, stream>>>(ww, wwbf);
    k_conv_ds<<<dim3(64, 4), 256, 0, stream>>>(f, gw, gb, fds, ssq);
    k_scale<<<4, 256, 0, stream>>>(unk, suk, out2);
    k_gate<<<dim3(64, 4), 64, 0, stream>>>(unk, ssq, suk, gbuf, dgbuf);

    for (int b0 = 0; b0 < B; b0 += nb) {
        k_buildW<<<dim3(64, 32, nb), dim3(64, 4), 0, stream>>>(fds, base, b0);
        k_gemm1<<<dim3(528, 1, nb), 256, 0, stream>>>(base, gbuf, dgbuf, b0);
        k_softmax<<<dim3(4096, nb), 256, 0, stream>>>(base, gbuf, dgbuf, out1, b0);
        k_buildA<<<dim3(16, 2048, nb), 256, 0, stream>>>(alpha, base, b0);
        k_gemm2<<<dim3(16, 32, nb), 256, 0, stream>>>(base);
        k_gather<<<dim3(64, 128, nb), 256, 0, stream>>>(base, yt, b0);
    }

    k_ywgemm<<<512, 256, 0, stream>>>(wwbf, yt, yw);
    k_stats<<<128, 256, 0, stream>>>(yw, meanvar);
    k_final<<<8192, 256, 0, stream>>>(yw, meanvar, gamma, beta, alpha, out0);
}

// Round 8
// 877.195 us; speedup vs baseline: 1.4707x; 1.1480x over previous
//
#include <hip/hip_runtime.h>
#include <math.h>

#define B 4
#define CG 256
#define CM 128
#define CA 128
#define H 128
#define W_ 128
#define HS 64
#define WS 64
#define L 4096
#define D1 1152
#define D2 2048
#define NPIX 65536
#define NT2 128   // L/32 k-tiles for gemm2

// slot layout (floats): [STP bf16 L*L][Wf fp32 -> At bf16][Whi bf16 -> Z bf16]
#define STP_F 8388608UL
#define WF_F  4718592UL
#define ZB_F  4194304UL
#define SLOT_F (STP_F + WF_F + ZB_F)   // 17,301,504 floats = 69.2 MB

typedef unsigned short u16;
typedef __attribute__((ext_vector_type(8))) short short8v;
typedef __attribute__((ext_vector_type(4))) unsigned short u16x4;
typedef __attribute__((ext_vector_type(4))) float f32x4;

__device__ __forceinline__ float bf2f(u16 x) {
    union { unsigned int u; float f; } v; v.u = ((unsigned int)x) << 16; return v.f;
}
__device__ __forceinline__ u16 f2bf(float x) {
    union { float f; unsigned int u; } v; v.f = x;
    unsigned int r = (v.u + 0x7FFFu + ((v.u >> 16) & 1u)) >> 16;
    return (u16)r;
}
__device__ __forceinline__ void gll16(const void* g, void* l) {
    __builtin_amdgcn_global_load_lds((const __attribute__((address_space(1))) void*)g,
                                     (__attribute__((address_space(3))) void*)l, 16, 0, 0);
}
__device__ __forceinline__ int refl(int i, int n) {
    return i < 0 ? -i : (i >= n ? 2 * n - 2 - i : i);
}
// swizzled LDS element offset for [128][32 u16] tiles: 16B-chunk XOR (gemm1)
__device__ __forceinline__ int swz(int row, int fq) {
    return row * 32 + ((fq ^ ((row >> 1) & 3)) * 8);
}

// ---- gemm2 256^2 pipeline helpers: [256][32 u16] tiles, 64B rows ----
// stage one 16KB tile (256 rows x 64B) linearly into LDS; source pre-swizzled
// with cb ^= (row&3)<<4 so swizzled reads return correct data (rule 21).
__device__ __forceinline__ void stage32(const u16* __restrict__ mat, int rowTile,
                                        int kt, u16* lds, int wid, int lane) {
#pragma unroll
    for (int c = 0; c < 2; ++c) {
        int off = c * 8192 + wid * 1024 + lane * 16;   // byte offset in tile
        int row = off >> 6;
        int cb  = off & 63;
        const u16* g = mat + (size_t)(rowTile + row) * L + kt * 32
                     + ((cb ^ ((row & 3) << 4)) >> 1);
        gll16(g, (char*)lds + c * 8192 + wid * 1024);  // wave-uniform base; HW adds lane*16
    }
}
__device__ __forceinline__ short8v rdfrag32(const u16* lds, int r, int fq) {
    return *(const short8v*)((const char*)lds + r * 64 + ((fq * 16) ^ ((r & 3) << 4)));
}

// K0: f_ds = 1x1 conv at even pixels + fused ssq
__global__ __launch_bounds__(256) void k_conv_ds(const float* __restrict__ f,
                                                 const float* __restrict__ gw,
                                                 const float* __restrict__ gb,
                                                 float* __restrict__ fds,
                                                 float* __restrict__ ssq) {
    __shared__ float sf[CG * 64];
    __shared__ float part[4][64];
    int t = threadIdx.x;
    int hs = blockIdx.x, b = blockIdx.y;
    const float* fb = f + (size_t)b * CG * H * W_ + (2 * hs) * W_;
    for (int idx = t; idx < CG * 64; idx += 256) {
        int ci = idx >> 6, ws = idx & 63;
        sf[idx] = fb[(size_t)ci * H * W_ + 2 * ws];
    }
    __syncthreads();
    int ws = t & 63;
    int wave = __builtin_amdgcn_readfirstlane(t >> 6);
    const float* gwp = gw + (size_t)(wave * 32) * CG;
    float acc[32];
#pragma unroll
    for (int r = 0; r < 32; ++r) acc[r] = gb[wave * 32 + r];
    for (int ci = 0; ci < CG; ++ci) {
        float fv = sf[ci * 64 + ws];
#pragma unroll
        for (int r = 0; r < 32; ++r) acc[r] += gwp[r * CG + ci] * fv;
    }
    float sq = 0.f;
#pragma unroll
    for (int r = 0; r < 32; ++r) {
        int co = wave * 32 + r;
        fds[(((size_t)b * CM + co) * HS + hs) * WS + ws] = acc[r];
        sq += acc[r] * acc[r];
    }
    part[wave][ws] = sq;
    __syncthreads();
    if (t < 64)
        ssq[((size_t)b * HS + hs) * WS + t] =
            part[0][t] + part[1][t] + part[2][t] + part[3][t];
}

__global__ __launch_bounds__(256) void k_scale(const float* __restrict__ unk,
                                               float* __restrict__ suk,
                                               float* __restrict__ out2) {
    int b = blockIdx.x, t = threadIdx.x;
    __shared__ float red[256];
    float s = 0.f;
    for (int i = t; i < L; i += 256) {
        int hs = i >> 6, ws = i & 63;
        s += unk[(size_t)b * H * W_ + (2 * hs) * W_ + 2 * ws];
    }
    red[t] = s;
    __syncthreads();
    for (int o = 128; o > 0; o >>= 1) {
        if (t < o) red[t] += red[t + o];
        __syncthreads();
    }
    if (t == 0) {
        float u = red[0] / (float)L;
        float k = 1.0f - u;
        float su = sqrtf(u / k); su = fminf(fmaxf(su, 0.1f), 10.0f);
        float sk = sqrtf(k / u); sk = fminf(fmaxf(sk, 0.1f), 10.0f);
        suk[b * 2] = su; suk[b * 2 + 1] = sk;
        out2[b * 2] = su; out2[b * 2 + 1] = sk;
    }
}

__global__ __launch_bounds__(64) void k_gate(const float* __restrict__ unk,
                                             const float* __restrict__ ssq,
                                             const float* __restrict__ suk,
                                             float* __restrict__ g,
                                             float* __restrict__ dg) {
    int ws = threadIdx.x, hs = blockIdx.x, b = blockIdx.y;
    float sm = 0.f, sq = 0.f;
    for (int di = -1; di <= 1; ++di) {
        int rh = refl(hs + di, HS);
        for (int dj = -1; dj <= 1; ++dj) {
            int rw = refl(ws + dj, WS);
            sm += unk[(size_t)b * H * W_ + (2 * rh) * W_ + 2 * rw];
            sq += ssq[((size_t)b * HS + rh) * WS + rw];
        }
    }
    float mm   = (sm > 0.0f) ? 1.0f : 0.0f;
    float norm = sqrtf(sq);
    float gate = (mm > 0.0f) ? suk[2 * b] : suk[2 * b + 1];
    int q = hs * WS + ws;
    g[(size_t)b * L + q]  = gate / fmaxf(norm, 1e-4f);
    dg[(size_t)b * L + q] = -10000.0f * mm;
}

// K4: fp32 W + bf16 W (batched over z)
__global__ __launch_bounds__(256) void k_buildW(const float* __restrict__ fds,
                                                float* __restrict__ base, int b0) {
    int bz = blockIdx.z;
    int b  = b0 + bz;
    float* S   = base + (size_t)bz * SLOT_F;
    float* Wf  = S + STP_F;
    u16*   Whi = (u16*)(S + STP_F + WF_F);
    int ws = threadIdx.x;
    int c  = blockIdx.y * 4 + threadIdx.y;
    int hs = blockIdx.x;
    int q = hs * WS + ws;
    size_t bo = (size_t)q * D1 + c * 9;
    const float* src = fds + ((size_t)b * CM + c) * HS * WS;
#pragma unroll
    for (int i = 0; i < 3; ++i) {
        int rh = refl(hs + i - 1, HS);
#pragma unroll
        for (int j = 0; j < 3; ++j) {
            int rw = refl(ws + j - 1, WS);
            float v = src[rh * WS + rw];
            Wf[bo + i * 3 + j]  = v;
            Whi[bo + i * 3 + j] = f2bf(v);
        }
    }
}

// K5: symmetric bf16 MFMA score GEMM -> bf16 ST (upper-tri + mirror, dbuf pipeline)
__global__ __launch_bounds__(256) void k_gemm1(float* __restrict__ base,
                                               const float* __restrict__ g0,
                                               const float* __restrict__ dg0,
                                               int b0) {
    __shared__ u16 sAh[2][128 * 32], sBh[2][128 * 32];
    int bz = blockIdx.z;
    float* S = base + (size_t)bz * SLOT_F;
    u16* STP = (u16*)S;
    const u16* Whi = (const u16*)(S + STP_F + WF_F);
    const float* g  = g0  + (size_t)(b0 + bz) * L;
    const float* dg = dg0 + (size_t)(b0 + bz) * L;

    int tid = threadIdx.x;
    int wv = tid >> 6, lane = tid & 63;
    int t = blockIdx.x, I = 0;
    while (t >= 32 - I) { t -= 32 - I; ++I; }
    int J = I + t;
    int pTile = I * 128, qTile = J * 128;
    int wp = (wv >> 1) * 64, wq = (wv & 1) * 64;
    int r0 = wv * 32;
    int lrow = lane >> 2;
    int csw = ((lane & 3) ^ ((lrow >> 1) & 3)) * 8;
    int fr = lane & 15, fq = lane >> 4;

    const u16* gArow = Whi + (size_t)(pTile + r0 + lrow) * D1 + csw;
    const u16* gBrow = Whi + (size_t)(qTile + r0 + lrow) * D1 + csw;

    f32x4 acc[4][4];
#pragma unroll
    for (int mi = 0; mi < 4; ++mi)
#pragma unroll
        for (int ni = 0; ni < 4; ++ni)
#pragma unroll
            for (int r = 0; r < 4; ++r) acc[mi][ni][r] = 0.f;

    gll16(gArow, &sAh[0][r0 * 32]);
    gll16(gArow + (size_t)16 * D1, &sAh[0][(r0 + 16) * 32]);
    gll16(gBrow, &sBh[0][r0 * 32]);
    gll16(gBrow + (size_t)16 * D1, &sBh[0][(r0 + 16) * 32]);
    __syncthreads();

    int cur = 0;
    for (int k0 = 0; k0 < D1; k0 += 32) {
        int nxt = k0 + 32;
        if (nxt < D1) {
            gll16(gArow + nxt, &sAh[cur ^ 1][r0 * 32]);
            gll16(gArow + nxt + (size_t)16 * D1, &sAh[cur ^ 1][(r0 + 16) * 32]);
            gll16(gBrow + nxt, &sBh[cur ^ 1][r0 * 32]);
            gll16(gBrow + nxt + (size_t)16 * D1, &sBh[cur ^ 1][(r0 + 16) * 32]);
        }
        short8v ah[4], bh[4];
#pragma unroll
        for (int i = 0; i < 4; ++i) {
            ah[i] = *(const short8v*)&sAh[cur][swz(wp + i * 16 + fr, fq)];
            bh[i] = *(const short8v*)&sBh[cur][swz(wq + i * 16 + fr, fq)];
        }
        __builtin_amdgcn_s_setprio(1);
#pragma unroll
        for (int mi = 0; mi < 4; ++mi)
#pragma unroll
            for (int ni = 0; ni < 4; ++ni)
                acc[mi][ni] = __builtin_amdgcn_mfma_f32_16x16x32_bf16(ah[mi], bh[ni], acc[mi][ni], 0, 0, 0);
        __builtin_amdgcn_s_setprio(0);
        __syncthreads();
        cur ^= 1;
    }

#pragma unroll
    for (int ni = 0; ni < 4; ++ni) {
        int qq = qTile + wq + ni * 16 + fr;
        float gq = g[qq];
        float dq = dg[qq];
#pragma unroll
        for (int mi = 0; mi < 4; ++mi) {
            int pB = pTile + wp + mi * 16 + fq * 4;
#pragma unroll
            for (int r = 0; r < 4; ++r) {
                int p = pB + r;
                float v = acc[mi][ni][r] * gq;
                if (p == qq) v += dq;
                STP[(size_t)p * L + qq] = f2bf(v);
            }
        }
    }
    if (I != J) {
#pragma unroll
        for (int mi = 0; mi < 4; ++mi) {
            int p0 = pTile + wp + mi * 16 + fq * 4;
            float gp0 = g[p0], gp1 = g[p0 + 1], gp2 = g[p0 + 2], gp3 = g[p0 + 3];
#pragma unroll
            for (int ni = 0; ni < 4; ++ni) {
                int qq = qTile + wq + ni * 16 + fr;
                u16x4 mv;
                mv[0] = f2bf(acc[mi][ni][0] * gp0);
                mv[1] = f2bf(acc[mi][ni][1] * gp1);
                mv[2] = f2bf(acc[mi][ni][2] * gp2);
                mv[3] = f2bf(acc[mi][ni][3] * gp3);
                *(u16x4*)(STP + (size_t)qq * L + p0) = mv;
            }
        }
    }
}

// K6: softmax in-place (bf16) + exact argmax via candidate refinement
__global__ __launch_bounds__(256) void k_softmax(float* __restrict__ base,
                                                 const float* __restrict__ g0,
                                                 const float* __restrict__ dg0,
                                                 float* __restrict__ out1, int b0) {
    __shared__ float buf[L];
    __shared__ float red[256];
    __shared__ int candList[128];
    __shared__ int candCount;
    int bz = blockIdx.y;
    int b  = b0 + bz;
    float* S = base + (size_t)bz * SLOT_F;
    u16* STP = (u16*)S;
    const float* Wf = S + STP_F;
    const float* g  = g0  + (size_t)b * L;
    const float* dg = dg0 + (size_t)b * L;

    int p = blockIdx.x, t = threadIdx.x;
    u16* rowp = STP + (size_t)p * L;

    if (t == 0) candCount = 0;
    float mx = -3.4e38f;
    for (int i = t; i < L / 8; i += 256) {
        short8v v8 = ((const short8v*)rowp)[i];
#pragma unroll
        for (int j = 0; j < 8; ++j) {
            float v = bf2f((u16)v8[j]);
            buf[i * 8 + j] = v;
            mx = fmaxf(mx, v);
        }
    }
    red[t] = mx;
    __syncthreads();
    for (int o = 128; o > 0; o >>= 1) {
        if (t < o) red[t] = fmaxf(red[t], red[t + o]);
        __syncthreads();
    }
    float M = red[0];
    float u = fabsf(M) * 0.0625f + 1e-5f;
    float cth = M - u;
    __syncthreads();

    float s = 0.f;
    for (int i = t; i < L; i += 256) {
        float v = buf[i];
        if (v >= cth) {
            int ix = atomicAdd(&candCount, 1);
            if (ix < 128) candList[ix] = i;
        }
        float e = __expf(v - M);
        buf[i] = e;
        s += e;
    }
    red[t] = s;
    __syncthreads();
    for (int o = 128; o > 0; o >>= 1) {
        if (t < o) red[t] += red[t + o];
        __syncthreads();
    }
    float inv = 1.0f / red[0];
    __syncthreads();

    for (int i = t; i < L / 8; i += 256) {
        short8v o8;
#pragma unroll
        for (int j = 0; j < 8; ++j) o8[j] = (short)f2bf(buf[i * 8 + j] * inv);
        ((short8v*)rowp)[i] = o8;
    }
    __syncthreads();

    int nc = candCount; if (nc > 128) nc = 128;
    int bestI;
    if (nc == 1) {
        bestI = candList[0];
    } else {
        float bestE = -3.4e38f; bestI = L;
        const float* wp_ = Wf + (size_t)p * D1;
        for (int k = 0; k < nc; ++k) {
            int cand = candList[k];
            const float* wc = Wf + (size_t)cand * D1;
            float part = 0.f;
            for (int j = t; j < D1; j += 256) part += wp_[j] * wc[j];
            red[t] = part;
            __syncthreads();
            for (int o = 128; o > 0; o >>= 1) {
                if (t < o) red[t] += red[t + o];
                __syncthreads();
            }
            float e1 = red[0] * g[cand] + (p == cand ? dg[cand] : 0.f);
            if (e1 > bestE || (e1 == bestE && cand < bestI)) { bestE = e1; bestI = cand; }
            __syncthreads();
        }
    }
    if (t == 0) {
        out1[(size_t)(b * 2 + 0) * L + p] = (float)(bestI / WS - 32);
        out1[(size_t)(b * 2 + 1) * L + p] = (float)(bestI % WS - 32);
    }
}

// K7: At[n,q] = bf16(alpha patch), transposed (overwrites Wf region; batched over z)
__global__ __launch_bounds__(256) void k_buildA(const float* __restrict__ alpha,
                                                float* __restrict__ base, int b0) {
    int bz = blockIdx.z;
    int b  = b0 + bz;
    u16* At = (u16*)(base + (size_t)bz * SLOT_F + STP_F);
    int q = blockIdx.x * 256 + threadIdx.x;
    int n = blockIdx.y;
    int hs = q >> 6, ws = q & 63;
    int c = n >> 4, ki = (n >> 2) & 3, kj = n & 3;
    int rh = refl(2 * hs + ki - 1, H);
    int rw = refl(2 * ws + kj - 1, W_);
    At[(size_t)n * L + q] = f2bf(alpha[((size_t)b * CA + c) * H * W_ + rh * W_ + rw]);
}

// K8: 256^2-tile bf16 MFMA paste GEMM, 3-buffer counted-vmcnt pipeline.
// Z[p,n] = sum_q P[p,q]*At[n,q].  8 waves (2M x 4N), per-wave 128x64 out.
__global__ __launch_bounds__(512, 2) void k_gemm2(float* __restrict__ base) {
    __shared__ u16 smem[49152];   // 96 KB: 3 bufs x (A 16KB + B 16KB)
    int bz = blockIdx.z;
    float* S = base + (size_t)bz * SLOT_F;
    const u16* P  = (const u16*)S;
    const u16* At = (const u16*)(S + STP_F);
    u16* Z        = (u16*)(S + STP_F + WF_F);

    int tid = threadIdx.x;
    int wid = tid >> 6, lane = tid & 63;
    int wm = wid >> 2, wn = wid & 3;
    int nTile = blockIdx.x * 256, pTile = blockIdx.y * 256;
    int fr = lane & 15, fq = lane >> 4;

    f32x4 acc[8][4];
#pragma unroll
    for (int m = 0; m < 8; ++m)
#pragma unroll
        for (int n = 0; n < 4; ++n)
#pragma unroll
            for (int r = 0; r < 4; ++r) acc[m][n][r] = 0.f;

    // prologue: stage k-tiles 0,1 into bufs 0,1 (8 loads); wait tile 0 only
    stage32(P,  pTile, 0, smem,         wid, lane);
    stage32(At, nTile, 0, smem + 8192,  wid, lane);
    stage32(P,  pTile, 1, smem + 16384, wid, lane);
    stage32(At, nTile, 1, smem + 24576, wid, lane);
    asm volatile("s_waitcnt vmcnt(4)" ::: "memory");
    __builtin_amdgcn_s_barrier();
    __builtin_amdgcn_sched_barrier(0);

    for (int t = 0; t < NT2; ++t) {
        const u16* Ab = smem + (t % 3) * 16384;
        const u16* Bb = Ab + 8192;
        short8v a[8], b[4];
#pragma unroll
        for (int n = 0; n < 4; ++n) b[n] = rdfrag32(Bb, wn * 64 + n * 16 + fr, fq);
#pragma unroll
        for (int m = 0; m < 4; ++m) a[m] = rdfrag32(Ab, wm * 128 + m * 16 + fr, fq);
        __builtin_amdgcn_s_setprio(1);
#pragma unroll
        for (int m = 0; m < 2; ++m)
#pragma unroll
            for (int n = 0; n < 4; ++n)
                acc[m][n] = __builtin_amdgcn_mfma_f32_16x16x32_bf16(a[m], b[n], acc[m][n], 0, 0, 0);
        __builtin_amdgcn_s_setprio(0);
#pragma unroll
        for (int m = 4; m < 8; ++m) a[m] = rdfrag32(Ab, wm * 128 + m * 16 + fr, fq);
        __builtin_amdgcn_s_setprio(1);
#pragma unroll
        for (int m = 2; m < 6; ++m)
#pragma unroll
            for (int n = 0; n < 4; ++n)
                acc[m][n] = __builtin_amdgcn_mfma_f32_16x16x32_bf16(a[m], b[n], acc[m][n], 0, 0, 0);
        __builtin_amdgcn_s_setprio(0);
        // stage k-tile t+2 into buf (t+2)%3 (dead buffer; tile t-1 readers passed
        // the previous barrier). Dummy-stage kt=0 at the tail keeps vmcnt uniform.
        int kt2 = (t + 2 < NT2) ? (t + 2) : 0;
        u16* d2 = smem + ((t + 2) % 3) * 16384;
        stage32(P,  pTile, kt2, d2,        wid, lane);
        stage32(At, nTile, kt2, d2 + 8192, wid, lane);
        // counted wait: <=4 outstanding == exactly tile t+2's loads -> tile t+1 ready.
        asm volatile("s_waitcnt vmcnt(4)" ::: "memory");
        __builtin_amdgcn_sched_barrier(0);
        __builtin_amdgcn_s_setprio(1);
#pragma unroll
        for (int m = 6; m < 8; ++m)
#pragma unroll
            for (int n = 0; n < 4; ++n)
                acc[m][n] = __builtin_amdgcn_mfma_f32_16x16x32_bf16(a[m], b[n], acc[m][n], 0, 0, 0);
        __builtin_amdgcn_s_setprio(0);
        __builtin_amdgcn_s_barrier();
        __builtin_amdgcn_sched_barrier(0);
    }

#pragma unroll
    for (int m = 0; m < 8; ++m)
#pragma unroll
        for (int n = 0; n < 4; ++n) {
            int nn = nTile + wn * 64 + n * 16 + fr;
#pragma unroll
            for (int r = 0; r < 4; ++r) {
                int pp = pTile + wm * 128 + m * 16 + fq * 4 + r;
                Z[(size_t)pp * D2 + nn] = f2bf(acc[m][n][r]);
            }
        }
}

// K9: transposed-conv gather -> yt[pix, c] bf16 (batched over z)
__global__ __launch_bounds__(256) void k_gather(float* __restrict__ base,
                                                u16* __restrict__ yt, int b0) {
    int bz = blockIdx.z;
    int b  = b0 + bz;
    const u16* Z = (const u16*)(base + (size_t)bz * SLOT_F + STP_F + WF_F);
    int c  = threadIdx.x & 127;
    int pl = threadIdx.x >> 7;
    int w  = blockIdx.x * 2 + pl;
    int h  = blockIdx.y;
    float s = 0.f;
#pragma unroll
    for (int ki = 0; ki < 4; ++ki) {
        int num = h + 1 - ki;
        if (num < 0 || (num & 1)) continue;
        int hs = num >> 1;
        if (hs >= HS) continue;
#pragma unroll
        for (int kj = 0; kj < 4; ++kj) {
            int numw = w + 1 - kj;
            if (numw < 0 || (numw & 1)) continue;
            int wsd = numw >> 1;
            if (wsd >= WS) continue;
            s += bf2f(Z[(size_t)(hs * WS + wsd) * D2 + c * 16 + ki * 4 + kj]);
        }
    }
    int pix = h * W_ + w;
    int cs = c ^ ((pix & 7) << 3);
    yt[((size_t)b * 16384 + pix) * 128 + cs] = f2bf(0.25f * s);
}

__global__ __launch_bounds__(256) void k_cvtww(const float* __restrict__ ww,
                                               u16* __restrict__ wwbf) {
    int i = blockIdx.x * 256 + threadIdx.x;
    int o = i >> 7, c = i & 127;
    wwbf[o * 128 + (c ^ ((o & 7) << 3))] = f2bf(ww[i]);
}

// K10: yw[o, gp] = sum_c w_w[o,c] * y[gp, c]   MFMA, K=128
__global__ __launch_bounds__(256) void k_ywgemm(const u16* __restrict__ wwbf,
                                                const u16* __restrict__ yt,
                                                float* __restrict__ yw) {
    __shared__ u16 sA[128 * 128], sB[128 * 128];
    int tid = threadIdx.x;
    int wv = tid >> 6, lane = tid & 63;
    int nTile = blockIdx.x * 128;
    int wp = (wv >> 1) * 64, wn = (wv & 1) * 64;
    int fr = lane & 15, fq = lane >> 4;

    const u16* gB = yt + (size_t)nTile * 128;
#pragma unroll
    for (int i = 0; i < 8; ++i) {
        int o = (i * 4 + wv) * 512;
        gll16(wwbf + o + lane * 8, &sA[o]);
        gll16(gB + o + lane * 8, &sB[o]);
    }
    __syncthreads();

    f32x4 acc[4][4];
#pragma unroll
    for (int mi = 0; mi < 4; ++mi)
#pragma unroll
        for (int ni = 0; ni < 4; ++ni)
#pragma unroll
            for (int r = 0; r < 4; ++r) acc[mi][ni][r] = 0.f;

#pragma unroll
    for (int ks = 0; ks < 4; ++ks) {
        int k0 = ks * 32 + fq * 8;
        short8v a[4], bb[4];
#pragma unroll
        for (int i = 0; i < 4; ++i) {
            int ra = wp + i * 16 + fr;
            a[i] = *(const short8v*)&sA[ra * 128 + (k0 ^ ((ra & 7) << 3))];
            int rb = wn + i * 16 + fr;
            bb[i] = *(const short8v*)&sB[rb * 128 + (k0 ^ ((rb & 7) << 3))];
        }
#pragma unroll
        for (int mi = 0; mi < 4; ++mi)
#pragma unroll
            for (int ni = 0; ni < 4; ++ni)
                acc[mi][ni] = __builtin_amdgcn_mfma_f32_16x16x32_bf16(a[mi], bb[ni], acc[mi][ni], 0, 0, 0);
    }

#pragma unroll
    for (int mi = 0; mi < 4; ++mi)
#pragma unroll
        for (int ni = 0; ni < 4; ++ni) {
            int gp = nTile + wn + ni * 16 + fr;
#pragma unroll
            for (int r = 0; r < 4; ++r) {
                int o = wp + mi * 16 + fq * 4 + r;
                yw[(size_t)o * NPIX + gp] = acc[mi][ni][r];
            }
        }
}

__global__ __launch_bounds__(256) void k_stats(const float* __restrict__ yw,
                                               float* __restrict__ meanvar) {
    int o = blockIdx.x, t = threadIdx.x;
    __shared__ float rs[256], rq[256];
    float s = 0.f, q = 0.f;
    const float* p = yw + (size_t)o * NPIX;
    for (int i = t; i < NPIX; i += 256) {
        float v = p[i];
        s += v;
        q += v * v;
    }
    rs[t] = s; rq[t] = q;
    __syncthreads();
    for (int off = 128; off > 0; off >>= 1) {
        if (t < off) { rs[t] += rs[t + off]; rq[t] += rq[t + off]; }
        __syncthreads();
    }
    if (t == 0) {
        float n = (float)NPIX;
        float mean = rs[0] / n;
        float var  = rq[0] / n - mean * mean;
        meanvar[o] = mean;
        meanvar[CA + o] = var;
    }
}

__global__ __launch_bounds__(256) void k_final(const float* __restrict__ yw,
                                               const float* __restrict__ meanvar,
                                               const float* __restrict__ gamma,
                                               const float* __restrict__ beta,
                                               const float* __restrict__ alpha,
                                               float* __restrict__ out0) {
    size_t i = ((size_t)blockIdx.x * 256 + threadIdx.x) * 4;
    int c = (int)((i >> 14) & 127);
    int b = (int)(i >> 21);
    int pix = (int)(i & 16383);
    float4 v = *(const float4*)(yw + (size_t)c * NPIX + b * 16384 + pix);
    float4 a = *(const float4*)(alpha + i);
    float mean = meanvar[c];
    float var  = meanvar[CA + c];
    float sc   = rsqrtf(var + 1e-5f) * gamma[c];
    float bt   = beta[c];
    float4 r;
    r.x = (v.x - mean) * sc + bt + a.x;
    r.y = (v.y - mean) * sc + bt + a.y;
    r.z = (v.z - mean) * sc + bt + a.z;
    r.w = (v.w - mean) * sc + bt + a.w;
    *(float4*)(out0 + i) = r;
}

extern "C" void kernel_launch(void* const* d_in, const int* in_sizes, int n_in,
                              void* d_out, int out_size, void* d_ws, size_t ws_size,
                              hipStream_t stream) {
    (void)in_sizes; (void)n_in; (void)out_size;
    const float* f     = (const float*)d_in[0];
    const float* alpha = (const float*)d_in[1];
    const float* unk   = (const float*)d_in[2];
    const float* gw    = (const float*)d_in[3];
    const float* gb    = (const float*)d_in[4];
    const float* ww    = (const float*)d_in[5];
    const float* gamma = (const float*)d_in[6];
    const float* beta  = (const float*)d_in[7];

    float* out0 = (float*)d_out;
    float* out1 = out0 + (size_t)B * CA * H * W_;
    float* out2 = out1 + (size_t)B * 2 * HS * WS;

    // ---- persistent region ----
    float* wsf = (float*)d_ws;
    size_t off = 0;
    float* fds     = wsf + off; off += (size_t)B * CM * HS * WS;
    float* ssq     = wsf + off; off += (size_t)B * HS * WS;
    float* gbuf    = wsf + off; off += (size_t)B * L;
    float* dgbuf   = wsf + off; off += (size_t)B * L;
    float* suk     = wsf + off; off += 64;
    float* ytF     = wsf + off; off += (size_t)NPIX * 128 / 2;
    float* wwbfF   = wsf + off; off += 8192;
    float* meanvar = wsf + off; off += 256;
    float* base    = wsf + off;

    const size_t PRE_F = off;
    int nb = (ws_size >= (PRE_F + 4 * SLOT_F) * sizeof(float)) ? 4 : 2;

    float* yw   = base;
    u16*   yt   = (u16*)ytF;
    u16*   wwbf = (u16*)wwbfF;

    k_cvtww<<<64, 256, 0, stream>>>(ww, wwbf);
    k_conv_ds<<<dim3(64, 4), 256, 0, stream>>>(f, gw, gb, fds, ssq);
    k_scale<<<4, 256, 0, stream>>>(unk, suk, out2);
    k_gate<<<dim3(64, 4), 64, 0, stream>>>(unk, ssq, suk, gbuf, dgbuf);

    for (int b0 = 0; b0 < B; b0 += nb) {
        k_buildW<<<dim3(64, 32, nb), dim3(64, 4), 0, stream>>>(fds, base, b0);
        k_gemm1<<<dim3(528, 1, nb), 256, 0, stream>>>(base, gbuf, dgbuf, b0);
        k_softmax<<<dim3(4096, nb), 256, 0, stream>>>(base, gbuf, dgbuf, out1, b0);
        k_buildA<<<dim3(16, 2048, nb), 256, 0, stream>>>(alpha, base, b0);
        k_gemm2<<<dim3(8, 16, nb), 512, 0, stream>>>(base);
        k_gather<<<dim3(64, 128, nb), 256, 0, stream>>>(base, yt, b0);
    }

    k_ywgemm<<<512, 256, 0, stream>>>(wwbf, yt, yw);
    k_stats<<<128, 256, 0, stream>>>(yw, meanvar);
    k_final<<<8192, 256, 0, stream>>>(yw, meanvar, gamma, beta, alpha, out0);
}

// Round 9
// 863.161 us; speedup vs baseline: 1.4946x; 1.0163x over previous
//
#include <hip/hip_runtime.h>
#include <math.h>

#define B 4
#define CG 256
#define CM 128
#define CA 128
#define H 128
#define W_ 128
#define HS 64
#define WS 64
#define L 4096
#define D1 1152
#define D2 2048
#define NPIX 65536
#define NT2 128   // L/32 k-tiles for gemm2

// slot layout (floats): [STP bf16 L*L][Wf fp32 -> At bf16][Whi bf16 -> Z bf16]
#define STP_F 8388608UL
#define WF_F  4718592UL
#define ZB_F  4194304UL
#define SLOT_F (STP_F + WF_F + ZB_F)   // 17,301,504 floats = 69.2 MB

typedef unsigned short u16;
typedef __attribute__((ext_vector_type(8))) short short8v;
typedef __attribute__((ext_vector_type(4))) unsigned short u16x4;
typedef __attribute__((ext_vector_type(4))) float f32x4;

__device__ __forceinline__ float bf2f(u16 x) {
    union { unsigned int u; float f; } v; v.u = ((unsigned int)x) << 16; return v.f;
}
__device__ __forceinline__ u16 f2bf(float x) {
    union { float f; unsigned int u; } v; v.f = x;
    unsigned int r = (v.u + 0x7FFFu + ((v.u >> 16) & 1u)) >> 16;
    return (u16)r;
}
__device__ __forceinline__ void gll16(const void* g, void* l) {
    __builtin_amdgcn_global_load_lds((const __attribute__((address_space(1))) void*)g,
                                     (__attribute__((address_space(3))) void*)l, 16, 0, 0);
}
__device__ __forceinline__ int refl(int i, int n) {
    return i < 0 ? -i : (i >= n ? 2 * n - 2 - i : i);
}
// swizzled LDS element offset for [128][32 u16] tiles: 16B-chunk XOR (gemm1; 0-conflict per R5)
__device__ __forceinline__ int swz(int row, int fq) {
    return row * 32 + ((fq ^ ((row >> 1) & 3)) * 8);
}

// ---- gemm2 256^2 pipeline helpers: [256][32 u16] tiles, 64B rows ----
// (r>>1)&3 swizzle: 16 consecutive rows tile all 32 banks exactly 2x (free 2-way).
__device__ __forceinline__ void stage32(const u16* __restrict__ mat, int rowTile,
                                        int kt, u16* lds, int wid, int lane) {
#pragma unroll
    for (int c = 0; c < 2; ++c) {
        int off = c * 8192 + wid * 1024 + lane * 16;   // byte offset in tile
        int row = off >> 6;
        int cb  = off & 63;
        const u16* g = mat + (size_t)(rowTile + row) * L + kt * 32
                     + ((cb ^ (((row >> 1) & 3) << 4)) >> 1);
        gll16(g, (char*)lds + c * 8192 + wid * 1024);  // wave-uniform base; HW adds lane*16
    }
}
__device__ __forceinline__ short8v rdfrag32(const u16* lds, int r, int fq) {
    return *(const short8v*)((const char*)lds + r * 64 + ((fq * 16) ^ (((r >> 1) & 3) << 4)));
}

// K0: f_ds = 1x1 conv at even pixels + fused ssq
__global__ __launch_bounds__(256) void k_conv_ds(const float* __restrict__ f,
                                                 const float* __restrict__ gw,
                                                 const float* __restrict__ gb,
                                                 float* __restrict__ fds,
                                                 float* __restrict__ ssq) {
    __shared__ float sf[CG * 64];
    __shared__ float part[4][64];
    int t = threadIdx.x;
    int hs = blockIdx.x, b = blockIdx.y;
    const float* fb = f + (size_t)b * CG * H * W_ + (2 * hs) * W_;
    for (int idx = t; idx < CG * 64; idx += 256) {
        int ci = idx >> 6, ws = idx & 63;
        sf[idx] = fb[(size_t)ci * H * W_ + 2 * ws];
    }
    __syncthreads();
    int ws = t & 63;
    int wave = __builtin_amdgcn_readfirstlane(t >> 6);
    const float* gwp = gw + (size_t)(wave * 32) * CG;
    float acc[32];
#pragma unroll
    for (int r = 0; r < 32; ++r) acc[r] = gb[wave * 32 + r];
    for (int ci = 0; ci < CG; ++ci) {
        float fv = sf[ci * 64 + ws];
#pragma unroll
        for (int r = 0; r < 32; ++r) acc[r] += gwp[r * CG + ci] * fv;
    }
    float sq = 0.f;
#pragma unroll
    for (int r = 0; r < 32; ++r) {
        int co = wave * 32 + r;
        fds[(((size_t)b * CM + co) * HS + hs) * WS + ws] = acc[r];
        sq += acc[r] * acc[r];
    }
    part[wave][ws] = sq;
    __syncthreads();
    if (t < 64)
        ssq[((size_t)b * HS + hs) * WS + t] =
            part[0][t] + part[1][t] + part[2][t] + part[3][t];
}

__global__ __launch_bounds__(256) void k_scale(const float* __restrict__ unk,
                                               float* __restrict__ suk,
                                               float* __restrict__ out2) {
    int b = blockIdx.x, t = threadIdx.x;
    __shared__ float red[256];
    float s = 0.f;
    for (int i = t; i < L; i += 256) {
        int hs = i >> 6, ws = i & 63;
        s += unk[(size_t)b * H * W_ + (2 * hs) * W_ + 2 * ws];
    }
    red[t] = s;
    __syncthreads();
    for (int o = 128; o > 0; o >>= 1) {
        if (t < o) red[t] += red[t + o];
        __syncthreads();
    }
    if (t == 0) {
        float u = red[0] / (float)L;
        float k = 1.0f - u;
        float su = sqrtf(u / k); su = fminf(fmaxf(su, 0.1f), 10.0f);
        float sk = sqrtf(k / u); sk = fminf(fmaxf(sk, 0.1f), 10.0f);
        suk[b * 2] = su; suk[b * 2 + 1] = sk;
        out2[b * 2] = su; out2[b * 2 + 1] = sk;
    }
}

__global__ __launch_bounds__(64) void k_gate(const float* __restrict__ unk,
                                             const float* __restrict__ ssq,
                                             const float* __restrict__ suk,
                                             float* __restrict__ g,
                                             float* __restrict__ dg) {
    int ws = threadIdx.x, hs = blockIdx.x, b = blockIdx.y;
    float sm = 0.f, sq = 0.f;
    for (int di = -1; di <= 1; ++di) {
        int rh = refl(hs + di, HS);
        for (int dj = -1; dj <= 1; ++dj) {
            int rw = refl(ws + dj, WS);
            sm += unk[(size_t)b * H * W_ + (2 * rh) * W_ + 2 * rw];
            sq += ssq[((size_t)b * HS + rh) * WS + rw];
        }
    }
    float mm   = (sm > 0.0f) ? 1.0f : 0.0f;
    float norm = sqrtf(sq);
    float gate = (mm > 0.0f) ? suk[2 * b] : suk[2 * b + 1];
    int q = hs * WS + ws;
    g[(size_t)b * L + q]  = gate / fmaxf(norm, 1e-4f);
    dg[(size_t)b * L + q] = -10000.0f * mm;
}

// K4: fp32 W + bf16 W (batched over z)
__global__ __launch_bounds__(256) void k_buildW(const float* __restrict__ fds,
                                                float* __restrict__ base, int b0) {
    int bz = blockIdx.z;
    int b  = b0 + bz;
    float* S   = base + (size_t)bz * SLOT_F;
    float* Wf  = S + STP_F;
    u16*   Whi = (u16*)(S + STP_F + WF_F);
    int ws = threadIdx.x;
    int c  = blockIdx.y * 4 + threadIdx.y;
    int hs = blockIdx.x;
    int q = hs * WS + ws;
    size_t bo = (size_t)q * D1 + c * 9;
    const float* src = fds + ((size_t)b * CM + c) * HS * WS;
#pragma unroll
    for (int i = 0; i < 3; ++i) {
        int rh = refl(hs + i - 1, HS);
#pragma unroll
        for (int j = 0; j < 3; ++j) {
            int rw = refl(ws + j - 1, WS);
            float v = src[rh * WS + rw];
            Wf[bo + i * 3 + j]  = v;
            Whi[bo + i * 3 + j] = f2bf(v);
        }
    }
}

// K5: symmetric bf16 MFMA score GEMM -> bf16 ST (upper-tri + mirror, dbuf pipeline)
__global__ __launch_bounds__(256) void k_gemm1(float* __restrict__ base,
                                               const float* __restrict__ g0,
                                               const float* __restrict__ dg0,
                                               int b0) {
    __shared__ u16 sAh[2][128 * 32], sBh[2][128 * 32];
    int bz = blockIdx.z;
    float* S = base + (size_t)bz * SLOT_F;
    u16* STP = (u16*)S;
    const u16* Whi = (const u16*)(S + STP_F + WF_F);
    const float* g  = g0  + (size_t)(b0 + bz) * L;
    const float* dg = dg0 + (size_t)(b0 + bz) * L;

    int tid = threadIdx.x;
    int wv = tid >> 6, lane = tid & 63;
    int t = blockIdx.x, I = 0;
    while (t >= 32 - I) { t -= 32 - I; ++I; }
    int J = I + t;
    int pTile = I * 128, qTile = J * 128;
    int wp = (wv >> 1) * 64, wq = (wv & 1) * 64;
    int r0 = wv * 32;
    int lrow = lane >> 2;
    int csw = ((lane & 3) ^ ((lrow >> 1) & 3)) * 8;
    int fr = lane & 15, fq = lane >> 4;

    const u16* gArow = Whi + (size_t)(pTile + r0 + lrow) * D1 + csw;
    const u16* gBrow = Whi + (size_t)(qTile + r0 + lrow) * D1 + csw;

    f32x4 acc[4][4];
#pragma unroll
    for (int mi = 0; mi < 4; ++mi)
#pragma unroll
        for (int ni = 0; ni < 4; ++ni)
#pragma unroll
            for (int r = 0; r < 4; ++r) acc[mi][ni][r] = 0.f;

    gll16(gArow, &sAh[0][r0 * 32]);
    gll16(gArow + (size_t)16 * D1, &sAh[0][(r0 + 16) * 32]);
    gll16(gBrow, &sBh[0][r0 * 32]);
    gll16(gBrow + (size_t)16 * D1, &sBh[0][(r0 + 16) * 32]);
    __syncthreads();

    int cur = 0;
    for (int k0 = 0; k0 < D1; k0 += 32) {
        int nxt = k0 + 32;
        if (nxt < D1) {
            gll16(gArow + nxt, &sAh[cur ^ 1][r0 * 32]);
            gll16(gArow + nxt + (size_t)16 * D1, &sAh[cur ^ 1][(r0 + 16) * 32]);
            gll16(gBrow + nxt, &sBh[cur ^ 1][r0 * 32]);
            gll16(gBrow + nxt + (size_t)16 * D1, &sBh[cur ^ 1][(r0 + 16) * 32]);
        }
        short8v ah[4], bh[4];
#pragma unroll
        for (int i = 0; i < 4; ++i) {
            ah[i] = *(const short8v*)&sAh[cur][swz(wp + i * 16 + fr, fq)];
            bh[i] = *(const short8v*)&sBh[cur][swz(wq + i * 16 + fr, fq)];
        }
        __builtin_amdgcn_s_setprio(1);
#pragma unroll
        for (int mi = 0; mi < 4; ++mi)
#pragma unroll
            for (int ni = 0; ni < 4; ++ni)
                acc[mi][ni] = __builtin_amdgcn_mfma_f32_16x16x32_bf16(ah[mi], bh[ni], acc[mi][ni], 0, 0, 0);
        __builtin_amdgcn_s_setprio(0);
        __syncthreads();
        cur ^= 1;
    }

#pragma unroll
    for (int ni = 0; ni < 4; ++ni) {
        int qq = qTile + wq + ni * 16 + fr;
        float gq = g[qq];
        float dq = dg[qq];
#pragma unroll
        for (int mi = 0; mi < 4; ++mi) {
            int pB = pTile + wp + mi * 16 + fq * 4;
#pragma unroll
            for (int r = 0; r < 4; ++r) {
                int p = pB + r;
                float v = acc[mi][ni][r] * gq;
                if (p == qq) v += dq;
                STP[(size_t)p * L + qq] = f2bf(v);
            }
        }
    }
    if (I != J) {
#pragma unroll
        for (int mi = 0; mi < 4; ++mi) {
            int p0 = pTile + wp + mi * 16 + fq * 4;
            float gp0 = g[p0], gp1 = g[p0 + 1], gp2 = g[p0 + 2], gp3 = g[p0 + 3];
#pragma unroll
            for (int ni = 0; ni < 4; ++ni) {
                int qq = qTile + wq + ni * 16 + fr;
                u16x4 mv;
                mv[0] = f2bf(acc[mi][ni][0] * gp0);
                mv[1] = f2bf(acc[mi][ni][1] * gp1);
                mv[2] = f2bf(acc[mi][ni][2] * gp2);
                mv[3] = f2bf(acc[mi][ni][3] * gp3);
                *(u16x4*)(STP + (size_t)qq * L + p0) = mv;
            }
        }
    }
}

// K6: softmax in-place (bf16) + exact argmax via candidate refinement
__global__ __launch_bounds__(256) void k_softmax(float* __restrict__ base,
                                                 const float* __restrict__ g0,
                                                 const float* __restrict__ dg0,
                                                 float* __restrict__ out1, int b0) {
    __shared__ float buf[L];
    __shared__ float red[256];
    __shared__ int candList[128];
    __shared__ int candCount;
    int bz = blockIdx.y;
    int b  = b0 + bz;
    float* S = base + (size_t)bz * SLOT_F;
    u16* STP = (u16*)S;
    const float* Wf = S + STP_F;
    const float* g  = g0  + (size_t)b * L;
    const float* dg = dg0 + (size_t)b * L;

    int p = blockIdx.x, t = threadIdx.x;
    u16* rowp = STP + (size_t)p * L;

    if (t == 0) candCount = 0;
    float mx = -3.4e38f;
    for (int i = t; i < L / 8; i += 256) {
        short8v v8 = ((const short8v*)rowp)[i];
#pragma unroll
        for (int j = 0; j < 8; ++j) {
            float v = bf2f((u16)v8[j]);
            buf[i * 8 + j] = v;
            mx = fmaxf(mx, v);
        }
    }
    red[t] = mx;
    __syncthreads();
    for (int o = 128; o > 0; o >>= 1) {
        if (t < o) red[t] = fmaxf(red[t], red[t + o]);
        __syncthreads();
    }
    float M = red[0];
    float u = fabsf(M) * 0.0625f + 1e-5f;
    float cth = M - u;
    __syncthreads();

    float s = 0.f;
    for (int i = t; i < L; i += 256) {
        float v = buf[i];
        if (v >= cth) {
            int ix = atomicAdd(&candCount, 1);
            if (ix < 128) candList[ix] = i;
        }
        float e = __expf(v - M);
        buf[i] = e;
        s += e;
    }
    red[t] = s;
    __syncthreads();
    for (int o = 128; o > 0; o >>= 1) {
        if (t < o) red[t] += red[t + o];
        __syncthreads();
    }
    float inv = 1.0f / red[0];
    __syncthreads();

    for (int i = t; i < L / 8; i += 256) {
        short8v o8;
#pragma unroll
        for (int j = 0; j < 8; ++j) o8[j] = (short)f2bf(buf[i * 8 + j] * inv);
        ((short8v*)rowp)[i] = o8;
    }
    __syncthreads();

    int nc = candCount; if (nc > 128) nc = 128;
    int bestI;
    if (nc == 1) {
        bestI = candList[0];
    } else {
        float bestE = -3.4e38f; bestI = L;
        const float* wp_ = Wf + (size_t)p * D1;
        for (int k = 0; k < nc; ++k) {
            int cand = candList[k];
            const float* wc = Wf + (size_t)cand * D1;
            float part = 0.f;
            for (int j = t; j < D1; j += 256) part += wp_[j] * wc[j];
            red[t] = part;
            __syncthreads();
            for (int o = 128; o > 0; o >>= 1) {
                if (t < o) red[t] += red[t + o];
                __syncthreads();
            }
            float e1 = red[0] * g[cand] + (p == cand ? dg[cand] : 0.f);
            if (e1 > bestE || (e1 == bestE && cand < bestI)) { bestE = e1; bestI = cand; }
            __syncthreads();
        }
    }
    if (t == 0) {
        out1[(size_t)(b * 2 + 0) * L + p] = (float)(bestI / WS - 32);
        out1[(size_t)(b * 2 + 1) * L + p] = (float)(bestI % WS - 32);
    }
}

// K7: At[n,q] = bf16(alpha patch), transposed (overwrites Wf region; batched over z)
__global__ __launch_bounds__(256) void k_buildA(const float* __restrict__ alpha,
                                                float* __restrict__ base, int b0) {
    int bz = blockIdx.z;
    int b  = b0 + bz;
    u16* At = (u16*)(base + (size_t)bz * SLOT_F + STP_F);
    int q = blockIdx.x * 256 + threadIdx.x;
    int n = blockIdx.y;
    int hs = q >> 6, ws = q & 63;
    int c = n >> 4, ki = (n >> 2) & 3, kj = n & 3;
    int rh = refl(2 * hs + ki - 1, H);
    int rw = refl(2 * ws + kj - 1, W_);
    At[(size_t)n * L + q] = f2bf(alpha[((size_t)b * CA + c) * H * W_ + rh * W_ + rw]);
}

// K8: 256^2-tile bf16 MFMA paste GEMM, 3-buffer counted-vmcnt pipeline.
// Grid: x = pTile (16) so XCD = x%8 -> each XCD owns 2 P panels x all nTiles (T1).
__global__ __launch_bounds__(512, 2) void k_gemm2(float* __restrict__ base) {
    __shared__ u16 smem[49152];   // 96 KB: 3 bufs x (A 16KB + B 16KB)
    int bz = blockIdx.z;
    float* S = base + (size_t)bz * SLOT_F;
    const u16* P  = (const u16*)S;
    const u16* At = (const u16*)(S + STP_F);
    u16* Z        = (u16*)(S + STP_F + WF_F);

    int tid = threadIdx.x;
    int wid = tid >> 6, lane = tid & 63;
    int wm = wid >> 2, wn = wid & 3;
    int pTile = blockIdx.x * 256, nTile = blockIdx.y * 256;
    int fr = lane & 15, fq = lane >> 4;

    f32x4 acc[8][4];
#pragma unroll
    for (int m = 0; m < 8; ++m)
#pragma unroll
        for (int n = 0; n < 4; ++n)
#pragma unroll
            for (int r = 0; r < 4; ++r) acc[m][n][r] = 0.f;

    // prologue: stage k-tiles 0,1 into bufs 0,1 (8 loads); wait tile 0 only
    stage32(P,  pTile, 0, smem,         wid, lane);
    stage32(At, nTile, 0, smem + 8192,  wid, lane);
    stage32(P,  pTile, 1, smem + 16384, wid, lane);
    stage32(At, nTile, 1, smem + 24576, wid, lane);
    asm volatile("s_waitcnt vmcnt(4)" ::: "memory");
    __builtin_amdgcn_s_barrier();
    __builtin_amdgcn_sched_barrier(0);

    for (int t = 0; t < NT2; ++t) {
        const u16* Ab = smem + (t % 3) * 16384;
        const u16* Bb = Ab + 8192;
        short8v a[8], b[4];
#pragma unroll
        for (int n = 0; n < 4; ++n) b[n] = rdfrag32(Bb, wn * 64 + n * 16 + fr, fq);
#pragma unroll
        for (int m = 0; m < 4; ++m) a[m] = rdfrag32(Ab, wm * 128 + m * 16 + fr, fq);
        __builtin_amdgcn_s_setprio(1);
#pragma unroll
        for (int m = 0; m < 2; ++m)
#pragma unroll
            for (int n = 0; n < 4; ++n)
                acc[m][n] = __builtin_amdgcn_mfma_f32_16x16x32_bf16(a[m], b[n], acc[m][n], 0, 0, 0);
        __builtin_amdgcn_s_setprio(0);
#pragma unroll
        for (int m = 4; m < 8; ++m) a[m] = rdfrag32(Ab, wm * 128 + m * 16 + fr, fq);
        __builtin_amdgcn_s_setprio(1);
#pragma unroll
        for (int m = 2; m < 6; ++m)
#pragma unroll
            for (int n = 0; n < 4; ++n)
                acc[m][n] = __builtin_amdgcn_mfma_f32_16x16x32_bf16(a[m], b[n], acc[m][n], 0, 0, 0);
        __builtin_amdgcn_s_setprio(0);
        // stage k-tile t+2 into buf (t+2)%3; dummy-stage kt=0 at tail keeps vmcnt uniform
        int kt2 = (t + 2 < NT2) ? (t + 2) : 0;
        u16* d2 = smem + ((t + 2) % 3) * 16384;
        stage32(P,  pTile, kt2, d2,        wid, lane);
        stage32(At, nTile, kt2, d2 + 8192, wid, lane);
        // counted wait: <=4 outstanding == exactly tile t+2's loads -> tile t+1 ready
        asm volatile("s_waitcnt vmcnt(4)" ::: "memory");
        __builtin_amdgcn_sched_barrier(0);
        __builtin_amdgcn_s_setprio(1);
#pragma unroll
        for (int m = 6; m < 8; ++m)
#pragma unroll
            for (int n = 0; n < 4; ++n)
                acc[m][n] = __builtin_amdgcn_mfma_f32_16x16x32_bf16(a[m], b[n], acc[m][n], 0, 0, 0);
        __builtin_amdgcn_s_setprio(0);
        __builtin_amdgcn_s_barrier();
        __builtin_amdgcn_sched_barrier(0);
    }

#pragma unroll
    for (int m = 0; m < 8; ++m)
#pragma unroll
        for (int n = 0; n < 4; ++n) {
            int nn = nTile + wn * 64 + n * 16 + fr;
#pragma unroll
            for (int r = 0; r < 4; ++r) {
                int pp = pTile + wm * 128 + m * 16 + fq * 4 + r;
                Z[(size_t)pp * D2 + nn] = f2bf(acc[m][n][r]);
            }
        }
}

// K9: transposed-conv gather -> yt[pix, c] bf16 (batched over z)
__global__ __launch_bounds__(256) void k_gather(float* __restrict__ base,
                                                u16* __restrict__ yt, int b0) {
    int bz = blockIdx.z;
    int b  = b0 + bz;
    const u16* Z = (const u16*)(base + (size_t)bz * SLOT_F + STP_F + WF_F);
    int c  = threadIdx.x & 127;
    int pl = threadIdx.x >> 7;
    int w  = blockIdx.x * 2 + pl;
    int h  = blockIdx.y;
    float s = 0.f;
#pragma unroll
    for (int ki = 0; ki < 4; ++ki) {
        int num = h + 1 - ki;
        if (num < 0 || (num & 1)) continue;
        int hs = num >> 1;
        if (hs >= HS) continue;
#pragma unroll
        for (int kj = 0; kj < 4; ++kj) {
            int numw = w + 1 - kj;
            if (numw < 0 || (numw & 1)) continue;
            int wsd = numw >> 1;
            if (wsd >= WS) continue;
            s += bf2f(Z[(size_t)(hs * WS + wsd) * D2 + c * 16 + ki * 4 + kj]);
        }
    }
    int pix = h * W_ + w;
    int cs = c ^ ((pix & 7) << 3);
    yt[((size_t)b * 16384 + pix) * 128 + cs] = f2bf(0.25f * s);
}

__global__ __launch_bounds__(256) void k_cvtww(const float* __restrict__ ww,
                                               u16* __restrict__ wwbf) {
    int i = blockIdx.x * 256 + threadIdx.x;
    int o = i >> 7, c = i & 127;
    wwbf[o * 128 + (c ^ ((o & 7) << 3))] = f2bf(ww[i]);
}

// K10: yw[o, gp] = sum_c w_w[o,c] * y[gp, c]   MFMA, K=128
__global__ __launch_bounds__(256) void k_ywgemm(const u16* __restrict__ wwbf,
                                                const u16* __restrict__ yt,
                                                float* __restrict__ yw) {
    __shared__ u16 sA[128 * 128], sB[128 * 128];
    int tid = threadIdx.x;
    int wv = tid >> 6, lane = tid & 63;
    int nTile = blockIdx.x * 128;
    int wp = (wv >> 1) * 64, wn = (wv & 1) * 64;
    int fr = lane & 15, fq = lane >> 4;

    const u16* gB = yt + (size_t)nTile * 128;
#pragma unroll
    for (int i = 0; i < 8; ++i) {
        int o = (i * 4 + wv) * 512;
        gll16(wwbf + o + lane * 8, &sA[o]);
        gll16(gB + o + lane * 8, &sB[o]);
    }
    __syncthreads();

    f32x4 acc[4][4];
#pragma unroll
    for (int mi = 0; mi < 4; ++mi)
#pragma unroll
        for (int ni = 0; ni < 4; ++ni)
#pragma unroll
            for (int r = 0; r < 4; ++r) acc[mi][ni][r] = 0.f;

#pragma unroll
    for (int ks = 0; ks < 4; ++ks) {
        int k0 = ks * 32 + fq * 8;
        short8v a[4], bb[4];
#pragma unroll
        for (int i = 0; i < 4; ++i) {
            int ra = wp + i * 16 + fr;
            a[i] = *(const short8v*)&sA[ra * 128 + (k0 ^ ((ra & 7) << 3))];
            int rb = wn + i * 16 + fr;
            bb[i] = *(const short8v*)&sB[rb * 128 + (k0 ^ ((rb & 7) << 3))];
        }
#pragma unroll
        for (int mi = 0; mi < 4; ++mi)
#pragma unroll
            for (int ni = 0; ni < 4; ++ni)
                acc[mi][ni] = __builtin_amdgcn_mfma_f32_16x16x32_bf16(a[mi], bb[ni], acc[mi][ni], 0, 0, 0);
    }

#pragma unroll
    for (int mi = 0; mi < 4; ++mi)
#pragma unroll
        for (int ni = 0; ni < 4; ++ni) {
            int gp = nTile + wn + ni * 16 + fr;
#pragma unroll
            for (int r = 0; r < 4; ++r) {
                int o = wp + mi * 16 + fq * 4 + r;
                yw[(size_t)o * NPIX + gp] = acc[mi][ni][r];
            }
        }
}

__global__ __launch_bounds__(256) void k_stats(const float* __restrict__ yw,
                                               float* __restrict__ meanvar) {
    int o = blockIdx.x, t = threadIdx.x;
    __shared__ float rs[256], rq[256];
    float s = 0.f, q = 0.f;
    const float* p = yw + (size_t)o * NPIX;
    for (int i = t; i < NPIX; i += 256) {
        float v = p[i];
        s += v;
        q += v * v;
    }
    rs[t] = s; rq[t] = q;
    __syncthreads();
    for (int off = 128; off > 0; off >>= 1) {
        if (t < off) { rs[t] += rs[t + off]; rq[t] += rq[t + off]; }
        __syncthreads();
    }
    if (t == 0) {
        float n = (float)NPIX;
        float mean = rs[0] / n;
        float var  = rq[0] / n - mean * mean;
        meanvar[o] = mean;
        meanvar[CA + o] = var;
    }
}

__global__ __launch_bounds__(256) void k_final(const float* __restrict__ yw,
                                               const float* __restrict__ meanvar,
                                               const float* __restrict__ gamma,
                                               const float* __restrict__ beta,
                                               const float* __restrict__ alpha,
                                               float* __restrict__ out0) {
    size_t i = ((size_t)blockIdx.x * 256 + threadIdx.x) * 4;
    int c = (int)((i >> 14) & 127);
    int b = (int)(i >> 21);
    int pix = (int)(i & 16383);
    float4 v = *(const float4*)(yw + (size_t)c * NPIX + b * 16384 + pix);
    float4 a = *(const float4*)(alpha + i);
    float mean = meanvar[c];
    float var  = meanvar[CA + c];
    float sc   = rsqrtf(var + 1e-5f) * gamma[c];
    float bt   = beta[c];
    float4 r;
    r.x = (v.x - mean) * sc + bt + a.x;
    r.y = (v.y - mean) * sc + bt + a.y;
    r.z = (v.z - mean) * sc + bt + a.z;
    r.w = (v.w - mean) * sc + bt + a.w;
    *(float4*)(out0 + i) = r;
}

extern "C" void kernel_launch(void* const* d_in, const int* in_sizes, int n_in,
                              void* d_out, int out_size, void* d_ws, size_t ws_size,
                              hipStream_t stream) {
    (void)in_sizes; (void)n_in; (void)out_size;
    const float* f     = (const float*)d_in[0];
    const float* alpha = (const float*)d_in[1];
    const float* unk   = (const float*)d_in[2];
    const float* gw    = (const float*)d_in[3];
    const float* gb    = (const float*)d_in[4];
    const float* ww    = (const float*)d_in[5];
    const float* gamma = (const float*)d_in[6];
    const float* beta  = (const float*)d_in[7];

    float* out0 = (float*)d_out;
    float* out1 = out0 + (size_t)B * CA * H * W_;
    float* out2 = out1 + (size_t)B * 2 * HS * WS;

    // ---- persistent region ----
    float* wsf = (float*)d_ws;
    size_t off = 0;
    float* fds     = wsf + off; off += (size_t)B * CM * HS * WS;
    float* ssq     = wsf + off; off += (size_t)B * HS * WS;
    float* gbuf    = wsf + off; off += (size_t)B * L;
    float* dgbuf   = wsf + off; off += (size_t)B * L;
    float* suk     = wsf + off; off += 64;
    float* ytF     = wsf + off; off += (size_t)NPIX * 128 / 2;
    float* wwbfF   = wsf + off; off += 8192;
    float* meanvar = wsf + off; off += 256;
    float* base    = wsf + off;

    const size_t PRE_F = off;
    int nb = (ws_size >= (PRE_F + 4 * SLOT_F) * sizeof(float)) ? 4 : 2;

    float* yw   = base;
    u16*   yt   = (u16*)ytF;
    u16*   wwbf = (u16*)wwbfF;

    k_cvtww<<<64, 256, 0, stream>>>(ww, wwbf);
    k_conv_ds<<<dim3(64, 4), 256, 0, stream>>>(f, gw, gb, fds, ssq);
    k_scale<<<4, 256, 0, stream>>>(unk, suk, out2);
    k_gate<<<dim3(64, 4), 64, 0, stream>>>(unk, ssq, suk, gbuf, dgbuf);

    for (int b0 = 0; b0 < B; b0 += nb) {
        k_buildW<<<dim3(64, 32, nb), dim3(64, 4), 0, stream>>>(fds, base, b0);
        k_gemm1<<<dim3(528, 1, nb), 256, 0, stream>>>(base, gbuf, dgbuf, b0);
        k_softmax<<<dim3(4096, nb), 256, 0, stream>>>(base, gbuf, dgbuf, out1, b0);
        k_buildA<<<dim3(16, 2048, nb), 256, 0, stream>>>(alpha, base, b0);
        k_gemm2<<<dim3(16, 8, nb), 512, 0, stream>>>(base);
        k_gather<<<dim3(64, 128, nb), 256, 0, stream>>>(base, yt, b0);
    }

    k_ywgemm<<<512, 256, 0, stream>>>(wwbf, yt, yw);
    k_stats<<<128, 256, 0, stream>>>(yw, meanvar);
    k_final<<<8192, 256, 0, stream>>>(yw, meanvar, gamma, beta, alpha, out0);
}

// Round 10
// 846.455 us; speedup vs baseline: 1.5241x; 1.0197x over previous
//
#include <hip/hip_runtime.h>
#include <math.h>

#define B 4
#define CG 256
#define CM 128
#define CA 128
#define H 128
#define W_ 128
#define HS 64
#define WS 64
#define L 4096
#define D1 1152
#define D2 2048
#define NPIX 65536
#define NT1 36    // D1/32 k-tiles for gemm1
#define NT2 128   // L/32 k-tiles for gemm2

// slot layout (floats): [STP bf16 L*L][Wf fp32 -> At bf16][Whi bf16 -> Z bf16]
#define STP_F 8388608UL
#define WF_F  4718592UL
#define ZB_F  4194304UL
#define SLOT_F (STP_F + WF_F + ZB_F)   // 17,301,504 floats = 69.2 MB

typedef unsigned short u16;
typedef __attribute__((ext_vector_type(8))) short short8v;
typedef __attribute__((ext_vector_type(4))) unsigned short u16x4;
typedef __attribute__((ext_vector_type(4))) float f32x4;

__device__ __forceinline__ float bf2f(u16 x) {
    union { unsigned int u; float f; } v; v.u = ((unsigned int)x) << 16; return v.f;
}
__device__ __forceinline__ u16 f2bf(float x) {
    union { float f; unsigned int u; } v; v.f = x;
    unsigned int r = (v.u + 0x7FFFu + ((v.u >> 16) & 1u)) >> 16;
    return (u16)r;
}
__device__ __forceinline__ void gll16(const void* g, void* l) {
    __builtin_amdgcn_global_load_lds((const __attribute__((address_space(1))) void*)g,
                                     (__attribute__((address_space(3))) void*)l, 16, 0, 0);
}
__device__ __forceinline__ int refl(int i, int n) {
    return i < 0 ? -i : (i >= n ? 2 * n - 2 - i : i);
}
// swizzled LDS element offset for [128][32 u16] tiles (gemm1; 0-conflict per R5)
__device__ __forceinline__ int swz(int row, int fq) {
    return row * 32 + ((fq ^ ((row >> 1) & 3)) * 8);
}

// ---- gemm2 256^2 pipeline helpers: [256][32 u16] tiles, 64B rows ----
__device__ __forceinline__ void stage32(const u16* __restrict__ mat, int rowTile,
                                        int kt, u16* lds, int wid, int lane) {
#pragma unroll
    for (int c = 0; c < 2; ++c) {
        int off = c * 8192 + wid * 1024 + lane * 16;   // byte offset in tile
        int row = off >> 6;
        int cb  = off & 63;
        const u16* g = mat + (size_t)(rowTile + row) * L + kt * 32
                     + ((cb ^ (((row >> 1) & 3) << 4)) >> 1);
        gll16(g, (char*)lds + c * 8192 + wid * 1024);
    }
}
__device__ __forceinline__ short8v rdfrag32(const u16* lds, int r, int fq) {
    return *(const short8v*)((const char*)lds + r * 64 + ((fq * 16) ^ (((r >> 1) & 3) << 4)));
}

// K0: f_ds = 1x1 conv at even pixels + fused ssq
__global__ __launch_bounds__(256) void k_conv_ds(const float* __restrict__ f,
                                                 const float* __restrict__ gw,
                                                 const float* __restrict__ gb,
                                                 float* __restrict__ fds,
                                                 float* __restrict__ ssq) {
    __shared__ float sf[CG * 64];
    __shared__ float part[4][64];
    int t = threadIdx.x;
    int hs = blockIdx.x, b = blockIdx.y;
    const float* fb = f + (size_t)b * CG * H * W_ + (2 * hs) * W_;
    for (int idx = t; idx < CG * 64; idx += 256) {
        int ci = idx >> 6, ws = idx & 63;
        sf[idx] = fb[(size_t)ci * H * W_ + 2 * ws];
    }
    __syncthreads();
    int ws = t & 63;
    int wave = __builtin_amdgcn_readfirstlane(t >> 6);
    const float* gwp = gw + (size_t)(wave * 32) * CG;
    float acc[32];
#pragma unroll
    for (int r = 0; r < 32; ++r) acc[r] = gb[wave * 32 + r];
    for (int ci = 0; ci < CG; ++ci) {
        float fv = sf[ci * 64 + ws];
#pragma unroll
        for (int r = 0; r < 32; ++r) acc[r] += gwp[r * CG + ci] * fv;
    }
    float sq = 0.f;
#pragma unroll
    for (int r = 0; r < 32; ++r) {
        int co = wave * 32 + r;
        fds[(((size_t)b * CM + co) * HS + hs) * WS + ws] = acc[r];
        sq += acc[r] * acc[r];
    }
    part[wave][ws] = sq;
    __syncthreads();
    if (t < 64)
        ssq[((size_t)b * HS + hs) * WS + t] =
            part[0][t] + part[1][t] + part[2][t] + part[3][t];
}

__global__ __launch_bounds__(256) void k_scale(const float* __restrict__ unk,
                                               float* __restrict__ suk,
                                               float* __restrict__ out2) {
    int b = blockIdx.x, t = threadIdx.x;
    __shared__ float red[256];
    float s = 0.f;
    for (int i = t; i < L; i += 256) {
        int hs = i >> 6, ws = i & 63;
        s += unk[(size_t)b * H * W_ + (2 * hs) * W_ + 2 * ws];
    }
    red[t] = s;
    __syncthreads();
    for (int o = 128; o > 0; o >>= 1) {
        if (t < o) red[t] += red[t + o];
        __syncthreads();
    }
    if (t == 0) {
        float u = red[0] / (float)L;
        float k = 1.0f - u;
        float su = sqrtf(u / k); su = fminf(fmaxf(su, 0.1f), 10.0f);
        float sk = sqrtf(k / u); sk = fminf(fmaxf(sk, 0.1f), 10.0f);
        suk[b * 2] = su; suk[b * 2 + 1] = sk;
        out2[b * 2] = su; out2[b * 2 + 1] = sk;
    }
}

__global__ __launch_bounds__(64) void k_gate(const float* __restrict__ unk,
                                             const float* __restrict__ ssq,
                                             const float* __restrict__ suk,
                                             float* __restrict__ g,
                                             float* __restrict__ dg) {
    int ws = threadIdx.x, hs = blockIdx.x, b = blockIdx.y;
    float sm = 0.f, sq = 0.f;
    for (int di = -1; di <= 1; ++di) {
        int rh = refl(hs + di, HS);
        for (int dj = -1; dj <= 1; ++dj) {
            int rw = refl(ws + dj, WS);
            sm += unk[(size_t)b * H * W_ + (2 * rh) * W_ + 2 * rw];
            sq += ssq[((size_t)b * HS + rh) * WS + rw];
        }
    }
    float mm   = (sm > 0.0f) ? 1.0f : 0.0f;
    float norm = sqrtf(sq);
    float gate = (mm > 0.0f) ? suk[2 * b] : suk[2 * b + 1];
    int q = hs * WS + ws;
    g[(size_t)b * L + q]  = gate / fmaxf(norm, 1e-4f);
    dg[(size_t)b * L + q] = -10000.0f * mm;
}

// K4: fp32 W + bf16 W (batched over z)
__global__ __launch_bounds__(256) void k_buildW(const float* __restrict__ fds,
                                                float* __restrict__ base, int b0) {
    int bz = blockIdx.z;
    int b  = b0 + bz;
    float* S   = base + (size_t)bz * SLOT_F;
    float* Wf  = S + STP_F;
    u16*   Whi = (u16*)(S + STP_F + WF_F);
    int ws = threadIdx.x;
    int c  = blockIdx.y * 4 + threadIdx.y;
    int hs = blockIdx.x;
    int q = hs * WS + ws;
    size_t bo = (size_t)q * D1 + c * 9;
    const float* src = fds + ((size_t)b * CM + c) * HS * WS;
#pragma unroll
    for (int i = 0; i < 3; ++i) {
        int rh = refl(hs + i - 1, HS);
#pragma unroll
        for (int j = 0; j < 3; ++j) {
            int rw = refl(ws + j - 1, WS);
            float v = src[rh * WS + rw];
            Wf[bo + i * 3 + j]  = v;
            Whi[bo + i * 3 + j] = f2bf(v);
        }
    }
}

// K5: symmetric bf16 MFMA score GEMM -> bf16 ST (3-buf counted-vmcnt pipeline)
__global__ __launch_bounds__(256) void k_gemm1(float* __restrict__ base,
                                               const float* __restrict__ g0,
                                               const float* __restrict__ dg0,
                                               int b0) {
    __shared__ u16 sA[3][128 * 32], sB[3][128 * 32];   // 48 KB
    int bz = blockIdx.z;
    float* S = base + (size_t)bz * SLOT_F;
    u16* STP = (u16*)S;
    const u16* Whi = (const u16*)(S + STP_F + WF_F);
    const float* g  = g0  + (size_t)(b0 + bz) * L;
    const float* dg = dg0 + (size_t)(b0 + bz) * L;

    int tid = threadIdx.x;
    int wv = tid >> 6, lane = tid & 63;
    int t0 = blockIdx.x, I = 0;
    while (t0 >= 32 - I) { t0 -= 32 - I; ++I; }
    int J = I + t0;
    int pTile = I * 128, qTile = J * 128;
    int wp = (wv >> 1) * 64, wq = (wv & 1) * 64;
    int r0 = wv * 32;
    int lrow = lane >> 2;
    int csw = ((lane & 3) ^ ((lrow >> 1) & 3)) * 8;
    int fr = lane & 15, fq = lane >> 4;

    const u16* gArow = Whi + (size_t)(pTile + r0 + lrow) * D1 + csw;
    const u16* gBrow = Whi + (size_t)(qTile + r0 + lrow) * D1 + csw;

#define G1STAGE(kt, bf) do { \
    gll16(gArow + (kt) * 32, &sA[bf][r0 * 32]); \
    gll16(gArow + (kt) * 32 + (size_t)16 * D1, &sA[bf][(r0 + 16) * 32]); \
    gll16(gBrow + (kt) * 32, &sB[bf][r0 * 32]); \
    gll16(gBrow + (kt) * 32 + (size_t)16 * D1, &sB[bf][(r0 + 16) * 32]); } while (0)

    f32x4 acc[4][4];
#pragma unroll
    for (int mi = 0; mi < 4; ++mi)
#pragma unroll
        for (int ni = 0; ni < 4; ++ni)
#pragma unroll
            for (int r = 0; r < 4; ++r) acc[mi][ni][r] = 0.f;

    G1STAGE(0, 0);
    G1STAGE(1, 1);
    asm volatile("s_waitcnt vmcnt(4)" ::: "memory");
    __builtin_amdgcn_s_barrier();
    __builtin_amdgcn_sched_barrier(0);

    for (int t = 0; t < NT1; ++t) {
        int cur = t % 3;
        short8v ah[4], bh[4];
#pragma unroll
        for (int i = 0; i < 4; ++i) {
            ah[i] = *(const short8v*)&sA[cur][swz(wp + i * 16 + fr, fq)];
            bh[i] = *(const short8v*)&sB[cur][swz(wq + i * 16 + fr, fq)];
        }
        __builtin_amdgcn_s_setprio(1);
#pragma unroll
        for (int mi = 0; mi < 2; ++mi)
#pragma unroll
            for (int ni = 0; ni < 4; ++ni)
                acc[mi][ni] = __builtin_amdgcn_mfma_f32_16x16x32_bf16(ah[mi], bh[ni], acc[mi][ni], 0, 0, 0);
        __builtin_amdgcn_s_setprio(0);
        int kt2 = (t + 2 < NT1) ? (t + 2) : 0;
        G1STAGE(kt2, (t + 2) % 3);
        asm volatile("s_waitcnt vmcnt(4)" ::: "memory");
        __builtin_amdgcn_sched_barrier(0);
        __builtin_amdgcn_s_setprio(1);
#pragma unroll
        for (int mi = 2; mi < 4; ++mi)
#pragma unroll
            for (int ni = 0; ni < 4; ++ni)
                acc[mi][ni] = __builtin_amdgcn_mfma_f32_16x16x32_bf16(ah[mi], bh[ni], acc[mi][ni], 0, 0, 0);
        __builtin_amdgcn_s_setprio(0);
        __builtin_amdgcn_s_barrier();
        __builtin_amdgcn_sched_barrier(0);
    }
#undef G1STAGE

#pragma unroll
    for (int ni = 0; ni < 4; ++ni) {
        int qq = qTile + wq + ni * 16 + fr;
        float gq = g[qq];
        float dq = dg[qq];
#pragma unroll
        for (int mi = 0; mi < 4; ++mi) {
            int pB = pTile + wp + mi * 16 + fq * 4;
#pragma unroll
            for (int r = 0; r < 4; ++r) {
                int p = pB + r;
                float v = acc[mi][ni][r] * gq;
                if (p == qq) v += dq;
                STP[(size_t)p * L + qq] = f2bf(v);
            }
        }
    }
    if (I != J) {
#pragma unroll
        for (int mi = 0; mi < 4; ++mi) {
            int p0 = pTile + wp + mi * 16 + fq * 4;
            float gp0 = g[p0], gp1 = g[p0 + 1], gp2 = g[p0 + 2], gp3 = g[p0 + 3];
#pragma unroll
            for (int ni = 0; ni < 4; ++ni) {
                int qq = qTile + wq + ni * 16 + fr;
                u16x4 mv;
                mv[0] = f2bf(acc[mi][ni][0] * gp0);
                mv[1] = f2bf(acc[mi][ni][1] * gp1);
                mv[2] = f2bf(acc[mi][ni][2] * gp2);
                mv[3] = f2bf(acc[mi][ni][3] * gp3);
                *(u16x4*)(STP + (size_t)qq * L + p0) = mv;
            }
        }
    }
}

// K6: softmax in-place (bf16) + exact argmax; wave-shfl reductions
__global__ __launch_bounds__(256) void k_softmax(float* __restrict__ base,
                                                 const float* __restrict__ g0,
                                                 const float* __restrict__ dg0,
                                                 float* __restrict__ out1, int b0) {
    __shared__ float buf[L];
    __shared__ float wmax[4], wsum[4], cred[4];
    __shared__ int candList[128];
    __shared__ int candCount;
    int bz = blockIdx.y;
    int b  = b0 + bz;
    float* S = base + (size_t)bz * SLOT_F;
    u16* STP = (u16*)S;
    const float* Wf = S + STP_F;
    const float* g  = g0  + (size_t)b * L;
    const float* dg = dg0 + (size_t)b * L;

    int p = blockIdx.x, t = threadIdx.x;
    int lane = t & 63, wv = t >> 6;
    u16* rowp = STP + (size_t)p * L;

    if (t == 0) candCount = 0;
    float mx = -3.4e38f;
    for (int i = t; i < L / 8; i += 256) {
        short8v v8 = ((const short8v*)rowp)[i];
#pragma unroll
        for (int j = 0; j < 8; ++j) {
            float v = bf2f((u16)v8[j]);
            buf[i * 8 + j] = v;
            mx = fmaxf(mx, v);
        }
    }
#pragma unroll
    for (int o = 32; o > 0; o >>= 1) mx = fmaxf(mx, __shfl_xor(mx, o));
    if (lane == 0) wmax[wv] = mx;
    __syncthreads();
    float M = fmaxf(fmaxf(wmax[0], wmax[1]), fmaxf(wmax[2], wmax[3]));
    float cth = M - (fabsf(M) * 0.0625f + 1e-5f);

    float s = 0.f;
    for (int i = t; i < L; i += 256) {
        float v = buf[i];
        if (v >= cth) {
            int ix = atomicAdd(&candCount, 1);
            if (ix < 128) candList[ix] = i;
        }
        float e = __expf(v - M);
        buf[i] = e;
        s += e;
    }
#pragma unroll
    for (int o = 32; o > 0; o >>= 1) s += __shfl_xor(s, o);
    if (lane == 0) wsum[wv] = s;
    __syncthreads();
    float inv = 1.0f / (wsum[0] + wsum[1] + wsum[2] + wsum[3]);

    for (int i = t; i < L / 8; i += 256) {
        short8v o8;
#pragma unroll
        for (int j = 0; j < 8; ++j) o8[j] = (short)f2bf(buf[i * 8 + j] * inv);
        ((short8v*)rowp)[i] = o8;
    }

    int nc = candCount; if (nc > 128) nc = 128;
    int bestI;
    if (nc == 1) {
        bestI = candList[0];
    } else {
        float bestE = -3.4e38f; bestI = L;
        const float* wp_ = Wf + (size_t)p * D1;
        for (int k = 0; k < nc; ++k) {
            int cand = candList[k];
            const float* wc = Wf + (size_t)cand * D1;
            float part = 0.f;
            for (int j = t; j < D1; j += 256) part += wp_[j] * wc[j];
#pragma unroll
            for (int o = 32; o > 0; o >>= 1) part += __shfl_xor(part, o);
            if (lane == 0) cred[wv] = part;
            __syncthreads();
            float e1 = (cred[0] + cred[1] + cred[2] + cred[3]) * g[cand]
                     + (p == cand ? dg[cand] : 0.f);
            if (e1 > bestE || (e1 == bestE && cand < bestI)) { bestE = e1; bestI = cand; }
            __syncthreads();
        }
    }
    if (t == 0) {
        out1[(size_t)(b * 2 + 0) * L + p] = (float)(bestI / WS - 32);
        out1[(size_t)(b * 2 + 1) * L + p] = (float)(bestI % WS - 32);
    }
}

// K7: At[n,q] = bf16(alpha patch), transposed (overwrites Wf region; batched over z)
__global__ __launch_bounds__(256) void k_buildA(const float* __restrict__ alpha,
                                                float* __restrict__ base, int b0) {
    int bz = blockIdx.z;
    int b  = b0 + bz;
    u16* At = (u16*)(base + (size_t)bz * SLOT_F + STP_F);
    int q = blockIdx.x * 256 + threadIdx.x;
    int n = blockIdx.y;
    int hs = q >> 6, ws = q & 63;
    int c = n >> 4, ki = (n >> 2) & 3, kj = n & 3;
    int rh = refl(2 * hs + ki - 1, H);
    int rw = refl(2 * ws + kj - 1, W_);
    At[(size_t)n * L + q] = f2bf(alpha[((size_t)b * CA + c) * H * W_ + rh * W_ + rw]);
}

// K8: 256^2-tile bf16 MFMA paste GEMM, 4-buffer depth-3 counted-vmcnt pipeline.
__global__ __launch_bounds__(512, 2) void k_gemm2(float* __restrict__ base) {
    __shared__ u16 smem[65536];   // 128 KB: 4 bufs x (A 16KB + B 16KB)
    int bz = blockIdx.z;
    float* S = base + (size_t)bz * SLOT_F;
    const u16* P  = (const u16*)S;
    const u16* At = (const u16*)(S + STP_F);
    u16* Z        = (u16*)(S + STP_F + WF_F);

    int tid = threadIdx.x;
    int wid = tid >> 6, lane = tid & 63;
    int wm = wid >> 2, wn = wid & 3;
    int pTile = blockIdx.x * 256, nTile = blockIdx.y * 256;
    int fr = lane & 15, fq = lane >> 4;

    f32x4 acc[8][4];
#pragma unroll
    for (int m = 0; m < 8; ++m)
#pragma unroll
        for (int n = 0; n < 4; ++n)
#pragma unroll
            for (int r = 0; r < 4; ++r) acc[m][n][r] = 0.f;

    // prologue: stage k-tiles 0,1,2 (12 loads); wait tile 0 (tiles 1,2 in flight)
    stage32(P,  pTile, 0, smem,         wid, lane);
    stage32(At, nTile, 0, smem + 8192,  wid, lane);
    stage32(P,  pTile, 1, smem + 16384, wid, lane);
    stage32(At, nTile, 1, smem + 24576, wid, lane);
    stage32(P,  pTile, 2, smem + 32768, wid, lane);
    stage32(At, nTile, 2, smem + 40960, wid, lane);
    asm volatile("s_waitcnt vmcnt(8)" ::: "memory");
    __builtin_amdgcn_s_barrier();
    __builtin_amdgcn_sched_barrier(0);

    for (int t = 0; t < NT2; ++t) {
        const u16* Ab = smem + (t & 3) * 16384;
        const u16* Bb = Ab + 8192;
        short8v a[8], b[4];
#pragma unroll
        for (int n = 0; n < 4; ++n) b[n] = rdfrag32(Bb, wn * 64 + n * 16 + fr, fq);
#pragma unroll
        for (int m = 0; m < 4; ++m) a[m] = rdfrag32(Ab, wm * 128 + m * 16 + fr, fq);
        __builtin_amdgcn_s_setprio(1);
#pragma unroll
        for (int m = 0; m < 2; ++m)
#pragma unroll
            for (int n = 0; n < 4; ++n)
                acc[m][n] = __builtin_amdgcn_mfma_f32_16x16x32_bf16(a[m], b[n], acc[m][n], 0, 0, 0);
        __builtin_amdgcn_s_setprio(0);
#pragma unroll
        for (int m = 4; m < 8; ++m) a[m] = rdfrag32(Ab, wm * 128 + m * 16 + fr, fq);
        __builtin_amdgcn_s_setprio(1);
#pragma unroll
        for (int m = 2; m < 6; ++m)
#pragma unroll
            for (int n = 0; n < 4; ++n)
                acc[m][n] = __builtin_amdgcn_mfma_f32_16x16x32_bf16(a[m], b[n], acc[m][n], 0, 0, 0);
        __builtin_amdgcn_s_setprio(0);
        // stage k-tile t+3 into buf (t+3)&3; dummy kt=0 at tail keeps vmcnt uniform
        int kt3 = (t + 3 < NT2) ? (t + 3) : 0;
        u16* d3 = smem + ((t + 3) & 3) * 16384;
        stage32(P,  pTile, kt3, d3,        wid, lane);
        stage32(At, nTile, kt3, d3 + 8192, wid, lane);
        // counted wait: <=8 outstanding == tiles t+2,t+3 -> tile t+1 ready
        asm volatile("s_waitcnt vmcnt(8)" ::: "memory");
        __builtin_amdgcn_sched_barrier(0);
        __builtin_amdgcn_s_setprio(1);
#pragma unroll
        for (int m = 6; m < 8; ++m)
#pragma unroll
            for (int n = 0; n < 4; ++n)
                acc[m][n] = __builtin_amdgcn_mfma_f32_16x16x32_bf16(a[m], b[n], acc[m][n], 0, 0, 0);
        __builtin_amdgcn_s_setprio(0);
        __builtin_amdgcn_s_barrier();
        __builtin_amdgcn_sched_barrier(0);
    }

#pragma unroll
    for (int m = 0; m < 8; ++m)
#pragma unroll
        for (int n = 0; n < 4; ++n) {
            int nn = nTile + wn * 64 + n * 16 + fr;
#pragma unroll
            for (int r = 0; r < 4; ++r) {
                int pp = pTile + wm * 128 + m * 16 + fq * 4 + r;
                Z[(size_t)pp * D2 + nn] = f2bf(acc[m][n][r]);
            }
        }
}

// K9: transposed-conv gather -> yt[pix, c] bf16 (batched over z)
__global__ __launch_bounds__(256) void k_gather(float* __restrict__ base,
                                                u16* __restrict__ yt, int b0) {
    int bz = blockIdx.z;
    int b  = b0 + bz;
    const u16* Z = (const u16*)(base + (size_t)bz * SLOT_F + STP_F + WF_F);
    int c  = threadIdx.x & 127;
    int pl = threadIdx.x >> 7;
    int w  = blockIdx.x * 2 + pl;
    int h  = blockIdx.y;
    float s = 0.f;
#pragma unroll
    for (int ki = 0; ki < 4; ++ki) {
        int num = h + 1 - ki;
        if (num < 0 || (num & 1)) continue;
        int hs = num >> 1;
        if (hs >= HS) continue;
#pragma unroll
        for (int kj = 0; kj < 4; ++kj) {
            int numw = w + 1 - kj;
            if (numw < 0 || (numw & 1)) continue;
            int wsd = numw >> 1;
            if (wsd >= WS) continue;
            s += bf2f(Z[(size_t)(hs * WS + wsd) * D2 + c * 16 + ki * 4 + kj]);
        }
    }
    int pix = h * W_ + w;
    int cs = c ^ ((pix & 7) << 3);
    yt[((size_t)b * 16384 + pix) * 128 + cs] = f2bf(0.25f * s);
}

__global__ __launch_bounds__(256) void k_cvtww(const float* __restrict__ ww,
                                               u16* __restrict__ wwbf) {
    int i = blockIdx.x * 256 + threadIdx.x;
    int o = i >> 7, c = i & 127;
    wwbf[o * 128 + (c ^ ((o & 7) << 3))] = f2bf(ww[i]);
}

// K10: yw[o, gp] = sum_c w_w[o,c] * y[gp, c]   MFMA, K=128
__global__ __launch_bounds__(256) void k_ywgemm(const u16* __restrict__ wwbf,
                                                const u16* __restrict__ yt,
                                                float* __restrict__ yw) {
    __shared__ u16 sA[128 * 128], sB[128 * 128];
    int tid = threadIdx.x;
    int wv = tid >> 6, lane = tid & 63;
    int nTile = blockIdx.x * 128;
    int wp = (wv >> 1) * 64, wn = (wv & 1) * 64;
    int fr = lane & 15, fq = lane >> 4;

    const u16* gB = yt + (size_t)nTile * 128;
#pragma unroll
    for (int i = 0; i < 8; ++i) {
        int o = (i * 4 + wv) * 512;
        gll16(wwbf + o + lane * 8, &sA[o]);
        gll16(gB + o + lane * 8, &sB[o]);
    }
    __syncthreads();

    f32x4 acc[4][4];
#pragma unroll
    for (int mi = 0; mi < 4; ++mi)
#pragma unroll
        for (int ni = 0; ni < 4; ++ni)
#pragma unroll
            for (int r = 0; r < 4; ++r) acc[mi][ni][r] = 0.f;

#pragma unroll
    for (int ks = 0; ks < 4; ++ks) {
        int k0 = ks * 32 + fq * 8;
        short8v a[4], bb[4];
#pragma unroll
        for (int i = 0; i < 4; ++i) {
            int ra = wp + i * 16 + fr;
            a[i] = *(const short8v*)&sA[ra * 128 + (k0 ^ ((ra & 7) << 3))];
            int rb = wn + i * 16 + fr;
            bb[i] = *(const short8v*)&sB[rb * 128 + (k0 ^ ((rb & 7) << 3))];
        }
#pragma unroll
        for (int mi = 0; mi < 4; ++mi)
#pragma unroll
            for (int ni = 0; ni < 4; ++ni)
                acc[mi][ni] = __builtin_amdgcn_mfma_f32_16x16x32_bf16(a[mi], bb[ni], acc[mi][ni], 0, 0, 0);
    }

#pragma unroll
    for (int mi = 0; mi < 4; ++mi)
#pragma unroll
        for (int ni = 0; ni < 4; ++ni) {
            int gp = nTile + wn + ni * 16 + fr;
#pragma unroll
            for (int r = 0; r < 4; ++r) {
                int o = wp + mi * 16 + fq * 4 + r;
                yw[(size_t)o * NPIX + gp] = acc[mi][ni][r];
            }
        }
}

__global__ __launch_bounds__(256) void k_stats(const float* __restrict__ yw,
                                               float* __restrict__ meanvar) {
    int o = blockIdx.x, t = threadIdx.x;
    __shared__ float rs[256], rq[256];
    float s = 0.f, q = 0.f;
    const float* p = yw + (size_t)o * NPIX;
    for (int i = t; i < NPIX; i += 256) {
        float v = p[i];
        s += v;
        q += v * v;
    }
    rs[t] = s; rq[t] = q;
    __syncthreads();
    for (int off = 128; off > 0; off >>= 1) {
        if (t < off) { rs[t] += rs[t + off]; rq[t] += rq[t + off]; }
        __syncthreads();
    }
    if (t == 0) {
        float n = (float)NPIX;
        float mean = rs[0] / n;
        float var  = rq[0] / n - mean * mean;
        meanvar[o] = mean;
        meanvar[CA + o] = var;
    }
}

__global__ __launch_bounds__(256) void k_final(const float* __restrict__ yw,
                                               const float* __restrict__ meanvar,
                                               const float* __restrict__ gamma,
                                               const float* __restrict__ beta,
                                               const float* __restrict__ alpha,
                                               float* __restrict__ out0) {
    size_t i = ((size_t)blockIdx.x * 256 + threadIdx.x) * 4;
    int c = (int)((i >> 14) & 127);
    int b = (int)(i >> 21);
    int pix = (int)(i & 16383);
    float4 v = *(const float4*)(yw + (size_t)c * NPIX + b * 16384 + pix);
    float4 a = *(const float4*)(alpha + i);
    float mean = meanvar[c];
    float var  = meanvar[CA + c];
    float sc   = rsqrtf(var + 1e-5f) * gamma[c];
    float bt   = beta[c];
    float4 r;
    r.x = (v.x - mean) * sc + bt + a.x;
    r.y = (v.y - mean) * sc + bt + a.y;
    r.z = (v.z - mean) * sc + bt + a.z;
    r.w = (v.w - mean) * sc + bt + a.w;
    *(float4*)(out0 + i) = r;
}

extern "C" void kernel_launch(void* const* d_in, const int* in_sizes, int n_in,
                              void* d_out, int out_size, void* d_ws, size_t ws_size,
                              hipStream_t stream) {
    (void)in_sizes; (void)n_in; (void)out_size;
    const float* f     = (const float*)d_in[0];
    const float* alpha = (const float*)d_in[1];
    const float* unk   = (const float*)d_in[2];
    const float* gw    = (const float*)d_in[3];
    const float* gb    = (const float*)d_in[4];
    const float* ww    = (const float*)d_in[5];
    const float* gamma = (const float*)d_in[6];
    const float* beta  = (const float*)d_in[7];

    float* out0 = (float*)d_out;
    float* out1 = out0 + (size_t)B * CA * H * W_;
    float* out2 = out1 + (size_t)B * 2 * HS * WS;

    // ---- persistent region ----
    float* wsf = (float*)d_ws;
    size_t off = 0;
    float* fds     = wsf + off; off += (size_t)B * CM * HS * WS;
    float* ssq     = wsf + off; off += (size_t)B * HS * WS;
    float* gbuf    = wsf + off; off += (size_t)B * L;
    float* dgbuf   = wsf + off; off += (size_t)B * L;
    float* suk     = wsf + off; off += 64;
    float* ytF     = wsf + off; off += (size_t)NPIX * 128 / 2;
    float* wwbfF   = wsf + off; off += 8192;
    float* meanvar = wsf + off; off += 256;
    float* base    = wsf + off;

    const size_t PRE_F = off;
    int nb = (ws_size >= (PRE_F + 4 * SLOT_F) * sizeof(float)) ? 4 : 2;

    float* yw   = base;
    u16*   yt   = (u16*)ytF;
    u16*   wwbf = (u16*)wwbfF;

    k_cvtww<<<64, 256, 0, stream>>>(ww, wwbf);
    k_conv_ds<<<dim3(64, 4), 256, 0, stream>>>(f, gw, gb, fds, ssq);
    k_scale<<<4, 256, 0, stream>>>(unk, suk, out2);
    k_gate<<<dim3(64, 4), 64, 0, stream>>>(unk, ssq, suk, gbuf, dgbuf);

    for (int b0 = 0; b0 < B; b0 += nb) {
        k_buildW<<<dim3(64, 32, nb), dim3(64, 4), 0, stream>>>(fds, base, b0);
        k_gemm1<<<dim3(528, 1, nb), 256, 0, stream>>>(base, gbuf, dgbuf, b0);
        k_softmax<<<dim3(4096, nb), 256, 0, stream>>>(base, gbuf, dgbuf, out1, b0);
        k_buildA<<<dim3(16, 2048, nb), 256, 0, stream>>>(alpha, base, b0);
        k_gemm2<<<dim3(16, 8, nb), 512, 0, stream>>>(base);
        k_gather<<<dim3(64, 128, nb), 256, 0, stream>>>(base, yt, b0);
    }

    k_ywgemm<<<512, 256, 0, stream>>>(wwbf, yt, yw);
    k_stats<<<128, 256, 0, stream>>>(yw, meanvar);
    k_final<<<8192, 256, 0, stream>>>(yw, meanvar, gamma, beta, alpha, out0);
}

// Round 11
// 843.838 us; speedup vs baseline: 1.5288x; 1.0031x over previous
//
#include <hip/hip_runtime.h>
#include <math.h>

#define B 4
#define CG 256
#define CM 128
#define CA 128
#define H 128
#define W_ 128
#define HS 64
#define WS 64
#define L 4096
#define D1 1152
#define D2 2048
#define NPIX 65536
#define NT1 36    // D1/32 k-tiles for gemm1
#define NT2 128   // L/32 k-tiles for gemm2

// slot layout (floats): [STP bf16 L*L][Wf fp32 -> At bf16][Whi bf16 -> Z bf16]
#define STP_F 8388608UL
#define WF_F  4718592UL
#define ZB_F  4194304UL
#define SLOT_F (STP_F + WF_F + ZB_F)   // 17,301,504 floats = 69.2 MB

typedef unsigned short u16;
typedef __attribute__((ext_vector_type(8))) short short8v;
typedef __attribute__((ext_vector_type(4))) unsigned short u16x4;
typedef __attribute__((ext_vector_type(4))) float f32x4;

__device__ __forceinline__ float bf2f(u16 x) {
    union { unsigned int u; float f; } v; v.u = ((unsigned int)x) << 16; return v.f;
}
__device__ __forceinline__ u16 f2bf(float x) {
    union { float f; unsigned int u; } v; v.f = x;
    unsigned int r = (v.u + 0x7FFFu + ((v.u >> 16) & 1u)) >> 16;
    return (u16)r;
}
__device__ __forceinline__ void gll16(const void* g, void* l) {
    __builtin_amdgcn_global_load_lds((const __attribute__((address_space(1))) void*)g,
                                     (__attribute__((address_space(3))) void*)l, 16, 0, 0);
}
__device__ __forceinline__ int refl(int i, int n) {
    return i < 0 ? -i : (i >= n ? 2 * n - 2 - i : i);
}
// swizzled LDS element offset for [128][32 u16] tiles (gemm1; 0-conflict per R5)
__device__ __forceinline__ int swz(int row, int fq) {
    return row * 32 + ((fq ^ ((row >> 1) & 3)) * 8);
}
// gemm2 [256][32 u16] tiles, 64B rows, (r>>1)&3 chunk-XOR (0-conflict per R9)
__device__ __forceinline__ short8v rdfrag32(const char* lds, int r, int fq) {
    return *(const short8v*)(lds + r * 64 + ((fq * 16) ^ (((r >> 1) & 3) << 4)));
}

// K0: f_ds = 1x1 conv at even pixels + fused ssq
__global__ __launch_bounds__(256) void k_conv_ds(const float* __restrict__ f,
                                                 const float* __restrict__ gw,
                                                 const float* __restrict__ gb,
                                                 float* __restrict__ fds,
                                                 float* __restrict__ ssq) {
    __shared__ float sf[CG * 64];
    __shared__ float part[4][64];
    int t = threadIdx.x;
    int hs = blockIdx.x, b = blockIdx.y;
    const float* fb = f + (size_t)b * CG * H * W_ + (2 * hs) * W_;
    for (int idx = t; idx < CG * 64; idx += 256) {
        int ci = idx >> 6, ws = idx & 63;
        sf[idx] = fb[(size_t)ci * H * W_ + 2 * ws];
    }
    __syncthreads();
    int ws = t & 63;
    int wave = __builtin_amdgcn_readfirstlane(t >> 6);
    const float* gwp = gw + (size_t)(wave * 32) * CG;
    float acc[32];
#pragma unroll
    for (int r = 0; r < 32; ++r) acc[r] = gb[wave * 32 + r];
    for (int ci = 0; ci < CG; ++ci) {
        float fv = sf[ci * 64 + ws];
#pragma unroll
        for (int r = 0; r < 32; ++r) acc[r] += gwp[r * CG + ci] * fv;
    }
    float sq = 0.f;
#pragma unroll
    for (int r = 0; r < 32; ++r) {
        int co = wave * 32 + r;
        fds[(((size_t)b * CM + co) * HS + hs) * WS + ws] = acc[r];
        sq += acc[r] * acc[r];
    }
    part[wave][ws] = sq;
    __syncthreads();
    if (t < 64)
        ssq[((size_t)b * HS + hs) * WS + t] =
            part[0][t] + part[1][t] + part[2][t] + part[3][t];
}

__global__ __launch_bounds__(256) void k_scale(const float* __restrict__ unk,
                                               float* __restrict__ suk,
                                               float* __restrict__ out2) {
    int b = blockIdx.x, t = threadIdx.x;
    __shared__ float red[256];
    float s = 0.f;
    for (int i = t; i < L; i += 256) {
        int hs = i >> 6, ws = i & 63;
        s += unk[(size_t)b * H * W_ + (2 * hs) * W_ + 2 * ws];
    }
    red[t] = s;
    __syncthreads();
    for (int o = 128; o > 0; o >>= 1) {
        if (t < o) red[t] += red[t + o];
        __syncthreads();
    }
    if (t == 0) {
        float u = red[0] / (float)L;
        float k = 1.0f - u;
        float su = sqrtf(u / k); su = fminf(fmaxf(su, 0.1f), 10.0f);
        float sk = sqrtf(k / u); sk = fminf(fmaxf(sk, 0.1f), 10.0f);
        suk[b * 2] = su; suk[b * 2 + 1] = sk;
        out2[b * 2] = su; out2[b * 2 + 1] = sk;
    }
}

__global__ __launch_bounds__(64) void k_gate(const float* __restrict__ unk,
                                             const float* __restrict__ ssq,
                                             const float* __restrict__ suk,
                                             float* __restrict__ g,
                                             float* __restrict__ dg) {
    int ws = threadIdx.x, hs = blockIdx.x, b = blockIdx.y;
    float sm = 0.f, sq = 0.f;
    for (int di = -1; di <= 1; ++di) {
        int rh = refl(hs + di, HS);
        for (int dj = -1; dj <= 1; ++dj) {
            int rw = refl(ws + dj, WS);
            sm += unk[(size_t)b * H * W_ + (2 * rh) * W_ + 2 * rw];
            sq += ssq[((size_t)b * HS + rh) * WS + rw];
        }
    }
    float mm   = (sm > 0.0f) ? 1.0f : 0.0f;
    float norm = sqrtf(sq);
    float gate = (mm > 0.0f) ? suk[2 * b] : suk[2 * b + 1];
    int q = hs * WS + ws;
    g[(size_t)b * L + q]  = gate / fmaxf(norm, 1e-4f);
    dg[(size_t)b * L + q] = -10000.0f * mm;
}

// K4: fp32 W + bf16 W (batched over z)
__global__ __launch_bounds__(256) void k_buildW(const float* __restrict__ fds,
                                                float* __restrict__ base, int b0) {
    int bz = blockIdx.z;
    int b  = b0 + bz;
    float* S   = base + (size_t)bz * SLOT_F;
    float* Wf  = S + STP_F;
    u16*   Whi = (u16*)(S + STP_F + WF_F);
    int ws = threadIdx.x;
    int c  = blockIdx.y * 4 + threadIdx.y;
    int hs = blockIdx.x;
    int q = hs * WS + ws;
    size_t bo = (size_t)q * D1 + c * 9;
    const float* src = fds + ((size_t)b * CM + c) * HS * WS;
#pragma unroll
    for (int i = 0; i < 3; ++i) {
        int rh = refl(hs + i - 1, HS);
#pragma unroll
        for (int j = 0; j < 3; ++j) {
            int rw = refl(ws + j - 1, WS);
            float v = src[rh * WS + rw];
            Wf[bo + i * 3 + j]  = v;
            Whi[bo + i * 3 + j] = f2bf(v);
        }
    }
}

// K5: symmetric bf16 MFMA score GEMM -> bf16 ST (3-buf counted-vmcnt pipeline)
__global__ __launch_bounds__(256) void k_gemm1(float* __restrict__ base,
                                               const float* __restrict__ g0,
                                               const float* __restrict__ dg0,
                                               int b0) {
    __shared__ u16 sA[3][128 * 32], sB[3][128 * 32];   // 48 KB
    int bz = blockIdx.z;
    float* S = base + (size_t)bz * SLOT_F;
    u16* STP = (u16*)S;
    const u16* Whi = (const u16*)(S + STP_F + WF_F);
    const float* g  = g0  + (size_t)(b0 + bz) * L;
    const float* dg = dg0 + (size_t)(b0 + bz) * L;

    int tid = threadIdx.x;
    int wv = tid >> 6, lane = tid & 63;
    int t0 = blockIdx.x, I = 0;
    while (t0 >= 32 - I) { t0 -= 32 - I; ++I; }
    int J = I + t0;
    int pTile = I * 128, qTile = J * 128;
    int wp = (wv >> 1) * 64, wq = (wv & 1) * 64;
    int r0 = wv * 32;
    int lrow = lane >> 2;
    int csw = ((lane & 3) ^ ((lrow >> 1) & 3)) * 8;
    int fr = lane & 15, fq = lane >> 4;

    const u16* gArow = Whi + (size_t)(pTile + r0 + lrow) * D1 + csw;
    const u16* gBrow = Whi + (size_t)(qTile + r0 + lrow) * D1 + csw;

#define G1STAGE(kt, bf) do { \
    gll16(gArow + (kt) * 32, &sA[bf][r0 * 32]); \
    gll16(gArow + (kt) * 32 + (size_t)16 * D1, &sA[bf][(r0 + 16) * 32]); \
    gll16(gBrow + (kt) * 32, &sB[bf][r0 * 32]); \
    gll16(gBrow + (kt) * 32 + (size_t)16 * D1, &sB[bf][(r0 + 16) * 32]); } while (0)

    f32x4 acc[4][4];
#pragma unroll
    for (int mi = 0; mi < 4; ++mi)
#pragma unroll
        for (int ni = 0; ni < 4; ++ni)
#pragma unroll
            for (int r = 0; r < 4; ++r) acc[mi][ni][r] = 0.f;

    G1STAGE(0, 0);
    G1STAGE(1, 1);
    asm volatile("s_waitcnt vmcnt(4)" ::: "memory");
    __builtin_amdgcn_s_barrier();
    __builtin_amdgcn_sched_barrier(0);

    for (int t = 0; t < NT1; ++t) {
        int cur = t % 3;
        short8v ah[4], bh[4];
#pragma unroll
        for (int i = 0; i < 4; ++i) {
            ah[i] = *(const short8v*)&sA[cur][swz(wp + i * 16 + fr, fq)];
            bh[i] = *(const short8v*)&sB[cur][swz(wq + i * 16 + fr, fq)];
        }
        __builtin_amdgcn_s_setprio(1);
#pragma unroll
        for (int mi = 0; mi < 2; ++mi)
#pragma unroll
            for (int ni = 0; ni < 4; ++ni)
                acc[mi][ni] = __builtin_amdgcn_mfma_f32_16x16x32_bf16(ah[mi], bh[ni], acc[mi][ni], 0, 0, 0);
        __builtin_amdgcn_s_setprio(0);
        int kt2 = (t + 2 < NT1) ? (t + 2) : 0;
        G1STAGE(kt2, (t + 2) % 3);
        asm volatile("s_waitcnt vmcnt(4)" ::: "memory");
        __builtin_amdgcn_sched_barrier(0);
        __builtin_amdgcn_s_setprio(1);
#pragma unroll
        for (int mi = 2; mi < 4; ++mi)
#pragma unroll
            for (int ni = 0; ni < 4; ++ni)
                acc[mi][ni] = __builtin_amdgcn_mfma_f32_16x16x32_bf16(ah[mi], bh[ni], acc[mi][ni], 0, 0, 0);
        __builtin_amdgcn_s_setprio(0);
        __builtin_amdgcn_s_barrier();
        __builtin_amdgcn_sched_barrier(0);
    }
#undef G1STAGE

#pragma unroll
    for (int ni = 0; ni < 4; ++ni) {
        int qq = qTile + wq + ni * 16 + fr;
        float gq = g[qq];
        float dq = dg[qq];
#pragma unroll
        for (int mi = 0; mi < 4; ++mi) {
            int pB = pTile + wp + mi * 16 + fq * 4;
#pragma unroll
            for (int r = 0; r < 4; ++r) {
                int p = pB + r;
                float v = acc[mi][ni][r] * gq;
                if (p == qq) v += dq;
                STP[(size_t)p * L + qq] = f2bf(v);
            }
        }
    }
    if (I != J) {
#pragma unroll
        for (int mi = 0; mi < 4; ++mi) {
            int p0 = pTile + wp + mi * 16 + fq * 4;
            float gp0 = g[p0], gp1 = g[p0 + 1], gp2 = g[p0 + 2], gp3 = g[p0 + 3];
#pragma unroll
            for (int ni = 0; ni < 4; ++ni) {
                int qq = qTile + wq + ni * 16 + fr;
                u16x4 mv;
                mv[0] = f2bf(acc[mi][ni][0] * gp0);
                mv[1] = f2bf(acc[mi][ni][1] * gp1);
                mv[2] = f2bf(acc[mi][ni][2] * gp2);
                mv[3] = f2bf(acc[mi][ni][3] * gp3);
                *(u16x4*)(STP + (size_t)qq * L + p0) = mv;
            }
        }
    }
}

// K6: softmax in-place (bf16) + exact argmax; wave-shfl reductions
__global__ __launch_bounds__(256) void k_softmax(float* __restrict__ base,
                                                 const float* __restrict__ g0,
                                                 const float* __restrict__ dg0,
                                                 float* __restrict__ out1, int b0) {
    __shared__ float buf[L];
    __shared__ float wmax[4], wsum[4], cred[4];
    __shared__ int candList[128];
    __shared__ int candCount;
    int bz = blockIdx.y;
    int b  = b0 + bz;
    float* S = base + (size_t)bz * SLOT_F;
    u16* STP = (u16*)S;
    const float* Wf = S + STP_F;
    const float* g  = g0  + (size_t)b * L;
    const float* dg = dg0 + (size_t)b * L;

    int p = blockIdx.x, t = threadIdx.x;
    int lane = t & 63, wv = t >> 6;
    u16* rowp = STP + (size_t)p * L;

    if (t == 0) candCount = 0;
    float mx = -3.4e38f;
    for (int i = t; i < L / 8; i += 256) {
        short8v v8 = ((const short8v*)rowp)[i];
#pragma unroll
        for (int j = 0; j < 8; ++j) {
            float v = bf2f((u16)v8[j]);
            buf[i * 8 + j] = v;
            mx = fmaxf(mx, v);
        }
    }
#pragma unroll
    for (int o = 32; o > 0; o >>= 1) mx = fmaxf(mx, __shfl_xor(mx, o));
    if (lane == 0) wmax[wv] = mx;
    __syncthreads();
    float M = fmaxf(fmaxf(wmax[0], wmax[1]), fmaxf(wmax[2], wmax[3]));
    float cth = M - (fabsf(M) * 0.0625f + 1e-5f);

    float s = 0.f;
    for (int i = t; i < L; i += 256) {
        float v = buf[i];
        if (v >= cth) {
            int ix = atomicAdd(&candCount, 1);
            if (ix < 128) candList[ix] = i;
        }
        float e = __expf(v - M);
        buf[i] = e;
        s += e;
    }
#pragma unroll
    for (int o = 32; o > 0; o >>= 1) s += __shfl_xor(s, o);
    if (lane == 0) wsum[wv] = s;
    __syncthreads();
    float inv = 1.0f / (wsum[0] + wsum[1] + wsum[2] + wsum[3]);

    for (int i = t; i < L / 8; i += 256) {
        short8v o8;
#pragma unroll
        for (int j = 0; j < 8; ++j) o8[j] = (short)f2bf(buf[i * 8 + j] * inv);
        ((short8v*)rowp)[i] = o8;
    }

    int nc = candCount; if (nc > 128) nc = 128;
    int bestI;
    if (nc == 1) {
        bestI = candList[0];
    } else {
        float bestE = -3.4e38f; bestI = L;
        const float* wp_ = Wf + (size_t)p * D1;
        for (int k = 0; k < nc; ++k) {
            int cand = candList[k];
            const float* wc = Wf + (size_t)cand * D1;
            float part = 0.f;
            for (int j = t; j < D1; j += 256) part += wp_[j] * wc[j];
#pragma unroll
            for (int o = 32; o > 0; o >>= 1) part += __shfl_xor(part, o);
            if (lane == 0) cred[wv] = part;
            __syncthreads();
            float e1 = (cred[0] + cred[1] + cred[2] + cred[3]) * g[cand]
                     + (p == cand ? dg[cand] : 0.f);
            if (e1 > bestE || (e1 == bestE && cand < bestI)) { bestE = e1; bestI = cand; }
            __syncthreads();
        }
    }
    if (t == 0) {
        out1[(size_t)(b * 2 + 0) * L + p] = (float)(bestI / WS - 32);
        out1[(size_t)(b * 2 + 1) * L + p] = (float)(bestI % WS - 32);
    }
}

// K7: At[n,q] = bf16(alpha patch), transposed (overwrites Wf region; batched over z)
__global__ __launch_bounds__(256) void k_buildA(const float* __restrict__ alpha,
                                                float* __restrict__ base, int b0) {
    int bz = blockIdx.z;
    int b  = b0 + bz;
    u16* At = (u16*)(base + (size_t)bz * SLOT_F + STP_F);
    int q = blockIdx.x * 256 + threadIdx.x;
    int n = blockIdx.y;
    int hs = q >> 6, ws = q & 63;
    int c = n >> 4, ki = (n >> 2) & 3, kj = n & 3;
    int rh = refl(2 * hs + ki - 1, H);
    int rw = refl(2 * ws + kj - 1, W_);
    At[(size_t)n * L + q] = f2bf(alpha[((size_t)b * CA + c) * H * W_ + rh * W_ + rw]);
}

// K8: 256^2-tile bf16 MFMA paste GEMM, 4-buf counted-vmcnt + frag-read pipelining.
// While MFMAs of tile t run (operands in regs), ds_reads for tile t+1 issue.
__global__ __launch_bounds__(512, 2) void k_gemm2(float* __restrict__ base) {
    __shared__ u16 smem[65536];   // 128 KB: 4 bufs x 32KB (A 16K + B 16K)
    char* sm = (char*)smem;
    int bz = blockIdx.z;
    float* S = base + (size_t)bz * SLOT_F;
    const u16* P  = (const u16*)S;
    const u16* At = (const u16*)(S + STP_F);
    u16* Z        = (u16*)(S + STP_F + WF_F);

    int tid = threadIdx.x;
    int wid = tid >> 6, lane = tid & 63;
    int wm = wid >> 2, wn = wid & 3;
    int pTile = blockIdx.x * 256, nTile = blockIdx.y * 256;
    int fr = lane & 15, fq = lane >> 4;

    // hoisted per-lane staging source pointers (pre-swizzled, rule 21)
    int off0 = wid * 1024 + lane * 16;
    int row0 = off0 >> 6, cb0 = off0 & 63;
    int off1 = off0 + 8192;
    int row1 = off1 >> 6, cb1 = off1 & 63;
    const u16* pA0 = P  + (size_t)(pTile + row0) * L + ((cb0 ^ (((row0 >> 1) & 3) << 4)) >> 1);
    const u16* pA1 = P  + (size_t)(pTile + row1) * L + ((cb1 ^ (((row1 >> 1) & 3) << 4)) >> 1);
    const u16* pB0 = At + (size_t)(nTile + row0) * L + ((cb0 ^ (((row0 >> 1) & 3) << 4)) >> 1);
    const u16* pB1 = At + (size_t)(nTile + row1) * L + ((cb1 ^ (((row1 >> 1) & 3) << 4)) >> 1);

#define STG2(kt, bi) do { \
    char* d = sm + (bi) * 32768 + wid * 1024; \
    gll16(pA0 + (size_t)(kt) * 32, d); \
    gll16(pA1 + (size_t)(kt) * 32, d + 8192); \
    gll16(pB0 + (size_t)(kt) * 32, d + 16384); \
    gll16(pB1 + (size_t)(kt) * 32, d + 24576); } while (0)

#define PRELOAD2(fa, fb, bi) do { \
    const char* Ab_ = sm + (bi) * 32768; \
    const char* Bb_ = Ab_ + 16384; \
    _Pragma("unroll") for (int n = 0; n < 4; ++n) fb[n] = rdfrag32(Bb_, wn * 64 + n * 16 + fr, fq); \
    _Pragma("unroll") for (int m = 0; m < 8; ++m) fa[m] = rdfrag32(Ab_, wm * 128 + m * 16 + fr, fq); } while (0)

#define PHASE2(t, ca, cb, na, nb_) do { \
    const char* Abn = sm + (((t) + 1) & 3) * 32768; \
    const char* Bbn = Abn + 16384; \
    _Pragma("unroll") for (int n = 0; n < 4; ++n) nb_[n] = rdfrag32(Bbn, wn * 64 + n * 16 + fr, fq); \
    __builtin_amdgcn_s_setprio(1); \
    _Pragma("unroll") for (int m = 0; m < 4; ++m) \
        _Pragma("unroll") for (int n = 0; n < 4; ++n) \
            acc[m][n] = __builtin_amdgcn_mfma_f32_16x16x32_bf16(ca[m], cb[n], acc[m][n], 0, 0, 0); \
    __builtin_amdgcn_s_setprio(0); \
    _Pragma("unroll") for (int m = 0; m < 8; ++m) na[m] = rdfrag32(Abn, wm * 128 + m * 16 + fr, fq); \
    STG2(((t) + 3 < NT2) ? (t) + 3 : 0, ((t) + 3) & 3); \
    asm volatile("s_waitcnt vmcnt(4)" ::: "memory"); \
    __builtin_amdgcn_s_setprio(1); \
    _Pragma("unroll") for (int m = 4; m < 8; ++m) \
        _Pragma("unroll") for (int n = 0; n < 4; ++n) \
            acc[m][n] = __builtin_amdgcn_mfma_f32_16x16x32_bf16(ca[m], cb[n], acc[m][n], 0, 0, 0); \
    __builtin_amdgcn_s_setprio(0); \
    asm volatile("s_waitcnt lgkmcnt(0)" ::: "memory"); \
    __builtin_amdgcn_s_barrier(); \
    __builtin_amdgcn_sched_barrier(0); } while (0)

    f32x4 acc[8][4];
#pragma unroll
    for (int m = 0; m < 8; ++m)
#pragma unroll
        for (int n = 0; n < 4; ++n)
#pragma unroll
            for (int r = 0; r < 4; ++r) acc[m][n][r] = 0.f;

    // prologue: stage tiles 0,1,2; wait so tiles 0,1 resident (tile 2 in flight)
    STG2(0, 0);
    STG2(1, 1);
    STG2(2, 2);
    asm volatile("s_waitcnt vmcnt(4)" ::: "memory");
    __builtin_amdgcn_s_barrier();
    __builtin_amdgcn_sched_barrier(0);

    short8v fa0[8], fb0[4], fa1[8], fb1[4];
    PRELOAD2(fa0, fb0, 0);
    asm volatile("s_waitcnt lgkmcnt(0)" ::: "memory");
    __builtin_amdgcn_sched_barrier(0);

    for (int t = 0; t < NT2; t += 2) {
        PHASE2(t,     fa0, fb0, fa1, fb1);
        PHASE2(t + 1, fa1, fb1, fa0, fb0);
    }
#undef PHASE2
#undef PRELOAD2
#undef STG2

#pragma unroll
    for (int m = 0; m < 8; ++m)
#pragma unroll
        for (int n = 0; n < 4; ++n) {
            int nn = nTile + wn * 64 + n * 16 + fr;
#pragma unroll
            for (int r = 0; r < 4; ++r) {
                int pp = pTile + wm * 128 + m * 16 + fq * 4 + r;
                Z[(size_t)pp * D2 + nn] = f2bf(acc[m][n][r]);
            }
        }
}

// K9: transposed-conv gather -> yt[pix, c] bf16 (batched over z)
__global__ __launch_bounds__(256) void k_gather(float* __restrict__ base,
                                                u16* __restrict__ yt, int b0) {
    int bz = blockIdx.z;
    int b  = b0 + bz;
    const u16* Z = (const u16*)(base + (size_t)bz * SLOT_F + STP_F + WF_F);
    int c  = threadIdx.x & 127;
    int pl = threadIdx.x >> 7;
    int w  = blockIdx.x * 2 + pl;
    int h  = blockIdx.y;
    float s = 0.f;
#pragma unroll
    for (int ki = 0; ki < 4; ++ki) {
        int num = h + 1 - ki;
        if (num < 0 || (num & 1)) continue;
        int hs = num >> 1;
        if (hs >= HS) continue;
#pragma unroll
        for (int kj = 0; kj < 4; ++kj) {
            int numw = w + 1 - kj;
            if (numw < 0 || (numw & 1)) continue;
            int wsd = numw >> 1;
            if (wsd >= WS) continue;
            s += bf2f(Z[(size_t)(hs * WS + wsd) * D2 + c * 16 + ki * 4 + kj]);
        }
    }
    int pix = h * W_ + w;
    int cs = c ^ ((pix & 7) << 3);
    yt[((size_t)b * 16384 + pix) * 128 + cs] = f2bf(0.25f * s);
}

__global__ __launch_bounds__(256) void k_cvtww(const float* __restrict__ ww,
                                               u16* __restrict__ wwbf) {
    int i = blockIdx.x * 256 + threadIdx.x;
    int o = i >> 7, c = i & 127;
    wwbf[o * 128 + (c ^ ((o & 7) << 3))] = f2bf(ww[i]);
}

// K10: yw[o, gp] = sum_c w_w[o,c] * y[gp, c]   MFMA, K=128
__global__ __launch_bounds__(256) void k_ywgemm(const u16* __restrict__ wwbf,
                                                const u16* __restrict__ yt,
                                                float* __restrict__ yw) {
    __shared__ u16 sA[128 * 128], sB[128 * 128];
    int tid = threadIdx.x;
    int wv = tid >> 6, lane = tid & 63;
    int nTile = blockIdx.x * 128;
    int wp = (wv >> 1) * 64, wn = (wv & 1) * 64;
    int fr = lane & 15, fq = lane >> 4;

    const u16* gB = yt + (size_t)nTile * 128;
#pragma unroll
    for (int i = 0; i < 8; ++i) {
        int o = (i * 4 + wv) * 512;
        gll16(wwbf + o + lane * 8, &sA[o]);
        gll16(gB + o + lane * 8, &sB[o]);
    }
    __syncthreads();

    f32x4 acc[4][4];
#pragma unroll
    for (int mi = 0; mi < 4; ++mi)
#pragma unroll
        for (int ni = 0; ni < 4; ++ni)
#pragma unroll
            for (int r = 0; r < 4; ++r) acc[mi][ni][r] = 0.f;

#pragma unroll
    for (int ks = 0; ks < 4; ++ks) {
        int k0 = ks * 32 + fq * 8;
        short8v a[4], bb[4];
#pragma unroll
        for (int i = 0; i < 4; ++i) {
            int ra = wp + i * 16 + fr;
            a[i] = *(const short8v*)&sA[ra * 128 + (k0 ^ ((ra & 7) << 3))];
            int rb = wn + i * 16 + fr;
            bb[i] = *(const short8v*)&sB[rb * 128 + (k0 ^ ((rb & 7) << 3))];
        }
#pragma unroll
        for (int mi = 0; mi < 4; ++mi)
#pragma unroll
            for (int ni = 0; ni < 4; ++ni)
                acc[mi][ni] = __builtin_amdgcn_mfma_f32_16x16x32_bf16(a[mi], bb[ni], acc[mi][ni], 0, 0, 0);
    }

#pragma unroll
    for (int mi = 0; mi < 4; ++mi)
#pragma unroll
        for (int ni = 0; ni < 4; ++ni) {
            int gp = nTile + wn + ni * 16 + fr;
#pragma unroll
            for (int r = 0; r < 4; ++r) {
                int o = wp + mi * 16 + fq * 4 + r;
                yw[(size_t)o * NPIX + gp] = acc[mi][ni][r];
            }
        }
}

__global__ __launch_bounds__(256) void k_stats(const float* __restrict__ yw,
                                               float* __restrict__ meanvar) {
    int o = blockIdx.x, t = threadIdx.x;
    __shared__ float rs[256], rq[256];
    float s = 0.f, q = 0.f;
    const float* p = yw + (size_t)o * NPIX;
    for (int i = t; i < NPIX; i += 256) {
        float v = p[i];
        s += v;
        q += v * v;
    }
    rs[t] = s; rq[t] = q;
    __syncthreads();
    for (int off = 128; off > 0; off >>= 1) {
        if (t < off) { rs[t] += rs[t + off]; rq[t] += rq[t + off]; }
        __syncthreads();
    }
    if (t == 0) {
        float n = (float)NPIX;
        float mean = rs[0] / n;
        float var  = rq[0] / n - mean * mean;
        meanvar[o] = mean;
        meanvar[CA + o] = var;
    }
}

__global__ __launch_bounds__(256) void k_final(const float* __restrict__ yw,
                                               const float* __restrict__ meanvar,
                                               const float* __restrict__ gamma,
                                               const float* __restrict__ beta,
                                               const float* __restrict__ alpha,
                                               float* __restrict__ out0) {
    size_t i = ((size_t)blockIdx.x * 256 + threadIdx.x) * 4;
    int c = (int)((i >> 14) & 127);
    int b = (int)(i >> 21);
    int pix = (int)(i & 16383);
    float4 v = *(const float4*)(yw + (size_t)c * NPIX + b * 16384 + pix);
    float4 a = *(const float4*)(alpha + i);
    float mean = meanvar[c];
    float var  = meanvar[CA + c];
    float sc   = rsqrtf(var + 1e-5f) * gamma[c];
    float bt   = beta[c];
    float4 r;
    r.x = (v.x - mean) * sc + bt + a.x;
    r.y = (v.y - mean) * sc + bt + a.y;
    r.z = (v.z - mean) * sc + bt + a.z;
    r.w = (v.w - mean) * sc + bt + a.w;
    *(float4*)(out0 + i) = r;
}

extern "C" void kernel_launch(void* const* d_in, const int* in_sizes, int n_in,
                              void* d_out, int out_size, void* d_ws, size_t ws_size,
                              hipStream_t stream) {
    (void)in_sizes; (void)n_in; (void)out_size;
    const float* f     = (const float*)d_in[0];
    const float* alpha = (const float*)d_in[1];
    const float* unk   = (const float*)d_in[2];
    const float* gw    = (const float*)d_in[3];
    const float* gb    = (const float*)d_in[4];
    const float* ww    = (const float*)d_in[5];
    const float* gamma = (const float*)d_in[6];
    const float* beta  = (const float*)d_in[7];

    float* out0 = (float*)d_out;
    float* out1 = out0 + (size_t)B * CA * H * W_;
    float* out2 = out1 + (size_t)B * 2 * HS * WS;

    // ---- persistent region ----
    float* wsf = (float*)d_ws;
    size_t off = 0;
    float* fds     = wsf + off; off += (size_t)B * CM * HS * WS;
    float* ssq     = wsf + off; off += (size_t)B * HS * WS;
    float* gbuf    = wsf + off; off += (size_t)B * L;
    float* dgbuf   = wsf + off; off += (size_t)B * L;
    float* suk     = wsf + off; off += 64;
    float* ytF     = wsf + off; off += (size_t)NPIX * 128 / 2;
    float* wwbfF   = wsf + off; off += 8192;
    float* meanvar = wsf + off; off += 256;
    float* base    = wsf + off;

    const size_t PRE_F = off;
    int nb = (ws_size >= (PRE_F + 4 * SLOT_F) * sizeof(float)) ? 4 : 2;

    float* yw   = base;
    u16*   yt   = (u16*)ytF;
    u16*   wwbf = (u16*)wwbfF;

    k_cvtww<<<64, 256, 0, stream>>>(ww, wwbf);
    k_conv_ds<<<dim3(64, 4), 256, 0, stream>>>(f, gw, gb, fds, ssq);
    k_scale<<<4, 256, 0, stream>>>(unk, suk, out2);
    k_gate<<<dim3(64, 4), 64, 0, stream>>>(unk, ssq, suk, gbuf, dgbuf);

    for (int b0 = 0; b0 < B; b0 += nb) {
        k_buildW<<<dim3(64, 32, nb), dim3(64, 4), 0, stream>>>(fds, base, b0);
        k_gemm1<<<dim3(528, 1, nb), 256, 0, stream>>>(base, gbuf, dgbuf, b0);
        k_softmax<<<dim3(4096, nb), 256, 0, stream>>>(base, gbuf, dgbuf, out1, b0);
        k_buildA<<<dim3(16, 2048, nb), 256, 0, stream>>>(alpha, base, b0);
        k_gemm2<<<dim3(16, 8, nb), 512, 0, stream>>>(base);
        k_gather<<<dim3(64, 128, nb), 256, 0, stream>>>(base, yt, b0);
    }

    k_ywgemm<<<512, 256, 0, stream>>>(wwbf, yt, yw);
    k_stats<<<128, 256, 0, stream>>>(yw, meanvar);
    k_final<<<8192, 256, 0, stream>>>(yw, meanvar, gamma, beta, alpha, out0);
}

// Round 13
// 829.877 us; speedup vs baseline: 1.5546x; 1.0168x over previous
//
#include <hip/hip_runtime.h>
#include <math.h>

#define B 4
#define CG 256
#define CM 128
#define CA 128
#define H 128
#define W_ 128
#define HS 64
#define WS 64
#define L 4096
#define D1 1152
#define D2 2048
#define NPIX 65536
#define NT1 36    // D1/32 k-tiles for gemm1
#define NT2 128   // L/32 k-tiles for gemm2

// slot layout (floats): [STP bf16 L*L][RA: Whi bf16 -> At bf16][RB: Z bf16]
#define STP_F 8388608UL
#define RA_F  4194304UL
#define SLOT_F (STP_F + RA_F + RA_F)   // 16,777,216 floats = 67.1 MB

typedef unsigned short u16;
typedef __attribute__((ext_vector_type(8))) short short8v;
typedef __attribute__((ext_vector_type(4))) unsigned short u16x4;
typedef __attribute__((ext_vector_type(4))) float f32x4;

__device__ __forceinline__ float bf2f(u16 x) {
    union { unsigned int u; float f; } v; v.u = ((unsigned int)x) << 16; return v.f;
}
__device__ __forceinline__ u16 f2bf(float x) {
    union { float f; unsigned int u; } v; v.f = x;
    unsigned int r = (v.u + 0x7FFFu + ((v.u >> 16) & 1u)) >> 16;
    return (u16)r;
}
__device__ __forceinline__ void gll16(const void* g, void* l) {
    __builtin_amdgcn_global_load_lds((const __attribute__((address_space(1))) void*)g,
                                     (__attribute__((address_space(3))) void*)l, 16, 0, 0);
}
__device__ __forceinline__ int refl(int i, int n) {
    return i < 0 ? -i : (i >= n ? 2 * n - 2 - i : i);
}
// swizzled LDS element offset for [128][32 u16] tiles (gemm1; 0-conflict per R5)
__device__ __forceinline__ int swz(int row, int fq) {
    return row * 32 + ((fq ^ ((row >> 1) & 3)) * 8);
}
// gemm2 [256][32 u16] tiles, 64B rows, (r>>1)&3 chunk-XOR (0-conflict per R9)
__device__ __forceinline__ short8v rdfrag32(const char* lds, int r, int fq) {
    return *(const short8v*)(lds + r * 64 + ((fq * 16) ^ (((r >> 1) & 3) << 4)));
}

// K0: f_ds = 1x1 conv at even pixels + fused ssq
__global__ __launch_bounds__(256) void k_conv_ds(const float* __restrict__ f,
                                                 const float* __restrict__ gw,
                                                 const float* __restrict__ gb,
                                                 float* __restrict__ fds,
                                                 float* __restrict__ ssq) {
    __shared__ float sf[CG * 64];
    __shared__ float part[4][64];
    int t = threadIdx.x;
    int hs = blockIdx.x, b = blockIdx.y;
    const float* fb = f + (size_t)b * CG * H * W_ + (2 * hs) * W_;
    for (int idx = t; idx < CG * 64; idx += 256) {
        int ci = idx >> 6, ws = idx & 63;
        sf[idx] = fb[(size_t)ci * H * W_ + 2 * ws];
    }
    __syncthreads();
    int ws = t & 63;
    int wave = __builtin_amdgcn_readfirstlane(t >> 6);
    const float* gwp = gw + (size_t)(wave * 32) * CG;
    float acc[32];
#pragma unroll
    for (int r = 0; r < 32; ++r) acc[r] = gb[wave * 32 + r];
    for (int ci = 0; ci < CG; ++ci) {
        float fv = sf[ci * 64 + ws];
#pragma unroll
        for (int r = 0; r < 32; ++r) acc[r] += gwp[r * CG + ci] * fv;
    }
    float sq = 0.f;
#pragma unroll
    for (int r = 0; r < 32; ++r) {
        int co = wave * 32 + r;
        fds[(((size_t)b * CM + co) * HS + hs) * WS + ws] = acc[r];
        sq += acc[r] * acc[r];
    }
    part[wave][ws] = sq;
    __syncthreads();
    if (t < 64)
        ssq[((size_t)b * HS + hs) * WS + t] =
            part[0][t] + part[1][t] + part[2][t] + part[3][t];
}

__global__ __launch_bounds__(256) void k_scale(const float* __restrict__ unk,
                                               float* __restrict__ suk,
                                               float* __restrict__ out2) {
    int b = blockIdx.x, t = threadIdx.x;
    __shared__ float red[256];
    float s = 0.f;
    for (int i = t; i < L; i += 256) {
        int hs = i >> 6, ws = i & 63;
        s += unk[(size_t)b * H * W_ + (2 * hs) * W_ + 2 * ws];
    }
    red[t] = s;
    __syncthreads();
    for (int o = 128; o > 0; o >>= 1) {
        if (t < o) red[t] += red[t + o];
        __syncthreads();
    }
    if (t == 0) {
        float u = red[0] / (float)L;
        float k = 1.0f - u;
        float su = sqrtf(u / k); su = fminf(fmaxf(su, 0.1f), 10.0f);
        float sk = sqrtf(k / u); sk = fminf(fmaxf(sk, 0.1f), 10.0f);
        suk[b * 2] = su; suk[b * 2 + 1] = sk;
        out2[b * 2] = su; out2[b * 2 + 1] = sk;
    }
}

__global__ __launch_bounds__(64) void k_gate(const float* __restrict__ unk,
                                             const float* __restrict__ ssq,
                                             const float* __restrict__ suk,
                                             float* __restrict__ g,
                                             float* __restrict__ dg) {
    int ws = threadIdx.x, hs = blockIdx.x, b = blockIdx.y;
    float sm = 0.f, sq = 0.f;
    for (int di = -1; di <= 1; ++di) {
        int rh = refl(hs + di, HS);
        for (int dj = -1; dj <= 1; ++dj) {
            int rw = refl(ws + dj, WS);
            sm += unk[(size_t)b * H * W_ + (2 * rh) * W_ + 2 * rw];
            sq += ssq[((size_t)b * HS + rh) * WS + rw];
        }
    }
    float mm   = (sm > 0.0f) ? 1.0f : 0.0f;
    float norm = sqrtf(sq);
    float gate = (mm > 0.0f) ? suk[2 * b] : suk[2 * b + 1];
    int q = hs * WS + ws;
    g[(size_t)b * L + q]  = gate / fmaxf(norm, 1e-4f);
    dg[(size_t)b * L + q] = -10000.0f * mm;
}

// K4: bf16 W only (fp32 refinement reads fds directly)
__global__ __launch_bounds__(256) void k_buildW(const float* __restrict__ fds,
                                                float* __restrict__ base, int b0) {
    int bz = blockIdx.z;
    int b  = b0 + bz;
    u16* Whi = (u16*)(base + (size_t)bz * SLOT_F + STP_F);
    int ws = threadIdx.x;
    int c  = blockIdx.y * 4 + threadIdx.y;
    int hs = blockIdx.x;
    int q = hs * WS + ws;
    size_t bo = (size_t)q * D1 + c * 9;
    const float* src = fds + ((size_t)b * CM + c) * HS * WS;
#pragma unroll
    for (int i = 0; i < 3; ++i) {
        int rh = refl(hs + i - 1, HS);
#pragma unroll
        for (int j = 0; j < 3; ++j) {
            int rw = refl(ws + j - 1, WS);
            Whi[bo + i * 3 + j] = f2bf(src[rh * WS + rw]);
        }
    }
}

// K5: symmetric bf16 MFMA score GEMM -> bf16 ST (3-buf + frag-read pipelining)
// R13 fix: barrier after preload — phase 0 stages into buf 0, which the preload reads.
__global__ __launch_bounds__(256, 3) void k_gemm1(float* __restrict__ base,
                                                  const float* __restrict__ g0,
                                                  const float* __restrict__ dg0,
                                                  int b0) {
    __shared__ u16 sA[3][128 * 32], sB[3][128 * 32];   // 48 KB
    int bz = blockIdx.z;
    float* S = base + (size_t)bz * SLOT_F;
    u16* STP = (u16*)S;
    const u16* Whi = (const u16*)(S + STP_F);
    const float* g  = g0  + (size_t)(b0 + bz) * L;
    const float* dg = dg0 + (size_t)(b0 + bz) * L;

    int tid = threadIdx.x;
    int wv = tid >> 6, lane = tid & 63;
    int t0 = blockIdx.x, I = 0;
    while (t0 >= 32 - I) { t0 -= 32 - I; ++I; }
    int J = I + t0;
    int pTile = I * 128, qTile = J * 128;
    int wp = (wv >> 1) * 64, wq = (wv & 1) * 64;
    int r0 = wv * 32;
    int lrow = lane >> 2;
    int csw = ((lane & 3) ^ ((lrow >> 1) & 3)) * 8;
    int fr = lane & 15, fq = lane >> 4;

    const u16* gArow = Whi + (size_t)(pTile + r0 + lrow) * D1 + csw;
    const u16* gBrow = Whi + (size_t)(qTile + r0 + lrow) * D1 + csw;

#define G1STG(kt, bf) do { \
    gll16(gArow + (kt) * 32, &sA[bf][r0 * 32]); \
    gll16(gArow + (kt) * 32 + (size_t)16 * D1, &sA[bf][(r0 + 16) * 32]); \
    gll16(gBrow + (kt) * 32, &sB[bf][r0 * 32]); \
    gll16(gBrow + (kt) * 32 + (size_t)16 * D1, &sB[bf][(r0 + 16) * 32]); } while (0)

#define G1PHASE(t, ca, cb, na, nb_) do { \
    int nxb = ((t) + 1) % 3; \
    _Pragma("unroll") for (int i = 0; i < 4; ++i) \
        nb_[i] = *(const short8v*)&sB[nxb][swz(wq + i * 16 + fr, fq)]; \
    __builtin_amdgcn_s_setprio(1); \
    _Pragma("unroll") for (int mi = 0; mi < 2; ++mi) \
        _Pragma("unroll") for (int ni = 0; ni < 4; ++ni) \
            acc[mi][ni] = __builtin_amdgcn_mfma_f32_16x16x32_bf16(ca[mi], cb[ni], acc[mi][ni], 0, 0, 0); \
    __builtin_amdgcn_s_setprio(0); \
    _Pragma("unroll") for (int i = 0; i < 4; ++i) \
        na[i] = *(const short8v*)&sA[nxb][swz(wp + i * 16 + fr, fq)]; \
    G1STG(((t) + 3 < NT1) ? (t) + 3 : 0, (t) % 3); \
    asm volatile("s_waitcnt vmcnt(4)" ::: "memory"); \
    __builtin_amdgcn_s_setprio(1); \
    _Pragma("unroll") for (int mi = 2; mi < 4; ++mi) \
        _Pragma("unroll") for (int ni = 0; ni < 4; ++ni) \
            acc[mi][ni] = __builtin_amdgcn_mfma_f32_16x16x32_bf16(ca[mi], cb[ni], acc[mi][ni], 0, 0, 0); \
    __builtin_amdgcn_s_setprio(0); \
    asm volatile("s_waitcnt lgkmcnt(0)" ::: "memory"); \
    __builtin_amdgcn_s_barrier(); \
    __builtin_amdgcn_sched_barrier(0); } while (0)

    f32x4 acc[4][4];
#pragma unroll
    for (int mi = 0; mi < 4; ++mi)
#pragma unroll
        for (int ni = 0; ni < 4; ++ni)
#pragma unroll
            for (int r = 0; r < 4; ++r) acc[mi][ni][r] = 0.f;

    G1STG(0, 0);
    G1STG(1, 1);
    G1STG(2, 2);
    asm volatile("s_waitcnt vmcnt(4)" ::: "memory");
    __builtin_amdgcn_s_barrier();
    __builtin_amdgcn_sched_barrier(0);

    short8v fa0[4], fb0[4], fa1[4], fb1[4];
#pragma unroll
    for (int i = 0; i < 4; ++i) {
        fa0[i] = *(const short8v*)&sA[0][swz(wp + i * 16 + fr, fq)];
        fb0[i] = *(const short8v*)&sB[0][swz(wq + i * 16 + fr, fq)];
    }
    asm volatile("s_waitcnt lgkmcnt(0)" ::: "memory");
    __builtin_amdgcn_s_barrier();        // R13 FIX: preload reads of buf 0 complete in
    __builtin_amdgcn_sched_barrier(0);   // ALL waves before phase 0 overwrites buf 0

    for (int t = 0; t < NT1; t += 2) {
        G1PHASE(t,     fa0, fb0, fa1, fb1);
        G1PHASE(t + 1, fa1, fb1, fa0, fb0);
    }
#undef G1PHASE
#undef G1STG

#pragma unroll
    for (int ni = 0; ni < 4; ++ni) {
        int qq = qTile + wq + ni * 16 + fr;
        float gq = g[qq];
        float dq = dg[qq];
#pragma unroll
        for (int mi = 0; mi < 4; ++mi) {
            int pB = pTile + wp + mi * 16 + fq * 4;
#pragma unroll
            for (int r = 0; r < 4; ++r) {
                int p = pB + r;
                float v = acc[mi][ni][r] * gq;
                if (p == qq) v += dq;
                STP[(size_t)p * L + qq] = f2bf(v);
            }
        }
    }
    if (I != J) {
#pragma unroll
        for (int mi = 0; mi < 4; ++mi) {
            int p0 = pTile + wp + mi * 16 + fq * 4;
            float gp0 = g[p0], gp1 = g[p0 + 1], gp2 = g[p0 + 2], gp3 = g[p0 + 3];
#pragma unroll
            for (int ni = 0; ni < 4; ++ni) {
                int qq = qTile + wq + ni * 16 + fr;
                u16x4 mv;
                mv[0] = f2bf(acc[mi][ni][0] * gp0);
                mv[1] = f2bf(acc[mi][ni][1] * gp1);
                mv[2] = f2bf(acc[mi][ni][2] * gp2);
                mv[3] = f2bf(acc[mi][ni][3] * gp3);
                *(u16x4*)(STP + (size_t)qq * L + p0) = mv;
            }
        }
    }
}

// K6: softmax in-place (bf16) + exact argmax via fds-stencil refinement
__global__ __launch_bounds__(256) void k_softmax(float* __restrict__ base,
                                                 const float* __restrict__ fds,
                                                 const float* __restrict__ g0,
                                                 const float* __restrict__ dg0,
                                                 float* __restrict__ out1, int b0) {
    __shared__ float buf[L];
    __shared__ float wmax[4], wsum[4], cred[4];
    __shared__ int candList[128];
    __shared__ int candCount;
    int bz = blockIdx.y;
    int b  = b0 + bz;
    float* S = base + (size_t)bz * SLOT_F;
    u16* STP = (u16*)S;
    const float* fdsb = fds + (size_t)b * CM * HS * WS;
    const float* g  = g0  + (size_t)b * L;
    const float* dg = dg0 + (size_t)b * L;

    int p = blockIdx.x, t = threadIdx.x;
    int lane = t & 63, wv = t >> 6;
    u16* rowp = STP + (size_t)p * L;

    if (t == 0) candCount = 0;
    float mx = -3.4e38f;
    for (int i = t; i < L / 8; i += 256) {
        short8v v8 = ((const short8v*)rowp)[i];
#pragma unroll
        for (int j = 0; j < 8; ++j) {
            float v = bf2f((u16)v8[j]);
            buf[i * 8 + j] = v;
            mx = fmaxf(mx, v);
        }
    }
#pragma unroll
    for (int o = 32; o > 0; o >>= 1) mx = fmaxf(mx, __shfl_xor(mx, o));
    if (lane == 0) wmax[wv] = mx;
    __syncthreads();
    float M = fmaxf(fmaxf(wmax[0], wmax[1]), fmaxf(wmax[2], wmax[3]));
    float cth = M - (fabsf(M) * 0.0625f + 1e-5f);

    float s = 0.f;
    for (int i = t; i < L; i += 256) {
        float v = buf[i];
        if (v >= cth) {
            int ix = atomicAdd(&candCount, 1);
            if (ix < 128) candList[ix] = i;
        }
        float e = __expf(v - M);
        buf[i] = e;
        s += e;
    }
#pragma unroll
    for (int o = 32; o > 0; o >>= 1) s += __shfl_xor(s, o);
    if (lane == 0) wsum[wv] = s;
    __syncthreads();
    float inv = 1.0f / (wsum[0] + wsum[1] + wsum[2] + wsum[3]);

    for (int i = t; i < L / 8; i += 256) {
        short8v o8;
#pragma unroll
        for (int j = 0; j < 8; ++j) o8[j] = (short)f2bf(buf[i * 8 + j] * inv);
        ((short8v*)rowp)[i] = o8;
    }

    int nc = candCount; if (nc > 128) nc = 128;
    int bestI;
    if (nc == 1) {
        bestI = candList[0];
    } else {
        float bestE = -3.4e38f; bestI = L;
        int hp = p >> 6, wpp = p & 63;
        for (int k = 0; k < nc; ++k) {
            int cand = candList[k];
            int hc = cand >> 6, wcc = cand & 63;
            float part = 0.f;
#pragma unroll
            for (int e = 0; e < 5; ++e) {   // static unroll: rule 20
                int kk = t + e * 256;
                if (kk < D1) {
                    int c  = kk / 9, ij = kk - c * 9;
                    int di = ij / 3, dj = ij - di * 3;
                    float pv = fdsb[(size_t)c * (HS * WS)
                                    + refl(hp + di - 1, HS) * WS + refl(wpp + dj - 1, WS)];
                    float cv = fdsb[(size_t)c * (HS * WS)
                                    + refl(hc + di - 1, HS) * WS + refl(wcc + dj - 1, WS)];
                    part += pv * cv;
                }
            }
#pragma unroll
            for (int o = 32; o > 0; o >>= 1) part += __shfl_xor(part, o);
            if (lane == 0) cred[wv] = part;
            __syncthreads();
            float e1 = (cred[0] + cred[1] + cred[2] + cred[3]) * g[cand]
                     + (p == cand ? dg[cand] : 0.f);
            if (e1 > bestE || (e1 == bestE && cand < bestI)) { bestE = e1; bestI = cand; }
            __syncthreads();
        }
    }
    if (t == 0) {
        out1[(size_t)(b * 2 + 0) * L + p] = (float)(bestI / WS - 32);
        out1[(size_t)(b * 2 + 1) * L + p] = (float)(bestI % WS - 32);
    }
}

// K7: At[n,q] = bf16(alpha patch), transposed (over Whi region; batched over z)
__global__ __launch_bounds__(256) void k_buildA(const float* __restrict__ alpha,
                                                float* __restrict__ base, int b0) {
    int bz = blockIdx.z;
    int b  = b0 + bz;
    u16* At = (u16*)(base + (size_t)bz * SLOT_F + STP_F);
    int q = blockIdx.x * 256 + threadIdx.x;
    int n = blockIdx.y;
    int hs = q >> 6, ws = q & 63;
    int c = n >> 4, ki = (n >> 2) & 3, kj = n & 3;
    int rh = refl(2 * hs + ki - 1, H);
    int rw = refl(2 * ws + kj - 1, W_);
    At[(size_t)n * L + q] = f2bf(alpha[((size_t)b * CA + c) * H * W_ + rh * W_ + rw]);
}

// K8: 256^2-tile bf16 MFMA paste GEMM, 4-buf counted-vmcnt + frag-read pipelining.
__global__ __launch_bounds__(512, 2) void k_gemm2(float* __restrict__ base) {
    __shared__ u16 smem[65536];   // 128 KB: 4 bufs x 32KB (A 16K + B 16K)
    char* sm = (char*)smem;
    int bz = blockIdx.z;
    float* S = base + (size_t)bz * SLOT_F;
    const u16* P  = (const u16*)S;
    const u16* At = (const u16*)(S + STP_F);
    u16* Z        = (u16*)(S + STP_F + RA_F);

    int tid = threadIdx.x;
    int wid = tid >> 6, lane = tid & 63;
    int wm = wid >> 2, wn = wid & 3;
    int pTile = blockIdx.x * 256, nTile = blockIdx.y * 256;
    int fr = lane & 15, fq = lane >> 4;

    int off0 = wid * 1024 + lane * 16;
    int row0 = off0 >> 6, cb0 = off0 & 63;
    int off1 = off0 + 8192;
    int row1 = off1 >> 6, cb1 = off1 & 63;
    const u16* pA0 = P  + (size_t)(pTile + row0) * L + ((cb0 ^ (((row0 >> 1) & 3) << 4)) >> 1);
    const u16* pA1 = P  + (size_t)(pTile + row1) * L + ((cb1 ^ (((row1 >> 1) & 3) << 4)) >> 1);
    const u16* pB0 = At + (size_t)(nTile + row0) * L + ((cb0 ^ (((row0 >> 1) & 3) << 4)) >> 1);
    const u16* pB1 = At + (size_t)(nTile + row1) * L + ((cb1 ^ (((row1 >> 1) & 3) << 4)) >> 1);

#define STG2(kt, bi) do { \
    char* d = sm + (bi) * 32768 + wid * 1024; \
    gll16(pA0 + (size_t)(kt) * 32, d); \
    gll16(pA1 + (size_t)(kt) * 32, d + 8192); \
    gll16(pB0 + (size_t)(kt) * 32, d + 16384); \
    gll16(pB1 + (size_t)(kt) * 32, d + 24576); } while (0)

#define PRELOAD2(fa, fb, bi) do { \
    const char* Ab_ = sm + (bi) * 32768; \
    const char* Bb_ = Ab_ + 16384; \
    _Pragma("unroll") for (int n = 0; n < 4; ++n) fb[n] = rdfrag32(Bb_, wn * 64 + n * 16 + fr, fq); \
    _Pragma("unroll") for (int m = 0; m < 8; ++m) fa[m] = rdfrag32(Ab_, wm * 128 + m * 16 + fr, fq); } while (0)

#define PHASE2(t, ca, cb, na, nb_) do { \
    const char* Abn = sm + (((t) + 1) & 3) * 32768; \
    const char* Bbn = Abn + 16384; \
    _Pragma("unroll") for (int n = 0; n < 4; ++n) nb_[n] = rdfrag32(Bbn, wn * 64 + n * 16 + fr, fq); \
    __builtin_amdgcn_s_setprio(1); \
    _Pragma("unroll") for (int m = 0; m < 4; ++m) \
        _Pragma("unroll") for (int n = 0; n < 4; ++n) \
            acc[m][n] = __builtin_amdgcn_mfma_f32_16x16x32_bf16(ca[m], cb[n], acc[m][n], 0, 0, 0); \
    __builtin_amdgcn_s_setprio(0); \
    _Pragma("unroll") for (int m = 0; m < 8; ++m) na[m] = rdfrag32(Abn, wm * 128 + m * 16 + fr, fq); \
    STG2(((t) + 3 < NT2) ? (t) + 3 : 0, ((t) + 3) & 3); \
    asm volatile("s_waitcnt vmcnt(4)" ::: "memory"); \
    __builtin_amdgcn_s_setprio(1); \
    _Pragma("unroll") for (int m = 4; m < 8; ++m) \
        _Pragma("unroll") for (int n = 0; n < 4; ++n) \
            acc[m][n] = __builtin_amdgcn_mfma_f32_16x16x32_bf16(ca[m], cb[n], acc[m][n], 0, 0, 0); \
    __builtin_amdgcn_s_setprio(0); \
    asm volatile("s_waitcnt lgkmcnt(0)" ::: "memory"); \
    __builtin_amdgcn_s_barrier(); \
    __builtin_amdgcn_sched_barrier(0); } while (0)

    f32x4 acc[8][4];
#pragma unroll
    for (int m = 0; m < 8; ++m)
#pragma unroll
        for (int n = 0; n < 4; ++n)
#pragma unroll
            for (int r = 0; r < 4; ++r) acc[m][n][r] = 0.f;

    STG2(0, 0);
    STG2(1, 1);
    STG2(2, 2);
    asm volatile("s_waitcnt vmcnt(4)" ::: "memory");
    __builtin_amdgcn_s_barrier();
    __builtin_amdgcn_sched_barrier(0);

    short8v fa0[8], fb0[4], fa1[8], fb1[4];
    PRELOAD2(fa0, fb0, 0);
    asm volatile("s_waitcnt lgkmcnt(0)" ::: "memory");
    __builtin_amdgcn_sched_barrier(0);

    for (int t = 0; t < NT2; t += 2) {
        PHASE2(t,     fa0, fb0, fa1, fb1);
        PHASE2(t + 1, fa1, fb1, fa0, fb0);
    }
#undef PHASE2
#undef PRELOAD2
#undef STG2

#pragma unroll
    for (int m = 0; m < 8; ++m)
#pragma unroll
        for (int n = 0; n < 4; ++n) {
            int nn = nTile + wn * 64 + n * 16 + fr;
#pragma unroll
            for (int r = 0; r < 4; ++r) {
                int pp = pTile + wm * 128 + m * 16 + fq * 4 + r;
                Z[(size_t)pp * D2 + nn] = f2bf(acc[m][n][r]);
            }
        }
}

// K9: transposed-conv gather -> yt[pix, c] bf16 (batched over z)
__global__ __launch_bounds__(256) void k_gather(float* __restrict__ base,
                                                u16* __restrict__ yt, int b0) {
    int bz = blockIdx.z;
    int b  = b0 + bz;
    const u16* Z = (const u16*)(base + (size_t)bz * SLOT_F + STP_F + RA_F);
    int c  = threadIdx.x & 127;
    int pl = threadIdx.x >> 7;
    int w  = blockIdx.x * 2 + pl;
    int h  = blockIdx.y;
    float s = 0.f;
#pragma unroll
    for (int ki = 0; ki < 4; ++ki) {
        int num = h + 1 - ki;
        if (num < 0 || (num & 1)) continue;
        int hs = num >> 1;
        if (hs >= HS) continue;
#pragma unroll
        for (int kj = 0; kj < 4; ++kj) {
            int numw = w + 1 - kj;
            if (numw < 0 || (numw & 1)) continue;
            int wsd = numw >> 1;
            if (wsd >= WS) continue;
            s += bf2f(Z[(size_t)(hs * WS + wsd) * D2 + c * 16 + ki * 4 + kj]);
        }
    }
    int pix = h * W_ + w;
    int cs = c ^ ((pix & 7) << 3);
    yt[((size_t)b * 16384 + pix) * 128 + cs] = f2bf(0.25f * s);
}

__global__ __launch_bounds__(256) void k_cvtww(const float* __restrict__ ww,
                                               u16* __restrict__ wwbf) {
    int i = blockIdx.x * 256 + threadIdx.x;
    int o = i >> 7, c = i & 127;
    wwbf[o * 128 + (c ^ ((o & 7) << 3))] = f2bf(ww[i]);
}

// K10: yw[o, gp] = sum_c w_w[o,c] * y[gp, c]   MFMA, K=128
__global__ __launch_bounds__(256) void k_ywgemm(const u16* __restrict__ wwbf,
                                                const u16* __restrict__ yt,
                                                float* __restrict__ yw) {
    __shared__ u16 sA[128 * 128], sB[128 * 128];
    int tid = threadIdx.x;
    int wv = tid >> 6, lane = tid & 63;
    int nTile = blockIdx.x * 128;
    int wp = (wv >> 1) * 64, wn = (wv & 1) * 64;
    int fr = lane & 15, fq = lane >> 4;

    const u16* gB = yt + (size_t)nTile * 128;
#pragma unroll
    for (int i = 0; i < 8; ++i) {
        int o = (i * 4 + wv) * 512;
        gll16(wwbf + o + lane * 8, &sA[o]);
        gll16(gB + o + lane * 8, &sB[o]);
    }
    __syncthreads();

    f32x4 acc[4][4];
#pragma unroll
    for (int mi = 0; mi < 4; ++mi)
#pragma unroll
        for (int ni = 0; ni < 4; ++ni)
#pragma unroll
            for (int r = 0; r < 4; ++r) acc[mi][ni][r] = 0.f;

#pragma unroll
    for (int ks = 0; ks < 4; ++ks) {
        int k0 = ks * 32 + fq * 8;
        short8v a[4], bb[4];
#pragma unroll
        for (int i = 0; i < 4; ++i) {
            int ra = wp + i * 16 + fr;
            a[i] = *(const short8v*)&sA[ra * 128 + (k0 ^ ((ra & 7) << 3))];
            int rb = wn + i * 16 + fr;
            bb[i] = *(const short8v*)&sB[rb * 128 + (k0 ^ ((rb & 7) << 3))];
        }
#pragma unroll
        for (int mi = 0; mi < 4; ++mi)
#pragma unroll
            for (int ni = 0; ni < 4; ++ni)
                acc[mi][ni] = __builtin_amdgcn_mfma_f32_16x16x32_bf16(a[mi], bb[ni], acc[mi][ni], 0, 0, 0);
    }

#pragma unroll
    for (int mi = 0; mi < 4; ++mi)
#pragma unroll
        for (int ni = 0; ni < 4; ++ni) {
            int gp = nTile + wn + ni * 16 + fr;
#pragma unroll
            for (int r = 0; r < 4; ++r) {
                int o = wp + mi * 16 + fq * 4 + r;
                yw[(size_t)o * NPIX + gp] = acc[mi][ni][r];
            }
        }
}

__global__ __launch_bounds__(256) void k_stats(const float* __restrict__ yw,
                                               float* __restrict__ meanvar) {
    int o = blockIdx.x, t = threadIdx.x;
    __shared__ float rs[256], rq[256];
    float s = 0.f, q = 0.f;
    const float* p = yw + (size_t)o * NPIX;
    for (int i = t; i < NPIX; i += 256) {
        float v = p[i];
        s += v;
        q += v * v;
    }
    rs[t] = s; rq[t] = q;
    __syncthreads();
    for (int off = 128; off > 0; off >>= 1) {
        if (t < off) { rs[t] += rs[t + off]; rq[t] += rq[t + off]; }
        __syncthreads();
    }
    if (t == 0) {
        float n = (float)NPIX;
        float mean = rs[0] / n;
        float var  = rq[0] / n - mean * mean;
        meanvar[o] = mean;
        meanvar[CA + o] = var;
    }
}

__global__ __launch_bounds__(256) void k_final(const float* __restrict__ yw,
                                               const float* __restrict__ meanvar,
                                               const float* __restrict__ gamma,
                                               const float* __restrict__ beta,
                                               const float* __restrict__ alpha,
                                               float* __restrict__ out0) {
    size_t i = ((size_t)blockIdx.x * 256 + threadIdx.x) * 4;
    int c = (int)((i >> 14) & 127);
    int b = (int)(i >> 21);
    int pix = (int)(i & 16383);
    float4 v = *(const float4*)(yw + (size_t)c * NPIX + b * 16384 + pix);
    float4 a = *(const float4*)(alpha + i);
    float mean = meanvar[c];
    float var  = meanvar[CA + c];
    float sc   = rsqrtf(var + 1e-5f) * gamma[c];
    float bt   = beta[c];
    float4 r;
    r.x = (v.x - mean) * sc + bt + a.x;
    r.y = (v.y - mean) * sc + bt + a.y;
    r.z = (v.z - mean) * sc + bt + a.z;
    r.w = (v.w - mean) * sc + bt + a.w;
    *(float4*)(out0 + i) = r;
}

extern "C" void kernel_launch(void* const* d_in, const int* in_sizes, int n_in,
                              void* d_out, int out_size, void* d_ws, size_t ws_size,
                              hipStream_t stream) {
    (void)in_sizes; (void)n_in; (void)out_size;
    const float* f     = (const float*)d_in[0];
    const float* alpha = (const float*)d_in[1];
    const float* unk   = (const float*)d_in[2];
    const float* gw    = (const float*)d_in[3];
    const float* gb    = (const float*)d_in[4];
    const float* ww    = (const float*)d_in[5];
    const float* gamma = (const float*)d_in[6];
    const float* beta  = (const float*)d_in[7];

    float* out0 = (float*)d_out;
    float* out1 = out0 + (size_t)B * CA * H * W_;
    float* out2 = out1 + (size_t)B * 2 * HS * WS;

    // ---- persistent region ----
    float* wsf = (float*)d_ws;
    size_t off = 0;
    float* fds     = wsf + off; off += (size_t)B * CM * HS * WS;
    float* ssq     = wsf + off; off += (size_t)B * HS * WS;
    float* gbuf    = wsf + off; off += (size_t)B * L;
    float* dgbuf   = wsf + off; off += (size_t)B * L;
    float* suk     = wsf + off; off += 64;
    float* ytF     = wsf + off; off += (size_t)NPIX * 128 / 2;
    float* wwbfF   = wsf + off; off += 8192;
    float* meanvar = wsf + off; off += 256;
    float* base    = wsf + off;

    const size_t PRE_F = off;
    int nb = (ws_size >= (PRE_F + 4 * SLOT_F) * sizeof(float)) ? 4 : 2;

    float* yw   = base;
    u16*   yt   = (u16*)ytF;
    u16*   wwbf = (u16*)wwbfF;

    k_cvtww<<<64, 256, 0, stream>>>(ww, wwbf);
    k_conv_ds<<<dim3(64, 4), 256, 0, stream>>>(f, gw, gb, fds, ssq);
    k_scale<<<4, 256, 0, stream>>>(unk, suk, out2);
    k_gate<<<dim3(64, 4), 64, 0, stream>>>(unk, ssq, suk, gbuf, dgbuf);

    for (int b0 = 0; b0 < B; b0 += nb) {
        k_buildW<<<dim3(64, 32, nb), dim3(64, 4), 0, stream>>>(fds, base, b0);
        k_gemm1<<<dim3(528, 1, nb), 256, 0, stream>>>(base, gbuf, dgbuf, b0);
        k_softmax<<<dim3(4096, nb), 256, 0, stream>>>(base, fds, gbuf, dgbuf, out1, b0);
        k_buildA<<<dim3(16, 2048, nb), 256, 0, stream>>>(alpha, base, b0);
        k_gemm2<<<dim3(16, 8, nb), 512, 0, stream>>>(base);
        k_gather<<<dim3(64, 128, nb), 256, 0, stream>>>(base, yt, b0);
    }

    k_ywgemm<<<512, 256, 0, stream>>>(wwbf, yt, yw);
    k_stats<<<128, 256, 0, stream>>>(yw, meanvar);
    k_final<<<8192, 256, 0, stream>>>(yw, meanvar, gamma, beta, alpha, out0);
}

// Round 14
// 803.714 us; speedup vs baseline: 1.6052x; 1.0326x over previous
//
#include <hip/hip_runtime.h>
#include <math.h>

#define B 4
#define CG 256
#define CM 128
#define CA 128
#define H 128
#define W_ 128
#define HS 64
#define WS 64
#define L 4096
#define D1 1152
#define D2 2048
#define NPIX 65536
#define NT1 36
#define NT2 128

// slot layout (floats): [STP bf16 L*L][RA: Whi bf16 -> At bf16][RB: Z bf16]
#define STP_F 8388608UL
#define RA_F  4194304UL
#define SLOT_F (STP_F + RA_F + RA_F)   // 16,777,216 floats = 67.1 MB

typedef unsigned short u16;
typedef __attribute__((ext_vector_type(8))) short short8v;
typedef __attribute__((ext_vector_type(4))) unsigned short u16x4;
typedef __attribute__((ext_vector_type(4))) float f32x4;

__device__ __forceinline__ float bf2f(u16 x) {
    union { unsigned int u; float f; } v; v.u = ((unsigned int)x) << 16; return v.f;
}
__device__ __forceinline__ u16 f2bf(float x) {
    union { float f; unsigned int u; } v; v.f = x;
    unsigned int r = (v.u + 0x7FFFu + ((v.u >> 16) & 1u)) >> 16;
    return (u16)r;
}
__device__ __forceinline__ void gll16(const void* g, void* l) {
    __builtin_amdgcn_global_load_lds((const __attribute__((address_space(1))) void*)g,
                                     (__attribute__((address_space(3))) void*)l, 16, 0, 0);
}
__device__ __forceinline__ int refl(int i, int n) {
    return i < 0 ? -i : (i >= n ? 2 * n - 2 - i : i);
}
// swizzled LDS element offset for [128][32 u16] tiles (gemm1; 0-conflict per R5)
__device__ __forceinline__ int swz(int row, int fq) {
    return row * 32 + ((fq ^ ((row >> 1) & 3)) * 8);
}
// gemm2 [256][32 u16] tiles, 64B rows, (r>>1)&3 chunk-XOR (0-conflict per R9)
__device__ __forceinline__ short8v rdfrag32(const char* lds, int r, int fq) {
    return *(const short8v*)(lds + r * 64 + ((fq * 16) ^ (((r >> 1) & 3) << 4)));
}

// K0: f_ds = 1x1 conv at even pixels + fused ssq
__global__ __launch_bounds__(256) void k_conv_ds(const float* __restrict__ f,
                                                 const float* __restrict__ gw,
                                                 const float* __restrict__ gb,
                                                 float* __restrict__ fds,
                                                 float* __restrict__ ssq) {
    __shared__ float sf[CG * 64];
    __shared__ float part[4][64];
    int t = threadIdx.x;
    int hs = blockIdx.x, b = blockIdx.y;
    const float* fb = f + (size_t)b * CG * H * W_ + (2 * hs) * W_;
    for (int idx = t; idx < CG * 64; idx += 256) {
        int ci = idx >> 6, ws = idx & 63;
        sf[idx] = fb[(size_t)ci * H * W_ + 2 * ws];
    }
    __syncthreads();
    int ws = t & 63;
    int wave = __builtin_amdgcn_readfirstlane(t >> 6);
    const float* gwp = gw + (size_t)(wave * 32) * CG;
    float acc[32];
#pragma unroll
    for (int r = 0; r < 32; ++r) acc[r] = gb[wave * 32 + r];
    for (int ci = 0; ci < CG; ++ci) {
        float fv = sf[ci * 64 + ws];
#pragma unroll
        for (int r = 0; r < 32; ++r) acc[r] += gwp[r * CG + ci] * fv;
    }
    float sq = 0.f;
#pragma unroll
    for (int r = 0; r < 32; ++r) {
        int co = wave * 32 + r;
        fds[(((size_t)b * CM + co) * HS + hs) * WS + ws] = acc[r];
        sq += acc[r] * acc[r];
    }
    part[wave][ws] = sq;
    __syncthreads();
    if (t < 64)
        ssq[((size_t)b * HS + hs) * WS + t] =
            part[0][t] + part[1][t] + part[2][t] + part[3][t];
}

__global__ __launch_bounds__(256) void k_scale(const float* __restrict__ unk,
                                               float* __restrict__ suk,
                                               float* __restrict__ out2) {
    int b = blockIdx.x, t = threadIdx.x;
    __shared__ float red[256];
    float s = 0.f;
    for (int i = t; i < L; i += 256) {
        int hs = i >> 6, ws = i & 63;
        s += unk[(size_t)b * H * W_ + (2 * hs) * W_ + 2 * ws];
    }
    red[t] = s;
    __syncthreads();
    for (int o = 128; o > 0; o >>= 1) {
        if (t < o) red[t] += red[t + o];
        __syncthreads();
    }
    if (t == 0) {
        float u = red[0] / (float)L;
        float k = 1.0f - u;
        float su = sqrtf(u / k); su = fminf(fmaxf(su, 0.1f), 10.0f);
        float sk = sqrtf(k / u); sk = fminf(fmaxf(sk, 0.1f), 10.0f);
        suk[b * 2] = su; suk[b * 2 + 1] = sk;
        out2[b * 2] = su; out2[b * 2 + 1] = sk;
    }
}

__global__ __launch_bounds__(64) void k_gate(const float* __restrict__ unk,
                                             const float* __restrict__ ssq,
                                             const float* __restrict__ suk,
                                             float* __restrict__ g,
                                             float* __restrict__ dg) {
    int ws = threadIdx.x, hs = blockIdx.x, b = blockIdx.y;
    float sm = 0.f, sq = 0.f;
    for (int di = -1; di <= 1; ++di) {
        int rh = refl(hs + di, HS);
        for (int dj = -1; dj <= 1; ++dj) {
            int rw = refl(ws + dj, WS);
            sm += unk[(size_t)b * H * W_ + (2 * rh) * W_ + 2 * rw];
            sq += ssq[((size_t)b * HS + rh) * WS + rw];
        }
    }
    float mm   = (sm > 0.0f) ? 1.0f : 0.0f;
    float norm = sqrtf(sq);
    float gate = (mm > 0.0f) ? suk[2 * b] : suk[2 * b + 1];
    int q = hs * WS + ws;
    g[(size_t)b * L + q]  = gate / fmaxf(norm, 1e-4f);
    dg[(size_t)b * L + q] = -10000.0f * mm;
}

// K4: bf16 W only
__global__ __launch_bounds__(256) void k_buildW(const float* __restrict__ fds,
                                                float* __restrict__ base, int b0) {
    int bz = blockIdx.z;
    int b  = b0 + bz;
    u16* Whi = (u16*)(base + (size_t)bz * SLOT_F + STP_F);
    int ws = threadIdx.x;
    int c  = blockIdx.y * 4 + threadIdx.y;
    int hs = blockIdx.x;
    int q = hs * WS + ws;
    size_t bo = (size_t)q * D1 + c * 9;
    const float* src = fds + ((size_t)b * CM + c) * HS * WS;
#pragma unroll
    for (int i = 0; i < 3; ++i) {
        int rh = refl(hs + i - 1, HS);
#pragma unroll
        for (int j = 0; j < 3; ++j) {
            int rw = refl(ws + j - 1, WS);
            Whi[bo + i * 3 + j] = f2bf(src[rh * WS + rw]);
        }
    }
}

// K5: symmetric bf16 MFMA score GEMM -> bf16 ST (3-buf + frag-read pipelining)
__global__ __launch_bounds__(256, 3) void k_gemm1(float* __restrict__ base,
                                                  const float* __restrict__ g0,
                                                  const float* __restrict__ dg0,
                                                  int b0) {
    __shared__ u16 sA[3][128 * 32], sB[3][128 * 32];   // 48 KB
    int bz = blockIdx.z;
    float* S = base + (size_t)bz * SLOT_F;
    u16* STP = (u16*)S;
    const u16* Whi = (const u16*)(S + STP_F);
    const float* g  = g0  + (size_t)(b0 + bz) * L;
    const float* dg = dg0 + (size_t)(b0 + bz) * L;

    int tid = threadIdx.x;
    int wv = tid >> 6, lane = tid & 63;
    int t0 = blockIdx.x, I = 0;
    while (t0 >= 32 - I) { t0 -= 32 - I; ++I; }
    int J = I + t0;
    int pTile = I * 128, qTile = J * 128;
    int wp = (wv >> 1) * 64, wq = (wv & 1) * 64;
    int r0 = wv * 32;
    int lrow = lane >> 2;
    int csw = ((lane & 3) ^ ((lrow >> 1) & 3)) * 8;
    int fr = lane & 15, fq = lane >> 4;

    const u16* gArow = Whi + (size_t)(pTile + r0 + lrow) * D1 + csw;
    const u16* gBrow = Whi + (size_t)(qTile + r0 + lrow) * D1 + csw;

#define G1STG(kt, bf) do { \
    gll16(gArow + (kt) * 32, &sA[bf][r0 * 32]); \
    gll16(gArow + (kt) * 32 + (size_t)16 * D1, &sA[bf][(r0 + 16) * 32]); \
    gll16(gBrow + (kt) * 32, &sB[bf][r0 * 32]); \
    gll16(gBrow + (kt) * 32 + (size_t)16 * D1, &sB[bf][(r0 + 16) * 32]); } while (0)

#define G1PHASE(t, ca, cb, na, nb_) do { \
    int nxb = ((t) + 1) % 3; \
    _Pragma("unroll") for (int i = 0; i < 4; ++i) \
        nb_[i] = *(const short8v*)&sB[nxb][swz(wq + i * 16 + fr, fq)]; \
    __builtin_amdgcn_s_setprio(1); \
    _Pragma("unroll") for (int mi = 0; mi < 2; ++mi) \
        _Pragma("unroll") for (int ni = 0; ni < 4; ++ni) \
            acc[mi][ni] = __builtin_amdgcn_mfma_f32_16x16x32_bf16(ca[mi], cb[ni], acc[mi][ni], 0, 0, 0); \
    __builtin_amdgcn_s_setprio(0); \
    _Pragma("unroll") for (int i = 0; i < 4; ++i) \
        na[i] = *(const short8v*)&sA[nxb][swz(wp + i * 16 + fr, fq)]; \
    G1STG(((t) + 3 < NT1) ? (t) + 3 : 0, (t) % 3); \
    asm volatile("s_waitcnt vmcnt(4)" ::: "memory"); \
    __builtin_amdgcn_s_setprio(1); \
    _Pragma("unroll") for (int mi = 2; mi < 4; ++mi) \
        _Pragma("unroll") for (int ni = 0; ni < 4; ++ni) \
            acc[mi][ni] = __builtin_amdgcn_mfma_f32_16x16x32_bf16(ca[mi], cb[ni], acc[mi][ni], 0, 0, 0); \
    __builtin_amdgcn_s_setprio(0); \
    asm volatile("s_waitcnt lgkmcnt(0)" ::: "memory"); \
    __builtin_amdgcn_s_barrier(); \
    __builtin_amdgcn_sched_barrier(0); } while (0)

    f32x4 acc[4][4];
#pragma unroll
    for (int mi = 0; mi < 4; ++mi)
#pragma unroll
        for (int ni = 0; ni < 4; ++ni)
#pragma unroll
            for (int r = 0; r < 4; ++r) acc[mi][ni][r] = 0.f;

    G1STG(0, 0);
    G1STG(1, 1);
    G1STG(2, 2);
    asm volatile("s_waitcnt vmcnt(4)" ::: "memory");
    __builtin_amdgcn_s_barrier();
    __builtin_amdgcn_sched_barrier(0);

    short8v fa0[4], fb0[4], fa1[4], fb1[4];
#pragma unroll
    for (int i = 0; i < 4; ++i) {
        fa0[i] = *(const short8v*)&sA[0][swz(wp + i * 16 + fr, fq)];
        fb0[i] = *(const short8v*)&sB[0][swz(wq + i * 16 + fr, fq)];
    }
    asm volatile("s_waitcnt lgkmcnt(0)" ::: "memory");
    __builtin_amdgcn_s_barrier();        // preload reads of buf 0 complete before phase 0 overwrites
    __builtin_amdgcn_sched_barrier(0);

    for (int t = 0; t < NT1; t += 2) {
        G1PHASE(t,     fa0, fb0, fa1, fb1);
        G1PHASE(t + 1, fa1, fb1, fa0, fb0);
    }
#undef G1PHASE
#undef G1STG

#pragma unroll
    for (int ni = 0; ni < 4; ++ni) {
        int qq = qTile + wq + ni * 16 + fr;
        float gq = g[qq];
        float dq = dg[qq];
#pragma unroll
        for (int mi = 0; mi < 4; ++mi) {
            int pB = pTile + wp + mi * 16 + fq * 4;
#pragma unroll
            for (int r = 0; r < 4; ++r) {
                int p = pB + r;
                float v = acc[mi][ni][r] * gq;
                if (p == qq) v += dq;
                STP[(size_t)p * L + qq] = f2bf(v);
            }
        }
    }
    if (I != J) {
#pragma unroll
        for (int mi = 0; mi < 4; ++mi) {
            int p0 = pTile + wp + mi * 16 + fq * 4;
            float gp0 = g[p0], gp1 = g[p0 + 1], gp2 = g[p0 + 2], gp3 = g[p0 + 3];
#pragma unroll
            for (int ni = 0; ni < 4; ++ni) {
                int qq = qTile + wq + ni * 16 + fr;
                u16x4 mv;
                mv[0] = f2bf(acc[mi][ni][0] * gp0);
                mv[1] = f2bf(acc[mi][ni][1] * gp1);
                mv[2] = f2bf(acc[mi][ni][2] * gp2);
                mv[3] = f2bf(acc[mi][ni][3] * gp3);
                *(u16x4*)(STP + (size_t)qq * L + p0) = mv;
            }
        }
    }
}

// K6: softmax -> UNNORMALIZED exp bf16 in place + rowsum; exact argmax via fds stencil.
// No LDS score buffer: in-place elementwise rewrite; normalization applied in gather.
__global__ __launch_bounds__(256) void k_softmax(float* __restrict__ base,
                                                 const float* __restrict__ fds,
                                                 const float* __restrict__ g0,
                                                 const float* __restrict__ dg0,
                                                 float* __restrict__ rowsum,
                                                 float* __restrict__ out1, int b0) {
    __shared__ float wmax[4], wsum[4], cred[4];
    __shared__ int candList[128];
    __shared__ int candCount;
    int bz = blockIdx.y;
    int b  = b0 + bz;
    float* S = base + (size_t)bz * SLOT_F;
    u16* STP = (u16*)S;
    const float* fdsb = fds + (size_t)b * CM * HS * WS;
    const float* g  = g0  + (size_t)b * L;
    const float* dg = dg0 + (size_t)b * L;

    int p = blockIdx.x, t = threadIdx.x;
    int lane = t & 63, wv = t >> 6;
    u16* rowp = STP + (size_t)p * L;

    if (t == 0) candCount = 0;
    float mx = -3.4e38f;
    for (int i = t; i < L / 8; i += 256) {
        short8v v8 = ((const short8v*)rowp)[i];
#pragma unroll
        for (int j = 0; j < 8; ++j) mx = fmaxf(mx, bf2f((u16)v8[j]));
    }
#pragma unroll
    for (int o = 32; o > 0; o >>= 1) mx = fmaxf(mx, __shfl_xor(mx, o));
    if (lane == 0) wmax[wv] = mx;
    __syncthreads();
    float M = fmaxf(fmaxf(wmax[0], wmax[1]), fmaxf(wmax[2], wmax[3]));
    float cth = M - (fabsf(M) * 0.0625f + 1e-5f);

    float s = 0.f;
    for (int i = t; i < L / 8; i += 256) {
        short8v v8 = ((const short8v*)rowp)[i];
        short8v o8;
#pragma unroll
        for (int j = 0; j < 8; ++j) {
            float v = bf2f((u16)v8[j]);
            if (v >= cth) {
                int ix = atomicAdd(&candCount, 1);
                if (ix < 128) candList[ix] = i * 8 + j;
            }
            float e = __expf(v - M);
            o8[j] = (short)f2bf(e);
            s += e;
        }
        ((short8v*)rowp)[i] = o8;
    }
#pragma unroll
    for (int o = 32; o > 0; o >>= 1) s += __shfl_xor(s, o);
    if (lane == 0) wsum[wv] = s;
    __syncthreads();
    if (t == 0) rowsum[(size_t)b * L + p] = wsum[0] + wsum[1] + wsum[2] + wsum[3];

    int nc = candCount; if (nc > 128) nc = 128;
    int bestI;
    if (nc == 1) {
        bestI = candList[0];
    } else {
        float bestE = -3.4e38f; bestI = L;
        int hp = p >> 6, wpp = p & 63;
        for (int k = 0; k < nc; ++k) {
            int cand = candList[k];
            int hc = cand >> 6, wcc = cand & 63;
            float part = 0.f;
#pragma unroll
            for (int e = 0; e < 5; ++e) {   // static unroll: rule 20
                int kk = t + e * 256;
                if (kk < D1) {
                    int c  = kk / 9, ij = kk - c * 9;
                    int di = ij / 3, dj = ij - di * 3;
                    float pv = fdsb[(size_t)c * (HS * WS)
                                    + refl(hp + di - 1, HS) * WS + refl(wpp + dj - 1, WS)];
                    float cv = fdsb[(size_t)c * (HS * WS)
                                    + refl(hc + di - 1, HS) * WS + refl(wcc + dj - 1, WS)];
                    part += pv * cv;
                }
            }
#pragma unroll
            for (int o = 32; o > 0; o >>= 1) part += __shfl_xor(part, o);
            if (lane == 0) cred[wv] = part;
            __syncthreads();
            float e1 = (cred[0] + cred[1] + cred[2] + cred[3]) * g[cand]
                     + (p == cand ? dg[cand] : 0.f);
            if (e1 > bestE || (e1 == bestE && cand < bestI)) { bestE = e1; bestI = cand; }
            __syncthreads();
        }
    }
    if (t == 0) {
        out1[(size_t)(b * 2 + 0) * L + p] = (float)(bestI / WS - 32);
        out1[(size_t)(b * 2 + 1) * L + p] = (float)(bestI % WS - 32);
    }
}

// K7: At[n',q], n' = (ki*4+kj)*128 + c  (gather-coalesced layout); 4 q per thread
__global__ __launch_bounds__(256) void k_buildA(const float* __restrict__ alpha,
                                                float* __restrict__ base, int b0) {
    int bz = blockIdx.z;
    int b  = b0 + bz;
    u16* At = (u16*)(base + (size_t)bz * SLOT_F + STP_F);
    int q0 = (blockIdx.x * 256 + threadIdx.x) * 4;
    int n  = blockIdx.y;
    int c = n & 127, kikj = n >> 7, ki = kikj >> 2, kj = kikj & 3;
    int hs = q0 >> 6, ws = q0 & 63;
    int rh = refl(2 * hs + ki - 1, H);
    const float* arow = alpha + ((size_t)b * CA + c) * H * W_ + rh * W_;
    u16x4 ov;
#pragma unroll
    for (int j = 0; j < 4; ++j)
        ov[j] = f2bf(arow[refl(2 * (ws + j) + kj - 1, W_)]);
    *(u16x4*)(At + (size_t)n * L + q0) = ov;
}

// K8: 256^2-tile bf16 MFMA paste GEMM, 4-buf counted-vmcnt + frag-read pipelining.
__global__ __launch_bounds__(512, 2) void k_gemm2(float* __restrict__ base) {
    __shared__ u16 smem[65536];   // 128 KB: 4 bufs x 32KB (A 16K + B 16K)
    char* sm = (char*)smem;
    int bz = blockIdx.z;
    float* S = base + (size_t)bz * SLOT_F;
    const u16* P  = (const u16*)S;
    const u16* At = (const u16*)(S + STP_F);
    u16* Z        = (u16*)(S + STP_F + RA_F);

    int tid = threadIdx.x;
    int wid = tid >> 6, lane = tid & 63;
    int wm = wid >> 2, wn = wid & 3;
    int pTile = blockIdx.x * 256, nTile = blockIdx.y * 256;
    int fr = lane & 15, fq = lane >> 4;

    int off0 = wid * 1024 + lane * 16;
    int row0 = off0 >> 6, cb0 = off0 & 63;
    int off1 = off0 + 8192;
    int row1 = off1 >> 6, cb1 = off1 & 63;
    const u16* pA0 = P  + (size_t)(pTile + row0) * L + ((cb0 ^ (((row0 >> 1) & 3) << 4)) >> 1);
    const u16* pA1 = P  + (size_t)(pTile + row1) * L + ((cb1 ^ (((row1 >> 1) & 3) << 4)) >> 1);
    const u16* pB0 = At + (size_t)(nTile + row0) * L + ((cb0 ^ (((row0 >> 1) & 3) << 4)) >> 1);
    const u16* pB1 = At + (size_t)(nTile + row1) * L + ((cb1 ^ (((row1 >> 1) & 3) << 4)) >> 1);

#define STG2(kt, bi) do { \
    char* d = sm + (bi) * 32768 + wid * 1024; \
    gll16(pA0 + (size_t)(kt) * 32, d); \
    gll16(pA1 + (size_t)(kt) * 32, d + 8192); \
    gll16(pB0 + (size_t)(kt) * 32, d + 16384); \
    gll16(pB1 + (size_t)(kt) * 32, d + 24576); } while (0)

#define PRELOAD2(fa, fb, bi) do { \
    const char* Ab_ = sm + (bi) * 32768; \
    const char* Bb_ = Ab_ + 16384; \
    _Pragma("unroll") for (int n = 0; n < 4; ++n) fb[n] = rdfrag32(Bb_, wn * 64 + n * 16 + fr, fq); \
    _Pragma("unroll") for (int m = 0; m < 8; ++m) fa[m] = rdfrag32(Ab_, wm * 128 + m * 16 + fr, fq); } while (0)

#define PHASE2(t, ca, cb, na, nb_) do { \
    const char* Abn = sm + (((t) + 1) & 3) * 32768; \
    const char* Bbn = Abn + 16384; \
    _Pragma("unroll") for (int n = 0; n < 4; ++n) nb_[n] = rdfrag32(Bbn, wn * 64 + n * 16 + fr, fq); \
    __builtin_amdgcn_s_setprio(1); \
    _Pragma("unroll") for (int m = 0; m < 4; ++m) \
        _Pragma("unroll") for (int n = 0; n < 4; ++n) \
            acc[m][n] = __builtin_amdgcn_mfma_f32_16x16x32_bf16(ca[m], cb[n], acc[m][n], 0, 0, 0); \
    __builtin_amdgcn_s_setprio(0); \
    _Pragma("unroll") for (int m = 0; m < 8; ++m) na[m] = rdfrag32(Abn, wm * 128 + m * 16 + fr, fq); \
    STG2(((t) + 3 < NT2) ? (t) + 3 : 0, ((t) + 3) & 3); \
    asm volatile("s_waitcnt vmcnt(4)" ::: "memory"); \
    __builtin_amdgcn_s_setprio(1); \
    _Pragma("unroll") for (int m = 4; m < 8; ++m) \
        _Pragma("unroll") for (int n = 0; n < 4; ++n) \
            acc[m][n] = __builtin_amdgcn_mfma_f32_16x16x32_bf16(ca[m], cb[n], acc[m][n], 0, 0, 0); \
    __builtin_amdgcn_s_setprio(0); \
    asm volatile("s_waitcnt lgkmcnt(0)" ::: "memory"); \
    __builtin_amdgcn_s_barrier(); \
    __builtin_amdgcn_sched_barrier(0); } while (0)

    f32x4 acc[8][4];
#pragma unroll
    for (int m = 0; m < 8; ++m)
#pragma unroll
        for (int n = 0; n < 4; ++n)
#pragma unroll
            for (int r = 0; r < 4; ++r) acc[m][n][r] = 0.f;

    STG2(0, 0);
    STG2(1, 1);
    STG2(2, 2);
    asm volatile("s_waitcnt vmcnt(4)" ::: "memory");
    __builtin_amdgcn_s_barrier();
    __builtin_amdgcn_sched_barrier(0);

    short8v fa0[8], fb0[4], fa1[8], fb1[4];
    PRELOAD2(fa0, fb0, 0);
    asm volatile("s_waitcnt lgkmcnt(0)" ::: "memory");
    __builtin_amdgcn_s_barrier();        // preload of buf 0 completes before later overwrite
    __builtin_amdgcn_sched_barrier(0);

    for (int t = 0; t < NT2; t += 2) {
        PHASE2(t,     fa0, fb0, fa1, fb1);
        PHASE2(t + 1, fa1, fb1, fa0, fb0);
    }
#undef PHASE2
#undef PRELOAD2
#undef STG2

#pragma unroll
    for (int m = 0; m < 8; ++m)
#pragma unroll
        for (int n = 0; n < 4; ++n) {
            int nn = nTile + wn * 64 + n * 16 + fr;
#pragma unroll
            for (int r = 0; r < 4; ++r) {
                int pp = pTile + wm * 128 + m * 16 + fq * 4 + r;
                Z[(size_t)pp * D2 + nn] = f2bf(acc[m][n][r]);
            }
        }
}

// K9: transposed-conv gather -> yt[pix, c] bf16; applies 1/rowsum[src] (coalesced Z reads)
__global__ __launch_bounds__(256) void k_gather(float* __restrict__ base,
                                                const float* __restrict__ rowsum,
                                                u16* __restrict__ yt, int b0) {
    int bz = blockIdx.z;
    int b  = b0 + bz;
    const u16* Z = (const u16*)(base + (size_t)bz * SLOT_F + STP_F + RA_F);
    const float* rs = rowsum + (size_t)b * L;
    int c  = threadIdx.x & 127;
    int pl = threadIdx.x >> 7;
    int w  = blockIdx.x * 2 + pl;
    int h  = blockIdx.y;
    float s = 0.f;
#pragma unroll
    for (int ki = 0; ki < 4; ++ki) {
        int num = h + 1 - ki;
        if (num < 0 || (num & 1)) continue;
        int hs = num >> 1;
        if (hs >= HS) continue;
#pragma unroll
        for (int kj = 0; kj < 4; ++kj) {
            int numw = w + 1 - kj;
            if (numw < 0 || (numw & 1)) continue;
            int wsd = numw >> 1;
            if (wsd >= WS) continue;
            int src = hs * WS + wsd;
            s += bf2f(Z[(size_t)src * D2 + (ki * 4 + kj) * 128 + c]) / rs[src];
        }
    }
    int pix = h * W_ + w;
    int cs = c ^ ((pix & 7) << 3);
    yt[((size_t)b * 16384 + pix) * 128 + cs] = f2bf(0.25f * s);
}

__global__ __launch_bounds__(256) void k_cvtww(const float* __restrict__ ww,
                                               u16* __restrict__ wwbf) {
    int i = blockIdx.x * 256 + threadIdx.x;
    int o = i >> 7, c = i & 127;
    wwbf[o * 128 + (c ^ ((o & 7) << 3))] = f2bf(ww[i]);
}

// K10: yw[o, gp] = sum_c w_w[o,c] * y[gp, c]   MFMA, K=128
__global__ __launch_bounds__(256) void k_ywgemm(const u16* __restrict__ wwbf,
                                                const u16* __restrict__ yt,
                                                float* __restrict__ yw) {
    __shared__ u16 sA[128 * 128], sB[128 * 128];
    int tid = threadIdx.x;
    int wv = tid >> 6, lane = tid & 63;
    int nTile = blockIdx.x * 128;
    int wp = (wv >> 1) * 64, wn = (wv & 1) * 64;
    int fr = lane & 15, fq = lane >> 4;

    const u16* gB = yt + (size_t)nTile * 128;
#pragma unroll
    for (int i = 0; i < 8; ++i) {
        int o = (i * 4 + wv) * 512;
        gll16(wwbf + o + lane * 8, &sA[o]);
        gll16(gB + o + lane * 8, &sB[o]);
    }
    __syncthreads();

    f32x4 acc[4][4];
#pragma unroll
    for (int mi = 0; mi < 4; ++mi)
#pragma unroll
        for (int ni = 0; ni < 4; ++ni)
#pragma unroll
            for (int r = 0; r < 4; ++r) acc[mi][ni][r] = 0.f;

#pragma unroll
    for (int ks = 0; ks < 4; ++ks) {
        int k0 = ks * 32 + fq * 8;
        short8v a[4], bb[4];
#pragma unroll
        for (int i = 0; i < 4; ++i) {
            int ra = wp + i * 16 + fr;
            a[i] = *(const short8v*)&sA[ra * 128 + (k0 ^ ((ra & 7) << 3))];
            int rb = wn + i * 16 + fr;
            bb[i] = *(const short8v*)&sB[rb * 128 + (k0 ^ ((rb & 7) << 3))];
        }
#pragma unroll
        for (int mi = 0; mi < 4; ++mi)
#pragma unroll
            for (int ni = 0; ni < 4; ++ni)
                acc[mi][ni] = __builtin_amdgcn_mfma_f32_16x16x32_bf16(a[mi], bb[ni], acc[mi][ni], 0, 0, 0);
    }

#pragma unroll
    for (int mi = 0; mi < 4; ++mi)
#pragma unroll
        for (int ni = 0; ni < 4; ++ni) {
            int gp = nTile + wn + ni * 16 + fr;
#pragma unroll
            for (int r = 0; r < 4; ++r) {
                int o = wp + mi * 16 + fq * 4 + r;
                yw[(size_t)o * NPIX + gp] = acc[mi][ni][r];
            }
        }
}

__global__ __launch_bounds__(256) void k_stats(const float* __restrict__ yw,
                                               float* __restrict__ meanvar) {
    int o = blockIdx.x, t = threadIdx.x;
    __shared__ float rs[256], rq[256];
    float s = 0.f, q = 0.f;
    const float* p = yw + (size_t)o * NPIX;
    for (int i = t; i < NPIX; i += 256) {
        float v = p[i];
        s += v;
        q += v * v;
    }
    rs[t] = s; rq[t] = q;
    __syncthreads();
    for (int off = 128; off > 0; off >>= 1) {
        if (t < off) { rs[t] += rs[t + off]; rq[t] += rq[t + off]; }
        __syncthreads();
    }
    if (t == 0) {
        float n = (float)NPIX;
        float mean = rs[0] / n;
        float var  = rq[0] / n - mean * mean;
        meanvar[o] = mean;
        meanvar[CA + o] = var;
    }
}

__global__ __launch_bounds__(256) void k_final(const float* __restrict__ yw,
                                               const float* __restrict__ meanvar,
                                               const float* __restrict__ gamma,
                                               const float* __restrict__ beta,
                                               const float* __restrict__ alpha,
                                               float* __restrict__ out0) {
    size_t i = ((size_t)blockIdx.x * 256 + threadIdx.x) * 4;
    int c = (int)((i >> 14) & 127);
    int b = (int)(i >> 21);
    int pix = (int)(i & 16383);
    float4 v = *(const float4*)(yw + (size_t)c * NPIX + b * 16384 + pix);
    float4 a = *(const float4*)(alpha + i);
    float mean = meanvar[c];
    float var  = meanvar[CA + c];
    float sc   = rsqrtf(var + 1e-5f) * gamma[c];
    float bt   = beta[c];
    float4 r;
    r.x = (v.x - mean) * sc + bt + a.x;
    r.y = (v.y - mean) * sc + bt + a.y;
    r.z = (v.z - mean) * sc + bt + a.z;
    r.w = (v.w - mean) * sc + bt + a.w;
    *(float4*)(out0 + i) = r;
}

extern "C" void kernel_launch(void* const* d_in, const int* in_sizes, int n_in,
                              void* d_out, int out_size, void* d_ws, size_t ws_size,
                              hipStream_t stream) {
    (void)in_sizes; (void)n_in; (void)out_size;
    const float* f     = (const float*)d_in[0];
    const float* alpha = (const float*)d_in[1];
    const float* unk   = (const float*)d_in[2];
    const float* gw    = (const float*)d_in[3];
    const float* gb    = (const float*)d_in[4];
    const float* ww    = (const float*)d_in[5];
    const float* gamma = (const float*)d_in[6];
    const float* beta  = (const float*)d_in[7];

    float* out0 = (float*)d_out;
    float* out1 = out0 + (size_t)B * CA * H * W_;
    float* out2 = out1 + (size_t)B * 2 * HS * WS;

    // ---- persistent region ----
    float* wsf = (float*)d_ws;
    size_t off = 0;
    float* fds     = wsf + off; off += (size_t)B * CM * HS * WS;
    float* ssq     = wsf + off; off += (size_t)B * HS * WS;
    float* gbuf    = wsf + off; off += (size_t)B * L;
    float* dgbuf   = wsf + off; off += (size_t)B * L;
    float* suk     = wsf + off; off += 64;
    float* ytF     = wsf + off; off += (size_t)NPIX * 128 / 2;
    float* wwbfF   = wsf + off; off += 8192;
    float* meanvar = wsf + off; off += 256;
    float* rowsum  = wsf + off; off += (size_t)B * L;
    float* base    = wsf + off;

    const size_t PRE_F = off;
    int nb = (ws_size >= (PRE_F + 4 * SLOT_F) * sizeof(float)) ? 4 : 2;

    float* yw   = base;
    u16*   yt   = (u16*)ytF;
    u16*   wwbf = (u16*)wwbfF;

    k_cvtww<<<64, 256, 0, stream>>>(ww, wwbf);
    k_conv_ds<<<dim3(64, 4), 256, 0, stream>>>(f, gw, gb, fds, ssq);
    k_scale<<<4, 256, 0, stream>>>(unk, suk, out2);
    k_gate<<<dim3(64, 4), 64, 0, stream>>>(unk, ssq, suk, gbuf, dgbuf);

    for (int b0 = 0; b0 < B; b0 += nb) {
        k_buildW<<<dim3(64, 32, nb), dim3(64, 4), 0, stream>>>(fds, base, b0);
        k_gemm1<<<dim3(528, 1, nb), 256, 0, stream>>>(base, gbuf, dgbuf, b0);
        k_softmax<<<dim3(4096, nb), 256, 0, stream>>>(base, fds, gbuf, dgbuf, rowsum, out1, b0);
        k_buildA<<<dim3(4, 2048, nb), 256, 0, stream>>>(alpha, base, b0);
        k_gemm2<<<dim3(16, 8, nb), 512, 0, stream>>>(base);
        k_gather<<<dim3(64, 128, nb), 256, 0, stream>>>(base, rowsum, yt, b0);
    }

    k_ywgemm<<<512, 256, 0, stream>>>(wwbf, yt, yw);
    k_stats<<<128, 256, 0, stream>>>(yw, meanvar);
    k_final<<<8192, 256, 0, stream>>>(yw, meanvar, gamma, beta, alpha, out0);
}